// Round 2
// baseline (972.651 us; speedup 1.0000x reference)
//
#include <hip/hip_runtime.h>
#include <hip/hip_bf16.h>
#include <cstdio>

#define NU_ 100000
#define NM_ 20000
#define FU_ 32
#define FM_ 128
#define H1_ 8
#define C1_ 16
#define D1_ 128
#define H2_ 4
#define C2_ 128
#define D2_ 512
#define NE_ 250000
#define EL_ 200000

static inline int cdiv_i(int a, int b) { return (a + b - 1) / b; }

// ---------------- CSR build ----------------

__global__ void copy_i32(const int* __restrict__ a, int* __restrict__ b, int n) {
    int i = blockIdx.x * blockDim.x + threadIdx.x;
    if (i < n) b[i] = a[i];
}

__global__ void count_dst(const int* __restrict__ dst, int* __restrict__ cnt, int E) {
    int i = blockIdx.x * blockDim.x + threadIdx.x;
    if (i < E) atomicAdd(&cnt[dst[i]], 1);
}

__global__ void fill_perm(const int* __restrict__ dst, int* __restrict__ ofs,
                          int* __restrict__ perm, int E) {
    int i = blockIdx.x * blockDim.x + threadIdx.x;
    if (i < E) {
        int p = atomicAdd(&ofs[dst[i]], 1);
        perm[p] = i;
    }
}

// single-block segmented exclusive scan; out[0..n-1] exclusive, out[n]=total
__global__ __launch_bounds__(1024) void exscan_kernel(const int* __restrict__ in,
                                                      int* __restrict__ out, int n) {
    __shared__ int sums[1024];
    int tid = threadIdx.x;
    int seg = (n + 1023) / 1024;
    int lo = tid * seg, hi = min(lo + seg, n);
    int s = 0;
    for (int i = lo; i < hi; ++i) s += in[i];
    sums[tid] = s;
    __syncthreads();
    for (int off = 1; off < 1024; off <<= 1) {
        int y = (tid >= off) ? sums[tid - off] : 0;
        __syncthreads();
        sums[tid] += y;
        __syncthreads();
    }
    int run = (tid == 0) ? 0 : sums[tid - 1];
    for (int i = lo; i < hi; ++i) { out[i] = run; run += in[i]; }
    if (tid == 1023) out[n] = sums[1023];
}

// ---------------- weight folding ----------------

// v[k,h] = sum_c W[k, h*C+c] * a[h,c]
__global__ void fold_a(const float* __restrict__ W, const float* __restrict__ a,
                       float* __restrict__ v, int K, int H, int C) {
    int i = blockIdx.x * blockDim.x + threadIdx.x;
    if (i >= K * H) return;
    int k = i / H, h = i % H;
    float s = 0.f;
    for (int c = 0; c < C; ++c) s += W[(size_t)k * (H * C) + h * C + c] * a[h * C + c];
    v[k * H + h] = s;
}

// wp[k, h*16+j] = sum_c W2s[k, h*128+c] * dw1[(rowoff + h*128 + c)*16 + j]
__global__ void fold_w2(const float* __restrict__ W2s, const float* __restrict__ dw1,
                        int rowoff, float* __restrict__ wp) {
    int i = blockIdx.x * blockDim.x + threadIdx.x;
    if (i >= 128 * 64) return;
    int k = i >> 6, hj = i & 63, h = hj >> 4, j = hj & 15;
    float s = 0.f;
    for (int c = 0; c < 128; ++c)
        s += W2s[(size_t)k * 512 + h * 128 + c] * dw1[(size_t)(rowoff + h * 128 + c) * 16 + j];
    wp[i] = s;
}

// cj[j] = db1[j] + sum_col b2mu[col]*dw1[col,j] + b2um[col]*dw1[512+col,j]
__global__ void fold_cj(const float* __restrict__ b2mu, const float* __restrict__ b2um,
                        const float* __restrict__ dw1, const float* __restrict__ db1,
                        float* __restrict__ cj) {
    int j = threadIdx.x;
    if (j >= 16) return;
    float s = db1[j];
    for (int col = 0; col < 512; ++col)
        s += b2mu[col] * dw1[col * 16 + j] + b2um[col] * dw1[(512 + col) * 16 + j];
    cj[j] = s;
}

// per-node logits: out[n,h] = sum_k X[n,k] * v[k,h]   (one wave per node)
template <int H>
__global__ __launch_bounds__(256) void node_logits(const float* __restrict__ X,
                                                   const float* __restrict__ v,
                                                   float* __restrict__ out, int N, int K) {
    int wid = (blockIdx.x * 256 + threadIdx.x) >> 6;
    int lane = threadIdx.x & 63;
    if (wid >= N) return;
    float p[H];
#pragma unroll
    for (int h = 0; h < H; ++h) p[h] = 0.f;
    for (int k = lane; k < K; k += 64) {
        float x = X[(size_t)wid * K + k];
#pragma unroll
        for (int h = 0; h < H; ++h) p[h] += x * v[k * H + h];
    }
#pragma unroll
    for (int off = 32; off; off >>= 1)
#pragma unroll
        for (int h = 0; h < H; ++h) p[h] += __shfl_xor(p[h], off, 64);
    if (lane == 0) {
#pragma unroll
        for (int h = 0; h < H; ++h) out[(size_t)wid * H + h] = p[h];
    }
}

// ---------------- fp32 tiled GEMM: C = A[NxK] @ B[KxM], K%16==0, M%64==0 ----------------
__global__ __launch_bounds__(256) void gemm_f32(const float* __restrict__ A,
                                                const float* __restrict__ B,
                                                float* __restrict__ C,
                                                int N, int K, int M) {
    __shared__ float As[16][65];
    __shared__ float Bs[16][64];
    int bm = blockIdx.y * 64;
    int bn = blockIdx.x * 64;
    int tid = threadIdx.x;
    int tr = tid >> 4, tc = tid & 15;
    float acc[4][4];
#pragma unroll
    for (int i = 0; i < 4; ++i)
#pragma unroll
        for (int j = 0; j < 4; ++j) acc[i][j] = 0.f;

    for (int k0 = 0; k0 < K; k0 += 16) {
        {
            int r = tid >> 2;
            int c4 = (tid & 3) * 4;
            int gr = bm + r;
            float4 v4 = make_float4(0.f, 0.f, 0.f, 0.f);
            if (gr < N) v4 = *(const float4*)(A + (size_t)gr * K + k0 + c4);
            As[c4 + 0][r] = v4.x;
            As[c4 + 1][r] = v4.y;
            As[c4 + 2][r] = v4.z;
            As[c4 + 3][r] = v4.w;
        }
        {
            int r = tid >> 4, c = tid & 15;
            float4 v4 = *(const float4*)(B + (size_t)(k0 + r) * M + bn + c * 4);
            *(float4*)&Bs[r][c * 4] = v4;
        }
        __syncthreads();
#pragma unroll
        for (int kk = 0; kk < 16; ++kk) {
            float a0 = As[kk][tr * 4 + 0], a1 = As[kk][tr * 4 + 1];
            float a2 = As[kk][tr * 4 + 2], a3 = As[kk][tr * 4 + 3];
            float b0 = Bs[kk][tc * 4 + 0], b1 = Bs[kk][tc * 4 + 1];
            float b2 = Bs[kk][tc * 4 + 2], b3 = Bs[kk][tc * 4 + 3];
            acc[0][0] = fmaf(a0, b0, acc[0][0]); acc[0][1] = fmaf(a0, b1, acc[0][1]);
            acc[0][2] = fmaf(a0, b2, acc[0][2]); acc[0][3] = fmaf(a0, b3, acc[0][3]);
            acc[1][0] = fmaf(a1, b0, acc[1][0]); acc[1][1] = fmaf(a1, b1, acc[1][1]);
            acc[1][2] = fmaf(a1, b2, acc[1][2]); acc[1][3] = fmaf(a1, b3, acc[1][3]);
            acc[2][0] = fmaf(a2, b0, acc[2][0]); acc[2][1] = fmaf(a2, b1, acc[2][1]);
            acc[2][2] = fmaf(a2, b2, acc[2][2]); acc[2][3] = fmaf(a2, b3, acc[2][3]);
            acc[3][0] = fmaf(a3, b0, acc[3][0]); acc[3][1] = fmaf(a3, b1, acc[3][1]);
            acc[3][2] = fmaf(a3, b2, acc[3][2]); acc[3][3] = fmaf(a3, b3, acc[3][3]);
        }
        __syncthreads();
    }
#pragma unroll
    for (int i = 0; i < 4; ++i) {
        int r = bm + tr * 4 + i;
        if (r < N) {
            float4 o4 = make_float4(acc[i][0], acc[i][1], acc[i][2], acc[i][3]);
            *(float4*)(C + (size_t)r * M + bn + tc * 4) = o4;
        }
    }
}

// ---------------- GAT edge-softmax + aggregation (one wave per dst) ----------------
// D = H*C must be a multiple of 64.
template <int H, int C>
__global__ __launch_bounds__(256) void gat_aggregate(
    const float* __restrict__ hs,    // [Ns, H*C] source features to aggregate
    const float* __restrict__ es,    // [Ns, H] source logits
    const float* __restrict__ ed,    // [Nd, H] dst logits
    const int* __restrict__ rowptr,  // [Nd+1]
    const int* __restrict__ perm,    // [E] edge ids sorted by dst
    const int* __restrict__ esrc,    // [E] src node per edge
    const float* __restrict__ bias,  // [H*C]
    float* __restrict__ out,         // [Nd, H*C]
    int Nd, int do_relu) {
    constexpr int D = H * C;
    constexpr int RP = D / 64;
    constexpr int SLOTS = 64 / H;
    int wid = (blockIdx.x * 256 + threadIdx.x) >> 6;
    int lane = threadIdx.x & 63;
    if (wid >= Nd) return;
    int r0 = rowptr[wid], r1 = rowptr[wid + 1];
    int hm = lane & (H - 1);
    int slot = lane / H;
    float edv = ed[(size_t)wid * H + hm];

    // pass 1: per-head max
    float mx = -1e30f;
    for (int i = r0 + slot; i < r1; i += SLOTS) {
        int s = esrc[perm[i]];
        float x = es[(size_t)s * H + hm] + edv;
        x = x > 0.f ? x : 0.2f * x;
        mx = fmaxf(mx, x);
    }
#pragma unroll
    for (int off = H; off < 64; off <<= 1) mx = fmaxf(mx, __shfl_xor(mx, off, 64));

    // pass 2: per-head sum of exp
    float ssum = 0.f;
    for (int i = r0 + slot; i < r1; i += SLOTS) {
        int s = esrc[perm[i]];
        float x = es[(size_t)s * H + hm] + edv;
        x = x > 0.f ? x : 0.2f * x;
        ssum += __expf(x - mx);
    }
#pragma unroll
    for (int off = H; off < 64; off <<= 1) ssum += __shfl_xor(ssum, off, 64);
    float inv = 1.f / (ssum + 1e-16f);

    // pass 3: weighted accumulation (lanes 0..H-1 hold alpha for head==lane)
    float acc[RP];
#pragma unroll
    for (int t = 0; t < RP; ++t) acc[t] = 0.f;
    for (int i = r0; i < r1; ++i) {
        int s = esrc[perm[i]];
        float am = 0.f;
        if (lane < H) {
            float x = es[(size_t)s * H + lane] + edv;
            x = x > 0.f ? x : 0.2f * x;
            am = __expf(x - mx) * inv;
        }
        const float* hr = hs + (size_t)s * D;
#pragma unroll
        for (int t = 0; t < RP; ++t) {
            int hh = (lane + 64 * t) / C;
            float alpha = __shfl(am, hh, 64);
            acc[t] = fmaf(hr[lane + 64 * t], alpha, acc[t]);
        }
    }
#pragma unroll
    for (int t = 0; t < RP; ++t) {
        float v = acc[t] + bias[lane + 64 * t];
        if (do_relu) v = fmaxf(v, 0.f);
        out[(size_t)wid * D + lane + 64 * t] = v;
    }
}

// ---------------- fused edge decoder (one wave per label edge) ----------------
// pu64/pm64: [N,64] per-head projected embeddings; h[j] = relu(sum_h(pu+pm)[h*16+j] + cj[j])
__global__ __launch_bounds__(256) void decoder_kernel(
    const float* __restrict__ pu64, const float* __restrict__ pm64,
    const int* __restrict__ lab_u, const int* __restrict__ lab_m,
    const float* __restrict__ cj, const float* __restrict__ dw2,
    const float* __restrict__ db2, float* __restrict__ out, int nE) {
    int wid = (blockIdx.x * 256 + threadIdx.x) >> 6;
    int lane = threadIdx.x & 63;
    if (wid >= nE) return;
    int u = lab_u[wid], m = lab_m[wid];
    float v = pu64[(size_t)u * 64 + lane] + pm64[(size_t)m * 64 + lane];
    v += __shfl_xor(v, 16, 64);
    v += __shfl_xor(v, 32, 64);   // lanes sharing j = lane&15 now hold sum over 4 heads
    float r = 0.f;
    if (lane < 16) r = fmaxf(v + cj[lane], 0.f) * dw2[lane];
#pragma unroll
    for (int off = 1; off < 64; off <<= 1) r += __shfl_xor(r, off, 64);
    if (lane == 0) out[wid] = r + db2[0];
}

// ---------------- host ----------------

extern "C" void kernel_launch(void* const* d_in, const int* in_sizes, int n_in,
                              void* d_out, int out_size, void* d_ws, size_t ws_size,
                              hipStream_t stream) {
    const float* xu = (const float*)d_in[0];
    const float* xm = (const float*)d_in[1];
    const int* um_src = (const int*)d_in[2];
    const int* um_dst = (const int*)d_in[3];
    const int* mu_src = (const int*)d_in[4];
    const int* mu_dst = (const int*)d_in[5];
    const int* lab_u = (const int*)d_in[6];
    const int* lab_m = (const int*)d_in[7];
    const float* w1um_s = (const float*)d_in[8];
    const float* w1um_d = (const float*)d_in[9];
    const float* a1um_s = (const float*)d_in[10];
    const float* a1um_d = (const float*)d_in[11];
    const float* b1um = (const float*)d_in[12];
    const float* w1mu_s = (const float*)d_in[13];
    const float* w1mu_d = (const float*)d_in[14];
    const float* a1mu_s = (const float*)d_in[15];
    const float* a1mu_d = (const float*)d_in[16];
    const float* b1mu = (const float*)d_in[17];
    const float* w2um_s = (const float*)d_in[18];
    const float* w2um_d = (const float*)d_in[19];
    const float* a2um_s = (const float*)d_in[20];
    const float* a2um_d = (const float*)d_in[21];
    const float* b2um = (const float*)d_in[22];
    const float* w2mu_s = (const float*)d_in[23];
    const float* w2mu_d = (const float*)d_in[24];
    const float* a2mu_s = (const float*)d_in[25];
    const float* a2mu_d = (const float*)d_in[26];
    const float* b2mu = (const float*)d_in[27];
    const float* dw1 = (const float*)d_in[28];
    const float* db1 = (const float*)d_in[29];
    const float* dw2 = (const float*)d_in[30];
    const float* db2 = (const float*)d_in[31];
    float* out = (float*)d_out;

    // -------- workspace layout (floats) --------
    float* ws = (float*)d_ws;
    size_t o = 0;
    float* zm   = ws + o; o += (size_t)NM_ * D1_;   // 2.56M
    float* zu   = ws + o; o += (size_t)NU_ * D1_;   // 12.8M
    float* hs1  = ws + o; o += (size_t)NU_ * D1_;   // 12.8M (layer-1 staging, reused)
    float* esb  = ws + o; o += (size_t)NU_ * H1_;   // 0.8M
    float* edb  = ws + o; o += (size_t)NU_ * H1_;   // 0.8M
    float* q2um = ws + o; o += (size_t)NU_ * 64;    // 6.4M
    float* q2mu = ws + o; o += (size_t)NM_ * 64;    // 1.28M
    float* pu64 = ws + o; o += (size_t)NU_ * 64;    // 6.4M
    float* pm64 = ws + o; o += (size_t)NM_ * 64;    // 1.28M
    float* zero64 = ws + o; o += 64;
    float* cj   = ws + o; o += 16;
    float* vS   = ws + o; o += 1024;
    float* vD   = ws + o; o += 1024;
    float* wpU  = ws + o; o += 128 * 64;            // W2um' (um source -> bottom half of dw1)
    float* wpM  = ws + o; o += 128 * 64;            // W2mu' (mu source -> top half of dw1)
    int* rp_um   = (int*)(ws + o);
    int* rp_mu   = rp_um + (NM_ + 1);
    int* perm_um = rp_mu + (NU_ + 1);
    int* perm_mu = perm_um + NE_;
    int* ofs     = perm_mu + NE_;
    size_t need = o * sizeof(float) +
                  (size_t)(NM_ + 1 + NU_ + 1 + NE_ + NE_ + NU_ + 1) * sizeof(int);
    if (ws_size < need) {
        fprintf(stderr, "kernel_launch: ws too small (%zu < %zu)\n", ws_size, need);
        return;
    }

    const int TB = 256;

    // -------- CSR for both directions --------
    hipMemsetAsync(ofs, 0, NM_ * sizeof(int), stream);
    count_dst<<<cdiv_i(NE_, TB), TB, 0, stream>>>(um_dst, ofs, NE_);
    exscan_kernel<<<1, 1024, 0, stream>>>(ofs, rp_um, NM_);
    copy_i32<<<cdiv_i(NM_, TB), TB, 0, stream>>>(rp_um, ofs, NM_);
    fill_perm<<<cdiv_i(NE_, TB), TB, 0, stream>>>(um_dst, ofs, perm_um, NE_);

    hipMemsetAsync(ofs, 0, NU_ * sizeof(int), stream);
    count_dst<<<cdiv_i(NE_, TB), TB, 0, stream>>>(mu_dst, ofs, NE_);
    exscan_kernel<<<1, 1024, 0, stream>>>(ofs, rp_mu, NU_);
    copy_i32<<<cdiv_i(NU_, TB), TB, 0, stream>>>(rp_mu, ofs, NU_);
    fill_perm<<<cdiv_i(NE_, TB), TB, 0, stream>>>(mu_dst, ofs, perm_mu, NE_);

    hipMemsetAsync(zero64, 0, 64 * sizeof(float), stream);

    // -------- layer 1, um (user -> movie): zm --------
    gemm_f32<<<dim3(D1_ / 64, cdiv_i(NU_, 64)), TB, 0, stream>>>(xu, w1um_s, hs1, NU_, FU_, D1_);
    fold_a<<<cdiv_i(FU_ * H1_, TB), TB, 0, stream>>>(w1um_s, a1um_s, vS, FU_, H1_, C1_);
    node_logits<H1_><<<cdiv_i(NU_, 4), TB, 0, stream>>>(xu, vS, esb, NU_, FU_);
    fold_a<<<cdiv_i(FM_ * H1_, TB), TB, 0, stream>>>(w1um_d, a1um_d, vD, FM_, H1_, C1_);
    node_logits<H1_><<<cdiv_i(NM_, 4), TB, 0, stream>>>(xm, vD, edb, NM_, FM_);
    gat_aggregate<H1_, C1_><<<cdiv_i(NM_, 4), TB, 0, stream>>>(
        hs1, esb, edb, rp_um, perm_um, um_src, b1um, zm, NM_, 1);

    // -------- layer 1, mu (movie -> user): zu --------
    gemm_f32<<<dim3(D1_ / 64, cdiv_i(NM_, 64)), TB, 0, stream>>>(xm, w1mu_s, hs1, NM_, FM_, D1_);
    fold_a<<<cdiv_i(FM_ * H1_, TB), TB, 0, stream>>>(w1mu_s, a1mu_s, vS, FM_, H1_, C1_);
    node_logits<H1_><<<cdiv_i(NM_, 4), TB, 0, stream>>>(xm, vS, esb, NM_, FM_);
    fold_a<<<cdiv_i(FU_ * H1_, TB), TB, 0, stream>>>(w1mu_d, a1mu_d, vD, FU_, H1_, C1_);
    node_logits<H1_><<<cdiv_i(NU_, 4), TB, 0, stream>>>(xu, vD, edb, NU_, FU_);
    gat_aggregate<H1_, C1_><<<cdiv_i(NU_, 4), TB, 0, stream>>>(
        hs1, esb, edb, rp_mu, perm_mu, mu_src, b1mu, zu, NU_, 1);

    // -------- layer 2 folded: project through dw1, aggregate 64-wide --------
    // zu2 occupies rows [0:512) of dw1 (top), zm2 rows [512:1024) (bottom)
    fold_w2<<<cdiv_i(128 * 64, TB), TB, 0, stream>>>(w2um_s, dw1, 512, wpU);
    fold_w2<<<cdiv_i(128 * 64, TB), TB, 0, stream>>>(w2mu_s, dw1, 0, wpM);
    fold_cj<<<1, 64, 0, stream>>>(b2mu, b2um, dw1, db1, cj);

    gemm_f32<<<dim3(1, cdiv_i(NU_, 64)), TB, 0, stream>>>(zu, wpU, q2um, NU_, D1_, 64);
    gemm_f32<<<dim3(1, cdiv_i(NM_, 64)), TB, 0, stream>>>(zm, wpM, q2mu, NM_, D1_, 64);

    // um direction -> pm64 (movie side)
    fold_a<<<cdiv_i(D1_ * H2_, TB), TB, 0, stream>>>(w2um_s, a2um_s, vS, D1_, H2_, C2_);
    node_logits<H2_><<<cdiv_i(NU_, 4), TB, 0, stream>>>(zu, vS, esb, NU_, D1_);
    fold_a<<<cdiv_i(D1_ * H2_, TB), TB, 0, stream>>>(w2um_d, a2um_d, vD, D1_, H2_, C2_);
    node_logits<H2_><<<cdiv_i(NM_, 4), TB, 0, stream>>>(zm, vD, edb, NM_, D1_);
    gat_aggregate<H2_, 16><<<cdiv_i(NM_, 4), TB, 0, stream>>>(
        q2um, esb, edb, rp_um, perm_um, um_src, zero64, pm64, NM_, 0);

    // mu direction -> pu64 (user side)
    fold_a<<<cdiv_i(D1_ * H2_, TB), TB, 0, stream>>>(w2mu_s, a2mu_s, vS, D1_, H2_, C2_);
    node_logits<H2_><<<cdiv_i(NM_, 4), TB, 0, stream>>>(zm, vS, esb, NM_, D1_);
    fold_a<<<cdiv_i(D1_ * H2_, TB), TB, 0, stream>>>(w2mu_d, a2mu_d, vD, D1_, H2_, C2_);
    node_logits<H2_><<<cdiv_i(NU_, 4), TB, 0, stream>>>(zu, vD, edb, NU_, D1_);
    gat_aggregate<H2_, 16><<<cdiv_i(NU_, 4), TB, 0, stream>>>(
        q2mu, esb, edb, rp_mu, perm_mu, mu_src, zero64, pu64, NU_, 0);

    // -------- decoder --------
    decoder_kernel<<<cdiv_i(EL_, 4), TB, 0, stream>>>(
        pu64, pm64, lab_u, lab_m, cj, dw2, db2, out, EL_);
}

// Round 3
// 814.713 us; speedup vs baseline: 1.1939x; 1.1939x over previous
//
#include <hip/hip_runtime.h>
#include <hip/hip_bf16.h>
#include <cstdio>

#define NU_ 100000
#define NM_ 20000
#define FU_ 32
#define FM_ 128
#define H1_ 8
#define C1_ 16
#define D1_ 128
#define H2_ 4
#define C2_ 128
#define D2_ 512
#define NE_ 250000
#define EL_ 200000
#define SCHUNK 2048

static inline int cdiv_i(int a, int b) { return (a + b - 1) / b; }

// ---------------- CSR build ----------------

__global__ void copy_i32(const int* __restrict__ a, int* __restrict__ b, int n) {
    int i = blockIdx.x * blockDim.x + threadIdx.x;
    if (i < n) b[i] = a[i];
}

__global__ void count_dst(const int* __restrict__ dst, int* __restrict__ cnt, int E) {
    int i = blockIdx.x * blockDim.x + threadIdx.x;
    if (i < E) atomicAdd(&cnt[dst[i]], 1);
}

__global__ void fill_perm(const int* __restrict__ dst, int* __restrict__ ofs,
                          int* __restrict__ perm, int E) {
    int i = blockIdx.x * blockDim.x + threadIdx.x;
    if (i < E) {
        int p = atomicAdd(&ofs[dst[i]], 1);
        perm[p] = i;
    }
}

// ---------------- 3-phase exclusive scan ----------------

__global__ __launch_bounds__(256) void scan_phaseA(const int* __restrict__ in,
                                                   int* __restrict__ partial, int n) {
    __shared__ int red[256];
    int b = blockIdx.x, tid = threadIdx.x;
    int base = b * SCHUNK + tid * 8;
    int s = 0;
#pragma unroll
    for (int j = 0; j < 8; ++j) { int i = base + j; if (i < n) s += in[i]; }
    red[tid] = s;
    __syncthreads();
    for (int off = 128; off; off >>= 1) {
        if (tid < off) red[tid] += red[tid + off];
        __syncthreads();
    }
    if (tid == 0) partial[b] = red[0];
}

__global__ void scan_phaseB(int* __restrict__ partial, int nb, int* __restrict__ rp, int n) {
    if (threadIdx.x == 0 && blockIdx.x == 0) {
        int run = 0;
        for (int i = 0; i < nb; ++i) { int v = partial[i]; partial[i] = run; run += v; }
        rp[n] = run;
    }
}

__global__ __launch_bounds__(256) void scan_phaseC(const int* __restrict__ in,
                                                   const int* __restrict__ partial,
                                                   int* __restrict__ out, int n) {
    __shared__ int tsum[256];
    int b = blockIdx.x, tid = threadIdx.x;
    int base = b * SCHUNK + tid * 8;
    int v[8];
    int s = 0;
#pragma unroll
    for (int j = 0; j < 8; ++j) { int i = base + j; v[j] = (i < n) ? in[i] : 0; s += v[j]; }
    tsum[tid] = s;
    __syncthreads();
    for (int off = 1; off < 256; off <<= 1) {
        int y = (tid >= off) ? tsum[tid - off] : 0;
        __syncthreads();
        tsum[tid] += y;
        __syncthreads();
    }
    int run = partial[b] + tsum[tid] - s;
#pragma unroll
    for (int j = 0; j < 8; ++j) { int i = base + j; if (i < n) out[i] = run; run += v[j]; }
}

// ---------------- weight folding ----------------

// v[k,h] = sum_c W[k, h*C+c] * a[h,c]
__global__ void fold_a(const float* __restrict__ W, const float* __restrict__ a,
                       float* __restrict__ v, int K, int H, int C) {
    int i = blockIdx.x * blockDim.x + threadIdx.x;
    if (i >= K * H) return;
    int k = i / H, h = i % H;
    float s = 0.f;
    for (int c = 0; c < C; ++c) s += W[(size_t)k * (H * C) + h * C + c] * a[h * C + c];
    v[k * H + h] = s;
}

// wp[k, h*16+j] = sum_c W2s[k, h*128+c] * dw1[(rowoff + h*128 + c)*16 + j]
__global__ void fold_w2(const float* __restrict__ W2s, const float* __restrict__ dw1,
                        int rowoff, float* __restrict__ wp) {
    int i = blockIdx.x * blockDim.x + threadIdx.x;
    if (i >= 128 * 64) return;
    int k = i >> 6, hj = i & 63, h = hj >> 4, j = hj & 15;
    float s = 0.f;
    for (int c = 0; c < 128; ++c)
        s += W2s[(size_t)k * 512 + h * 128 + c] * dw1[(size_t)(rowoff + h * 128 + c) * 16 + j];
    wp[i] = s;
}

// cj[j] = db1[j] + sum_col b2mu[col]*dw1[col,j] + b2um[col]*dw1[512+col,j]
__global__ void fold_cj(const float* __restrict__ b2mu, const float* __restrict__ b2um,
                        const float* __restrict__ dw1, const float* __restrict__ db1,
                        float* __restrict__ cj) {
    int j = threadIdx.x;
    if (j >= 16) return;
    float s = db1[j];
    for (int col = 0; col < 512; ++col)
        s += b2mu[col] * dw1[col * 16 + j] + b2um[col] * dw1[(512 + col) * 16 + j];
    cj[j] = s;
}

// per-node logits: out[n,h] = sum_k X[n,k] * v[k,h]   (one wave per node)
template <int H>
__global__ __launch_bounds__(256) void node_logits(const float* __restrict__ X,
                                                   const float* __restrict__ v,
                                                   float* __restrict__ out, int N, int K) {
    int wid = (blockIdx.x * 256 + threadIdx.x) >> 6;
    int lane = threadIdx.x & 63;
    if (wid >= N) return;
    float p[H];
#pragma unroll
    for (int h = 0; h < H; ++h) p[h] = 0.f;
    for (int k = lane; k < K; k += 64) {
        float x = X[(size_t)wid * K + k];
#pragma unroll
        for (int h = 0; h < H; ++h) p[h] += x * v[k * H + h];
    }
#pragma unroll
    for (int off = 32; off; off >>= 1)
#pragma unroll
        for (int h = 0; h < H; ++h) p[h] += __shfl_xor(p[h], off, 64);
    if (lane == 0) {
#pragma unroll
        for (int h = 0; h < H; ++h) out[(size_t)wid * H + h] = p[h];
    }
}

// ---------------- fp32 tiled GEMM: C = A[NxK] @ B[KxM], K%16==0, M%64==0 ----------------
__global__ __launch_bounds__(256) void gemm_f32(const float* __restrict__ A,
                                                const float* __restrict__ B,
                                                float* __restrict__ C,
                                                int N, int K, int M) {
    __shared__ float As[16][65];
    __shared__ float Bs[16][64];
    int bm = blockIdx.y * 64;
    int bn = blockIdx.x * 64;
    int tid = threadIdx.x;
    int tr = tid >> 4, tc = tid & 15;
    float acc[4][4];
#pragma unroll
    for (int i = 0; i < 4; ++i)
#pragma unroll
        for (int j = 0; j < 4; ++j) acc[i][j] = 0.f;

    for (int k0 = 0; k0 < K; k0 += 16) {
        {
            int r = tid >> 2;
            int c4 = (tid & 3) * 4;
            int gr = bm + r;
            float4 v4 = make_float4(0.f, 0.f, 0.f, 0.f);
            if (gr < N) v4 = *(const float4*)(A + (size_t)gr * K + k0 + c4);
            As[c4 + 0][r] = v4.x;
            As[c4 + 1][r] = v4.y;
            As[c4 + 2][r] = v4.z;
            As[c4 + 3][r] = v4.w;
        }
        {
            int r = tid >> 4, c = tid & 15;
            float4 v4 = *(const float4*)(B + (size_t)(k0 + r) * M + bn + c * 4);
            *(float4*)&Bs[r][c * 4] = v4;
        }
        __syncthreads();
#pragma unroll
        for (int kk = 0; kk < 16; ++kk) {
            float a0 = As[kk][tr * 4 + 0], a1 = As[kk][tr * 4 + 1];
            float a2 = As[kk][tr * 4 + 2], a3 = As[kk][tr * 4 + 3];
            float b0 = Bs[kk][tc * 4 + 0], b1 = Bs[kk][tc * 4 + 1];
            float b2 = Bs[kk][tc * 4 + 2], b3 = Bs[kk][tc * 4 + 3];
            acc[0][0] = fmaf(a0, b0, acc[0][0]); acc[0][1] = fmaf(a0, b1, acc[0][1]);
            acc[0][2] = fmaf(a0, b2, acc[0][2]); acc[0][3] = fmaf(a0, b3, acc[0][3]);
            acc[1][0] = fmaf(a1, b0, acc[1][0]); acc[1][1] = fmaf(a1, b1, acc[1][1]);
            acc[1][2] = fmaf(a1, b2, acc[1][2]); acc[1][3] = fmaf(a1, b3, acc[1][3]);
            acc[2][0] = fmaf(a2, b0, acc[2][0]); acc[2][1] = fmaf(a2, b1, acc[2][1]);
            acc[2][2] = fmaf(a2, b2, acc[2][2]); acc[2][3] = fmaf(a2, b3, acc[2][3]);
            acc[3][0] = fmaf(a3, b0, acc[3][0]); acc[3][1] = fmaf(a3, b1, acc[3][1]);
            acc[3][2] = fmaf(a3, b2, acc[3][2]); acc[3][3] = fmaf(a3, b3, acc[3][3]);
        }
        __syncthreads();
    }
#pragma unroll
    for (int i = 0; i < 4; ++i) {
        int r = bm + tr * 4 + i;
        if (r < N) {
            float4 o4 = make_float4(acc[i][0], acc[i][1], acc[i][2], acc[i][3]);
            *(float4*)(C + (size_t)r * M + bn + tc * 4) = o4;
        }
    }
}

// ---------------- GAT edge-softmax + aggregation (one wave per dst) ----------------
// D = H*C must be a multiple of 64.
template <int H, int C>
__global__ __launch_bounds__(256) void gat_aggregate(
    const float* __restrict__ hs,    // [Ns, H*C] source features to aggregate
    const float* __restrict__ es,    // [Ns, H] source logits
    const float* __restrict__ ed,    // [Nd, H] dst logits
    const int* __restrict__ rowptr,  // [Nd+1]
    const int* __restrict__ perm,    // [E] edge ids sorted by dst
    const int* __restrict__ esrc,    // [E] src node per edge
    const float* __restrict__ bias,  // [H*C]
    float* __restrict__ out,         // [Nd, H*C]
    int Nd, int do_relu) {
    constexpr int D = H * C;
    constexpr int RP = D / 64;
    constexpr int SLOTS = 64 / H;
    int wid = (blockIdx.x * 256 + threadIdx.x) >> 6;
    int lane = threadIdx.x & 63;
    if (wid >= Nd) return;
    int r0 = rowptr[wid], r1 = rowptr[wid + 1];
    int hm = lane & (H - 1);
    int slot = lane / H;
    float edv = ed[(size_t)wid * H + hm];

    // pass 1: per-head max
    float mx = -1e30f;
    for (int i = r0 + slot; i < r1; i += SLOTS) {
        int s = esrc[perm[i]];
        float x = es[(size_t)s * H + hm] + edv;
        x = x > 0.f ? x : 0.2f * x;
        mx = fmaxf(mx, x);
    }
#pragma unroll
    for (int off = H; off < 64; off <<= 1) mx = fmaxf(mx, __shfl_xor(mx, off, 64));

    // pass 2: per-head sum of exp
    float ssum = 0.f;
    for (int i = r0 + slot; i < r1; i += SLOTS) {
        int s = esrc[perm[i]];
        float x = es[(size_t)s * H + hm] + edv;
        x = x > 0.f ? x : 0.2f * x;
        ssum += __expf(x - mx);
    }
#pragma unroll
    for (int off = H; off < 64; off <<= 1) ssum += __shfl_xor(ssum, off, 64);
    float inv = 1.f / (ssum + 1e-16f);

    // pass 3: weighted accumulation (lanes 0..H-1 hold alpha for head==lane)
    float acc[RP];
#pragma unroll
    for (int t = 0; t < RP; ++t) acc[t] = 0.f;
    for (int i = r0; i < r1; ++i) {
        int s = esrc[perm[i]];
        float am = 0.f;
        if (lane < H) {
            float x = es[(size_t)s * H + lane] + edv;
            x = x > 0.f ? x : 0.2f * x;
            am = __expf(x - mx) * inv;
        }
        const float* hr = hs + (size_t)s * D;
#pragma unroll
        for (int t = 0; t < RP; ++t) {
            int hh = (lane + 64 * t) / C;
            float alpha = __shfl(am, hh, 64);
            acc[t] = fmaf(hr[lane + 64 * t], alpha, acc[t]);
        }
    }
#pragma unroll
    for (int t = 0; t < RP; ++t) {
        float v = acc[t] + bias[lane + 64 * t];
        if (do_relu) v = fmaxf(v, 0.f);
        out[(size_t)wid * D + lane + 64 * t] = v;
    }
}

// ---------------- fused edge decoder (one wave per label edge) ----------------
__global__ __launch_bounds__(256) void decoder_kernel(
    const float* __restrict__ pu64, const float* __restrict__ pm64,
    const int* __restrict__ lab_u, const int* __restrict__ lab_m,
    const float* __restrict__ cj, const float* __restrict__ dw2,
    const float* __restrict__ db2, float* __restrict__ out, int nE) {
    int wid = (blockIdx.x * 256 + threadIdx.x) >> 6;
    int lane = threadIdx.x & 63;
    if (wid >= nE) return;
    int u = lab_u[wid], m = lab_m[wid];
    float v = pu64[(size_t)u * 64 + lane] + pm64[(size_t)m * 64 + lane];
    v += __shfl_xor(v, 16, 64);
    v += __shfl_xor(v, 32, 64);   // lanes sharing j = lane&15 now hold sum over 4 heads
    float r = 0.f;
    if (lane < 16) r = fmaxf(v + cj[lane], 0.f) * dw2[lane];
#pragma unroll
    for (int off = 1; off < 64; off <<= 1) r += __shfl_xor(r, off, 64);
    if (lane == 0) out[wid] = r + db2[0];
}

// ---------------- host ----------------

extern "C" void kernel_launch(void* const* d_in, const int* in_sizes, int n_in,
                              void* d_out, int out_size, void* d_ws, size_t ws_size,
                              hipStream_t stream) {
    const float* xu = (const float*)d_in[0];
    const float* xm = (const float*)d_in[1];
    const int* um_src = (const int*)d_in[2];
    const int* um_dst = (const int*)d_in[3];
    const int* mu_src = (const int*)d_in[4];
    const int* mu_dst = (const int*)d_in[5];
    const int* lab_u = (const int*)d_in[6];
    const int* lab_m = (const int*)d_in[7];
    const float* w1um_s = (const float*)d_in[8];
    const float* w1um_d = (const float*)d_in[9];
    const float* a1um_s = (const float*)d_in[10];
    const float* a1um_d = (const float*)d_in[11];
    const float* b1um = (const float*)d_in[12];
    const float* w1mu_s = (const float*)d_in[13];
    const float* w1mu_d = (const float*)d_in[14];
    const float* a1mu_s = (const float*)d_in[15];
    const float* a1mu_d = (const float*)d_in[16];
    const float* b1mu = (const float*)d_in[17];
    const float* w2um_s = (const float*)d_in[18];
    const float* w2um_d = (const float*)d_in[19];
    const float* a2um_s = (const float*)d_in[20];
    const float* a2um_d = (const float*)d_in[21];
    const float* b2um = (const float*)d_in[22];
    const float* w2mu_s = (const float*)d_in[23];
    const float* w2mu_d = (const float*)d_in[24];
    const float* a2mu_s = (const float*)d_in[25];
    const float* a2mu_d = (const float*)d_in[26];
    const float* b2mu = (const float*)d_in[27];
    const float* dw1 = (const float*)d_in[28];
    const float* db1 = (const float*)d_in[29];
    const float* dw2 = (const float*)d_in[30];
    const float* db2 = (const float*)d_in[31];
    float* out = (float*)d_out;

    // -------- workspace layout (floats) --------
    float* ws = (float*)d_ws;
    size_t o = 0;
    float* zm   = ws + o; o += (size_t)NM_ * D1_;
    float* zu   = ws + o; o += (size_t)NU_ * D1_;
    float* hs1  = ws + o; o += (size_t)NU_ * D1_;
    float* esb  = ws + o; o += (size_t)NU_ * H1_;
    float* edb  = ws + o; o += (size_t)NU_ * H1_;
    float* q2um = ws + o; o += (size_t)NU_ * 64;
    float* q2mu = ws + o; o += (size_t)NM_ * 64;
    float* pu64 = ws + o; o += (size_t)NU_ * 64;
    float* pm64 = ws + o; o += (size_t)NM_ * 64;
    float* zero64 = ws + o; o += 64;
    float* cj   = ws + o; o += 16;
    float* vS   = ws + o; o += 1024;
    float* vD   = ws + o; o += 1024;
    float* wpU  = ws + o; o += 128 * 64;
    float* wpM  = ws + o; o += 128 * 64;
    int* rp_um   = (int*)(ws + o);
    int* rp_mu   = rp_um + (NM_ + 1);
    int* perm_um = rp_mu + (NU_ + 1);
    int* perm_mu = perm_um + NE_;
    int* ofs     = perm_mu + NE_;
    int* partials = ofs + (NU_ + 1);
    size_t need = o * sizeof(float) +
                  (size_t)(NM_ + 1 + NU_ + 1 + NE_ + NE_ + NU_ + 1 + 64) * sizeof(int);
    if (ws_size < need) {
        fprintf(stderr, "kernel_launch: ws too small (%zu < %zu)\n", ws_size, need);
        return;
    }

    const int TB = 256;

    // -------- CSR for both directions (multi-block 3-phase scan) --------
    hipMemsetAsync(ofs, 0, NM_ * sizeof(int), stream);
    count_dst<<<cdiv_i(NE_, TB), TB, 0, stream>>>(um_dst, ofs, NE_);
    {
        int nb = cdiv_i(NM_, SCHUNK);
        scan_phaseA<<<nb, 256, 0, stream>>>(ofs, partials, NM_);
        scan_phaseB<<<1, 64, 0, stream>>>(partials, nb, rp_um, NM_);
        scan_phaseC<<<nb, 256, 0, stream>>>(ofs, partials, rp_um, NM_);
    }
    copy_i32<<<cdiv_i(NM_, TB), TB, 0, stream>>>(rp_um, ofs, NM_);
    fill_perm<<<cdiv_i(NE_, TB), TB, 0, stream>>>(um_dst, ofs, perm_um, NE_);

    hipMemsetAsync(ofs, 0, NU_ * sizeof(int), stream);
    count_dst<<<cdiv_i(NE_, TB), TB, 0, stream>>>(mu_dst, ofs, NE_);
    {
        int nb = cdiv_i(NU_, SCHUNK);
        scan_phaseA<<<nb, 256, 0, stream>>>(ofs, partials, NU_);
        scan_phaseB<<<1, 64, 0, stream>>>(partials, nb, rp_mu, NU_);
        scan_phaseC<<<nb, 256, 0, stream>>>(ofs, partials, rp_mu, NU_);
    }
    copy_i32<<<cdiv_i(NU_, TB), TB, 0, stream>>>(rp_mu, ofs, NU_);
    fill_perm<<<cdiv_i(NE_, TB), TB, 0, stream>>>(mu_dst, ofs, perm_mu, NE_);

    hipMemsetAsync(zero64, 0, 64 * sizeof(float), stream);

    // -------- layer 1, um (user -> movie): zm --------
    gemm_f32<<<dim3(D1_ / 64, cdiv_i(NU_, 64)), TB, 0, stream>>>(xu, w1um_s, hs1, NU_, FU_, D1_);
    fold_a<<<cdiv_i(FU_ * H1_, TB), TB, 0, stream>>>(w1um_s, a1um_s, vS, FU_, H1_, C1_);
    node_logits<H1_><<<cdiv_i(NU_, 4), TB, 0, stream>>>(xu, vS, esb, NU_, FU_);
    fold_a<<<cdiv_i(FM_ * H1_, TB), TB, 0, stream>>>(w1um_d, a1um_d, vD, FM_, H1_, C1_);
    node_logits<H1_><<<cdiv_i(NM_, 4), TB, 0, stream>>>(xm, vD, edb, NM_, FM_);
    gat_aggregate<H1_, C1_><<<cdiv_i(NM_, 4), TB, 0, stream>>>(
        hs1, esb, edb, rp_um, perm_um, um_src, b1um, zm, NM_, 1);

    // -------- layer 1, mu (movie -> user): zu --------
    gemm_f32<<<dim3(D1_ / 64, cdiv_i(NM_, 64)), TB, 0, stream>>>(xm, w1mu_s, hs1, NM_, FM_, D1_);
    fold_a<<<cdiv_i(FM_ * H1_, TB), TB, 0, stream>>>(w1mu_s, a1mu_s, vS, FM_, H1_, C1_);
    node_logits<H1_><<<cdiv_i(NM_, 4), TB, 0, stream>>>(xm, vS, esb, NM_, FM_);
    fold_a<<<cdiv_i(FU_ * H1_, TB), TB, 0, stream>>>(w1mu_d, a1mu_d, vD, FU_, H1_, C1_);
    node_logits<H1_><<<cdiv_i(NU_, 4), TB, 0, stream>>>(xu, vD, edb, NU_, FU_);
    gat_aggregate<H1_, C1_><<<cdiv_i(NU_, 4), TB, 0, stream>>>(
        hs1, esb, edb, rp_mu, perm_mu, mu_src, b1mu, zu, NU_, 1);

    // -------- layer 2 folded: project through dw1, aggregate 64-wide --------
    fold_w2<<<cdiv_i(128 * 64, TB), TB, 0, stream>>>(w2um_s, dw1, 512, wpU);
    fold_w2<<<cdiv_i(128 * 64, TB), TB, 0, stream>>>(w2mu_s, dw1, 0, wpM);
    fold_cj<<<1, 64, 0, stream>>>(b2mu, b2um, dw1, db1, cj);

    gemm_f32<<<dim3(1, cdiv_i(NU_, 64)), TB, 0, stream>>>(zu, wpU, q2um, NU_, D1_, 64);
    gemm_f32<<<dim3(1, cdiv_i(NM_, 64)), TB, 0, stream>>>(zm, wpM, q2mu, NM_, D1_, 64);

    // um direction -> pm64 (movie side)
    fold_a<<<cdiv_i(D1_ * H2_, TB), TB, 0, stream>>>(w2um_s, a2um_s, vS, D1_, H2_, C2_);
    node_logits<H2_><<<cdiv_i(NU_, 4), TB, 0, stream>>>(zu, vS, esb, NU_, D1_);
    fold_a<<<cdiv_i(D1_ * H2_, TB), TB, 0, stream>>>(w2um_d, a2um_d, vD, D1_, H2_, C2_);
    node_logits<H2_><<<cdiv_i(NM_, 4), TB, 0, stream>>>(zm, vD, edb, NM_, D1_);
    gat_aggregate<H2_, 16><<<cdiv_i(NM_, 4), TB, 0, stream>>>(
        q2um, esb, edb, rp_um, perm_um, um_src, zero64, pm64, NM_, 0);

    // mu direction -> pu64 (user side)
    fold_a<<<cdiv_i(D1_ * H2_, TB), TB, 0, stream>>>(w2mu_s, a2mu_s, vS, D1_, H2_, C2_);
    node_logits<H2_><<<cdiv_i(NM_, 4), TB, 0, stream>>>(zm, vS, esb, NM_, D1_);
    fold_a<<<cdiv_i(D1_ * H2_, TB), TB, 0, stream>>>(w2mu_d, a2mu_d, vD, D1_, H2_, C2_);
    node_logits<H2_><<<cdiv_i(NU_, 4), TB, 0, stream>>>(zu, vD, edb, NU_, D1_);
    gat_aggregate<H2_, 16><<<cdiv_i(NU_, 4), TB, 0, stream>>>(
        q2mu, esb, edb, rp_mu, perm_mu, mu_src, zero64, pu64, NU_, 0);

    // -------- decoder --------
    decoder_kernel<<<cdiv_i(EL_, 4), TB, 0, stream>>>(
        pu64, pm64, lab_u, lab_m, cj, dw2, db2, out, EL_);
}

// Round 4
// 684.628 us; speedup vs baseline: 1.4207x; 1.1900x over previous
//
#include <hip/hip_runtime.h>
#include <hip/hip_bf16.h>
#include <cstdio>

#define NU_ 100000
#define NM_ 20000
#define FU_ 32
#define FM_ 128
#define H1_ 8
#define C1_ 16
#define D1_ 128
#define H2_ 4
#define C2_ 128
#define D2_ 512
#define NE_ 250000
#define EL_ 200000
#define SCHUNK 2048

static inline int cdiv_i(int a, int b) { return (a + b - 1) / b; }

// ---------------- CSR build ----------------

__global__ void copy_i32(const int* __restrict__ a, int* __restrict__ b, int n) {
    int i = blockIdx.x * blockDim.x + threadIdx.x;
    if (i < n) b[i] = a[i];
}

__global__ void count_dst(const int* __restrict__ dst, int* __restrict__ cnt, int E) {
    int i = blockIdx.x * blockDim.x + threadIdx.x;
    if (i < E) atomicAdd(&cnt[dst[i]], 1);
}

// writes src and dst in dst-sorted order (no edge ids kept)
__global__ void fill_perm2(const int* __restrict__ dst, const int* __restrict__ src,
                           int* __restrict__ ofs, int* __restrict__ sdst,
                           int* __restrict__ ssrc, int E) {
    int i = blockIdx.x * blockDim.x + threadIdx.x;
    if (i < E) {
        int d = dst[i];
        int p = atomicAdd(&ofs[d], 1);
        ssrc[p] = src[i];
        sdst[p] = d;
    }
}

// ---------------- 3-phase exclusive scan ----------------

__global__ __launch_bounds__(256) void scan_phaseA(const int* __restrict__ in,
                                                   int* __restrict__ partial, int n) {
    __shared__ int red[256];
    int b = blockIdx.x, tid = threadIdx.x;
    int base = b * SCHUNK + tid * 8;
    int s = 0;
#pragma unroll
    for (int j = 0; j < 8; ++j) { int i = base + j; if (i < n) s += in[i]; }
    red[tid] = s;
    __syncthreads();
    for (int off = 128; off; off >>= 1) {
        if (tid < off) red[tid] += red[tid + off];
        __syncthreads();
    }
    if (tid == 0) partial[b] = red[0];
}

__global__ void scan_phaseB(int* __restrict__ partial, int nb, int* __restrict__ rp, int n) {
    if (threadIdx.x == 0 && blockIdx.x == 0) {
        int run = 0;
        for (int i = 0; i < nb; ++i) { int v = partial[i]; partial[i] = run; run += v; }
        rp[n] = run;
    }
}

__global__ __launch_bounds__(256) void scan_phaseC(const int* __restrict__ in,
                                                   const int* __restrict__ partial,
                                                   int* __restrict__ out, int n) {
    __shared__ int tsum[256];
    int b = blockIdx.x, tid = threadIdx.x;
    int base = b * SCHUNK + tid * 8;
    int v[8];
    int s = 0;
#pragma unroll
    for (int j = 0; j < 8; ++j) { int i = base + j; v[j] = (i < n) ? in[i] : 0; s += v[j]; }
    tsum[tid] = s;
    __syncthreads();
    for (int off = 1; off < 256; off <<= 1) {
        int y = (tid >= off) ? tsum[tid - off] : 0;
        __syncthreads();
        tsum[tid] += y;
        __syncthreads();
    }
    int run = partial[b] + tsum[tid] - s;
#pragma unroll
    for (int j = 0; j < 8; ++j) { int i = base + j; if (i < n) out[i] = run; run += v[j]; }
}

// ---------------- weight folding ----------------

__global__ void fold_a(const float* __restrict__ W, const float* __restrict__ a,
                       float* __restrict__ v, int K, int H, int C) {
    int i = blockIdx.x * blockDim.x + threadIdx.x;
    if (i >= K * H) return;
    int k = i / H, h = i % H;
    float s = 0.f;
    for (int c = 0; c < C; ++c) s += W[(size_t)k * (H * C) + h * C + c] * a[h * C + c];
    v[k * H + h] = s;
}

__global__ void fold_w2(const float* __restrict__ W2s, const float* __restrict__ dw1,
                        int rowoff, float* __restrict__ wp) {
    int i = blockIdx.x * blockDim.x + threadIdx.x;
    if (i >= 128 * 64) return;
    int k = i >> 6, hj = i & 63, h = hj >> 4, j = hj & 15;
    float s = 0.f;
    for (int c = 0; c < 128; ++c)
        s += W2s[(size_t)k * 512 + h * 128 + c] * dw1[(size_t)(rowoff + h * 128 + c) * 16 + j];
    wp[i] = s;
}

__global__ void fold_cj(const float* __restrict__ b2mu, const float* __restrict__ b2um,
                        const float* __restrict__ dw1, const float* __restrict__ db1,
                        float* __restrict__ cj) {
    int j = threadIdx.x;
    if (j >= 16) return;
    float s = db1[j];
    for (int col = 0; col < 512; ++col)
        s += b2mu[col] * dw1[col * 16 + j] + b2um[col] * dw1[(512 + col) * 16 + j];
    cj[j] = s;
}

// dual per-node logits: one wave per node, two weight vectors at once
template <int H>
__global__ __launch_bounds__(256) void node_logits_dual(
    const float* __restrict__ X, const float* __restrict__ vA, const float* __restrict__ vB,
    float* __restrict__ outA, float* __restrict__ outB, int N, int K) {
    int wid = (blockIdx.x * 256 + threadIdx.x) >> 6;
    int lane = threadIdx.x & 63;
    if (wid >= N) return;
    float p[H], q[H];
#pragma unroll
    for (int h = 0; h < H; ++h) { p[h] = 0.f; q[h] = 0.f; }
    for (int k = lane; k < K; k += 64) {
        float x = X[(size_t)wid * K + k];
#pragma unroll
        for (int h = 0; h < H; ++h) {
            p[h] += x * vA[k * H + h];
            q[h] += x * vB[k * H + h];
        }
    }
#pragma unroll
    for (int off = 32; off; off >>= 1)
#pragma unroll
        for (int h = 0; h < H; ++h) {
            p[h] += __shfl_xor(p[h], off, 64);
            q[h] += __shfl_xor(q[h], off, 64);
        }
    if (lane == 0) {
#pragma unroll
        for (int h = 0; h < H; ++h) {
            outA[(size_t)wid * H + h] = p[h];
            outB[(size_t)wid * H + h] = q[h];
        }
    }
}

// ---------------- edge weights: w[i,h] = exp(leaky(es[src,h] + ed[dst,h])) ----------------
template <int H>
__global__ __launch_bounds__(256) void edge_weights(
    const int* __restrict__ ssrc, const int* __restrict__ sdst,
    const float* __restrict__ es, const float* __restrict__ ed,
    float* __restrict__ w, int E) {
    constexpr int SH = (H == 8) ? 3 : 2;
    int t = blockIdx.x * 256 + threadIdx.x;
    if (t >= E * H) return;
    int i = t >> SH, h = t & (H - 1);
    int s = ssrc[i], d = sdst[i];
    float x = es[(size_t)s * H + h] + ed[(size_t)d * H + h];
    x = x > 0.f ? x : 0.2f * x;
    w[t] = __expf(x);
}

// ---------------- layer-1 aggregation: 128-wide, relu, H=8 C=16 ----------------
__global__ __launch_bounds__(256) void gat_agg_l1(
    const float* __restrict__ hs, const float* __restrict__ w,
    const int* __restrict__ rowptr, const int* __restrict__ ssrc,
    const float* __restrict__ bias, float* __restrict__ out, int Nd) {
    int wid = (blockIdx.x * 256 + threadIdx.x) >> 6;
    int lane = threadIdx.x & 63;
    if (wid >= Nd) return;
    int r0 = rowptr[wid], r1 = rowptr[wid + 1];
    int hm = lane & 7, slot = lane >> 3;  // 8 slots x 8 heads

    float ssum = 0.f;
    for (int i = r0 + slot; i < r1; i += 8) ssum += w[(size_t)i * 8 + hm];
#pragma unroll
    for (int off = 8; off < 64; off <<= 1) ssum += __shfl_xor(ssum, off, 64);
    float inv = 1.f / (ssum + 1e-16f);

    float acc0 = 0.f, acc1 = 0.f;
    int hh0 = lane >> 4, hh1 = 4 + (lane >> 4);
    for (int i = r0; i < r1; ++i) {
        int s = ssrc[i];
        float am = (lane < 8) ? w[(size_t)i * 8 + lane] * inv : 0.f;
        const float* hr = hs + (size_t)s * 128;
        float al0 = __shfl(am, hh0, 64);
        float al1 = __shfl(am, hh1, 64);
        acc0 = fmaf(hr[lane], al0, acc0);
        acc1 = fmaf(hr[lane + 64], al1, acc1);
    }
    float v0 = fmaxf(acc0 + bias[lane], 0.f);
    float v1 = fmaxf(acc1 + bias[lane + 64], 0.f);
    out[(size_t)wid * 128 + lane] = v0;
    out[(size_t)wid * 128 + lane + 64] = v1;
}

// ---------------- layer-2 aggregation: 64-wide in, head-summed 16-wide out, H=4 ----------------
__global__ __launch_bounds__(256) void gat_agg_l2(
    const float* __restrict__ q, const float* __restrict__ w,
    const int* __restrict__ rowptr, const int* __restrict__ ssrc,
    const float* __restrict__ bias16, float* __restrict__ out16, int Nd) {
    int wid = (blockIdx.x * 256 + threadIdx.x) >> 6;
    int lane = threadIdx.x & 63;
    if (wid >= Nd) return;
    int r0 = rowptr[wid], r1 = rowptr[wid + 1];
    int hm = lane & 3, slot = lane >> 2;  // 16 slots x 4 heads

    float ssum = 0.f;
    for (int i = r0 + slot; i < r1; i += 16) ssum += w[(size_t)i * 4 + hm];
#pragma unroll
    for (int off = 4; off < 64; off <<= 1) ssum += __shfl_xor(ssum, off, 64);
    float inv = 1.f / (ssum + 1e-16f);

    float acc = 0.f;
    int hh = lane >> 4;
    for (int i = r0; i < r1; ++i) {
        int s = ssrc[i];
        float am = (lane < 4) ? w[(size_t)i * 4 + lane] * inv : 0.f;
        float al = __shfl(am, hh, 64);
        acc = fmaf(q[(size_t)s * 64 + lane], al, acc);
    }
    acc += __shfl_xor(acc, 16, 64);
    acc += __shfl_xor(acc, 32, 64);
    if (lane < 16) out16[(size_t)wid * 16 + lane] = acc + bias16[lane];
}

// ---------------- fp32 tiled GEMM: C = A[NxK] @ B[KxM], K%16==0, M%64==0 ----------------
__global__ __launch_bounds__(256) void gemm_f32(const float* __restrict__ A,
                                                const float* __restrict__ B,
                                                float* __restrict__ C,
                                                int N, int K, int M) {
    __shared__ float As[16][65];
    __shared__ float Bs[16][64];
    int bm = blockIdx.y * 64;
    int bn = blockIdx.x * 64;
    int tid = threadIdx.x;
    int tr = tid >> 4, tc = tid & 15;
    float acc[4][4];
#pragma unroll
    for (int i = 0; i < 4; ++i)
#pragma unroll
        for (int j = 0; j < 4; ++j) acc[i][j] = 0.f;

    for (int k0 = 0; k0 < K; k0 += 16) {
        {
            int r = tid >> 2;
            int c4 = (tid & 3) * 4;
            int gr = bm + r;
            float4 v4 = make_float4(0.f, 0.f, 0.f, 0.f);
            if (gr < N) v4 = *(const float4*)(A + (size_t)gr * K + k0 + c4);
            As[c4 + 0][r] = v4.x;
            As[c4 + 1][r] = v4.y;
            As[c4 + 2][r] = v4.z;
            As[c4 + 3][r] = v4.w;
        }
        {
            int r = tid >> 4, c = tid & 15;
            float4 v4 = *(const float4*)(B + (size_t)(k0 + r) * M + bn + c * 4);
            *(float4*)&Bs[r][c * 4] = v4;
        }
        __syncthreads();
#pragma unroll
        for (int kk = 0; kk < 16; ++kk) {
            float a0 = As[kk][tr * 4 + 0], a1 = As[kk][tr * 4 + 1];
            float a2 = As[kk][tr * 4 + 2], a3 = As[kk][tr * 4 + 3];
            float b0 = Bs[kk][tc * 4 + 0], b1 = Bs[kk][tc * 4 + 1];
            float b2 = Bs[kk][tc * 4 + 2], b3 = Bs[kk][tc * 4 + 3];
            acc[0][0] = fmaf(a0, b0, acc[0][0]); acc[0][1] = fmaf(a0, b1, acc[0][1]);
            acc[0][2] = fmaf(a0, b2, acc[0][2]); acc[0][3] = fmaf(a0, b3, acc[0][3]);
            acc[1][0] = fmaf(a1, b0, acc[1][0]); acc[1][1] = fmaf(a1, b1, acc[1][1]);
            acc[1][2] = fmaf(a1, b2, acc[1][2]); acc[1][3] = fmaf(a1, b3, acc[1][3]);
            acc[2][0] = fmaf(a2, b0, acc[2][0]); acc[2][1] = fmaf(a2, b1, acc[2][1]);
            acc[2][2] = fmaf(a2, b2, acc[2][2]); acc[2][3] = fmaf(a2, b3, acc[2][3]);
            acc[3][0] = fmaf(a3, b0, acc[3][0]); acc[3][1] = fmaf(a3, b1, acc[3][1]);
            acc[3][2] = fmaf(a3, b2, acc[3][2]); acc[3][3] = fmaf(a3, b3, acc[3][3]);
        }
        __syncthreads();
    }
#pragma unroll
    for (int i = 0; i < 4; ++i) {
        int r = bm + tr * 4 + i;
        if (r < N) {
            float4 o4 = make_float4(acc[i][0], acc[i][1], acc[i][2], acc[i][3]);
            *(float4*)(C + (size_t)r * M + bn + tc * 4) = o4;
        }
    }
}

// ---------------- decoder: 16 lanes per label edge ----------------
__global__ __launch_bounds__(256) void decoder16(
    const float* __restrict__ pu16, const float* __restrict__ pm16,
    const int* __restrict__ lab_u, const int* __restrict__ lab_m,
    const float* __restrict__ dw2, const float* __restrict__ db2,
    float* __restrict__ out, int nE) {
    int t = blockIdx.x * 256 + threadIdx.x;
    int e = t >> 4, j = t & 15;
    if (e >= nE) return;
    int u = lab_u[e], m = lab_m[e];
    float v = pu16[(size_t)u * 16 + j] + pm16[(size_t)m * 16 + j];
    float r = fmaxf(v, 0.f) * dw2[j];
    r += __shfl_xor(r, 1, 16);
    r += __shfl_xor(r, 2, 16);
    r += __shfl_xor(r, 4, 16);
    r += __shfl_xor(r, 8, 16);
    if (j == 0) out[e] = r + db2[0];
}

// ---------------- host ----------------

extern "C" void kernel_launch(void* const* d_in, const int* in_sizes, int n_in,
                              void* d_out, int out_size, void* d_ws, size_t ws_size,
                              hipStream_t stream) {
    const float* xu = (const float*)d_in[0];
    const float* xm = (const float*)d_in[1];
    const int* um_src = (const int*)d_in[2];
    const int* um_dst = (const int*)d_in[3];
    const int* mu_src = (const int*)d_in[4];
    const int* mu_dst = (const int*)d_in[5];
    const int* lab_u = (const int*)d_in[6];
    const int* lab_m = (const int*)d_in[7];
    const float* w1um_s = (const float*)d_in[8];
    const float* w1um_d = (const float*)d_in[9];
    const float* a1um_s = (const float*)d_in[10];
    const float* a1um_d = (const float*)d_in[11];
    const float* b1um = (const float*)d_in[12];
    const float* w1mu_s = (const float*)d_in[13];
    const float* w1mu_d = (const float*)d_in[14];
    const float* a1mu_s = (const float*)d_in[15];
    const float* a1mu_d = (const float*)d_in[16];
    const float* b1mu = (const float*)d_in[17];
    const float* w2um_s = (const float*)d_in[18];
    const float* w2um_d = (const float*)d_in[19];
    const float* a2um_s = (const float*)d_in[20];
    const float* a2um_d = (const float*)d_in[21];
    const float* b2um = (const float*)d_in[22];
    const float* w2mu_s = (const float*)d_in[23];
    const float* w2mu_d = (const float*)d_in[24];
    const float* a2mu_s = (const float*)d_in[25];
    const float* a2mu_d = (const float*)d_in[26];
    const float* b2mu = (const float*)d_in[27];
    const float* dw1 = (const float*)d_in[28];
    const float* db1 = (const float*)d_in[29];
    const float* dw2 = (const float*)d_in[30];
    const float* db2 = (const float*)d_in[31];
    float* out = (float*)d_out;

    // -------- workspace layout (floats) --------
    float* ws = (float*)d_ws;
    size_t o = 0;
    float* zm    = ws + o; o += (size_t)NM_ * D1_;
    float* zu    = ws + o; o += (size_t)NU_ * D1_;
    float* hs1   = ws + o; o += (size_t)NU_ * D1_;
    float* q2um  = ws + o; o += (size_t)NU_ * 64;
    float* q2mu  = ws + o; o += (size_t)NM_ * 64;
    float* pu16  = ws + o; o += (size_t)NU_ * 16;
    float* pm16  = ws + o; o += (size_t)NM_ * 16;
    float* esU1  = ws + o; o += (size_t)NU_ * H1_;
    float* edU1  = ws + o; o += (size_t)NU_ * H1_;
    float* esM1  = ws + o; o += (size_t)NM_ * H1_;
    float* edM1  = ws + o; o += (size_t)NM_ * H1_;
    float* es2um = ws + o; o += (size_t)NU_ * H2_;
    float* ed2mu = ws + o; o += (size_t)NU_ * H2_;
    float* es2mu = ws + o; o += (size_t)NM_ * H2_;
    float* ed2um = ws + o; o += (size_t)NM_ * H2_;
    float* wbuf  = ws + o; o += (size_t)NE_ * H1_;   // reused for all 4 edge-weight sets
    float* zero16= ws + o; o += 16;
    float* cj    = ws + o; o += 16;
    float* vA1   = ws + o; o += 1024;
    float* vB1   = ws + o; o += 1024;
    float* vA2   = ws + o; o += 1024;
    float* vB2   = ws + o; o += 1024;
    float* vA3   = ws + o; o += 1024;
    float* vB3   = ws + o; o += 1024;
    float* vA4   = ws + o; o += 1024;
    float* vB4   = ws + o; o += 1024;
    float* wpU   = ws + o; o += 128 * 64;
    float* wpM   = ws + o; o += 128 * 64;
    int* rp_um    = (int*)(ws + o);
    int* rp_mu    = rp_um + (NM_ + 1);
    int* ssrc_um  = rp_mu + (NU_ + 1);
    int* sdst_um  = ssrc_um + NE_;
    int* ssrc_mu  = sdst_um + NE_;
    int* sdst_mu  = ssrc_mu + NE_;
    int* ofs      = sdst_mu + NE_;
    int* partials = ofs + (NU_ + 1);
    size_t need = o * sizeof(float) +
                  (size_t)(NM_ + 1 + NU_ + 1 + 4 * NE_ + NU_ + 1 + 64) * sizeof(int);
    if (ws_size < need) {
        fprintf(stderr, "kernel_launch: ws too small (%zu < %zu)\n", ws_size, need);
        return;
    }

    const int TB = 256;

    // -------- CSR (dst-sorted src/dst arrays) --------
    hipMemsetAsync(ofs, 0, NM_ * sizeof(int), stream);
    count_dst<<<cdiv_i(NE_, TB), TB, 0, stream>>>(um_dst, ofs, NE_);
    {
        int nb = cdiv_i(NM_, SCHUNK);
        scan_phaseA<<<nb, 256, 0, stream>>>(ofs, partials, NM_);
        scan_phaseB<<<1, 64, 0, stream>>>(partials, nb, rp_um, NM_);
        scan_phaseC<<<nb, 256, 0, stream>>>(ofs, partials, rp_um, NM_);
    }
    copy_i32<<<cdiv_i(NM_, TB), TB, 0, stream>>>(rp_um, ofs, NM_);
    fill_perm2<<<cdiv_i(NE_, TB), TB, 0, stream>>>(um_dst, um_src, ofs, sdst_um, ssrc_um, NE_);

    hipMemsetAsync(ofs, 0, NU_ * sizeof(int), stream);
    count_dst<<<cdiv_i(NE_, TB), TB, 0, stream>>>(mu_dst, ofs, NE_);
    {
        int nb = cdiv_i(NU_, SCHUNK);
        scan_phaseA<<<nb, 256, 0, stream>>>(ofs, partials, NU_);
        scan_phaseB<<<1, 64, 0, stream>>>(partials, nb, rp_mu, NU_);
        scan_phaseC<<<nb, 256, 0, stream>>>(ofs, partials, rp_mu, NU_);
    }
    copy_i32<<<cdiv_i(NU_, TB), TB, 0, stream>>>(rp_mu, ofs, NU_);
    fill_perm2<<<cdiv_i(NE_, TB), TB, 0, stream>>>(mu_dst, mu_src, ofs, sdst_mu, ssrc_mu, NE_);

    hipMemsetAsync(zero16, 0, 16 * sizeof(float), stream);

    // -------- layer-1 logits (dual: each X read once) --------
    fold_a<<<cdiv_i(FU_ * H1_, TB), TB, 0, stream>>>(w1um_s, a1um_s, vA1, FU_, H1_, C1_);
    fold_a<<<cdiv_i(FU_ * H1_, TB), TB, 0, stream>>>(w1mu_d, a1mu_d, vB1, FU_, H1_, C1_);
    node_logits_dual<H1_><<<cdiv_i(NU_, 4), TB, 0, stream>>>(xu, vA1, vB1, esU1, edU1, NU_, FU_);
    fold_a<<<cdiv_i(FM_ * H1_, TB), TB, 0, stream>>>(w1mu_s, a1mu_s, vA2, FM_, H1_, C1_);
    fold_a<<<cdiv_i(FM_ * H1_, TB), TB, 0, stream>>>(w1um_d, a1um_d, vB2, FM_, H1_, C1_);
    node_logits_dual<H1_><<<cdiv_i(NM_, 4), TB, 0, stream>>>(xm, vA2, vB2, esM1, edM1, NM_, FM_);

    // -------- layer 1, um (user -> movie): zm --------
    gemm_f32<<<dim3(D1_ / 64, cdiv_i(NU_, 64)), TB, 0, stream>>>(xu, w1um_s, hs1, NU_, FU_, D1_);
    edge_weights<H1_><<<cdiv_i(NE_ * H1_, TB), TB, 0, stream>>>(ssrc_um, sdst_um, esU1, edM1, wbuf, NE_);
    gat_agg_l1<<<cdiv_i(NM_, 4), TB, 0, stream>>>(hs1, wbuf, rp_um, ssrc_um, b1um, zm, NM_);

    // -------- layer 1, mu (movie -> user): zu --------
    gemm_f32<<<dim3(D1_ / 64, cdiv_i(NM_, 64)), TB, 0, stream>>>(xm, w1mu_s, hs1, NM_, FM_, D1_);
    edge_weights<H1_><<<cdiv_i(NE_ * H1_, TB), TB, 0, stream>>>(ssrc_mu, sdst_mu, esM1, edU1, wbuf, NE_);
    gat_agg_l1<<<cdiv_i(NU_, 4), TB, 0, stream>>>(hs1, wbuf, rp_mu, ssrc_mu, b1mu, zu, NU_);

    // -------- layer 2: fold dw1 through, project, aggregate head-summed --------
    fold_w2<<<cdiv_i(128 * 64, TB), TB, 0, stream>>>(w2um_s, dw1, 512, wpU);
    fold_w2<<<cdiv_i(128 * 64, TB), TB, 0, stream>>>(w2mu_s, dw1, 0, wpM);
    fold_cj<<<1, 64, 0, stream>>>(b2mu, b2um, dw1, db1, cj);

    gemm_f32<<<dim3(1, cdiv_i(NU_, 64)), TB, 0, stream>>>(zu, wpU, q2um, NU_, D1_, 64);
    gemm_f32<<<dim3(1, cdiv_i(NM_, 64)), TB, 0, stream>>>(zm, wpM, q2mu, NM_, D1_, 64);

    fold_a<<<cdiv_i(D1_ * H2_, TB), TB, 0, stream>>>(w2um_s, a2um_s, vA3, D1_, H2_, C2_);
    fold_a<<<cdiv_i(D1_ * H2_, TB), TB, 0, stream>>>(w2mu_d, a2mu_d, vB3, D1_, H2_, C2_);
    node_logits_dual<H2_><<<cdiv_i(NU_, 4), TB, 0, stream>>>(zu, vA3, vB3, es2um, ed2mu, NU_, D1_);
    fold_a<<<cdiv_i(D1_ * H2_, TB), TB, 0, stream>>>(w2mu_s, a2mu_s, vA4, D1_, H2_, C2_);
    fold_a<<<cdiv_i(D1_ * H2_, TB), TB, 0, stream>>>(w2um_d, a2um_d, vB4, D1_, H2_, C2_);
    node_logits_dual<H2_><<<cdiv_i(NM_, 4), TB, 0, stream>>>(zm, vA4, vB4, es2mu, ed2um, NM_, D1_);

    // um: src=user q2um -> movie pm16 (bias16 = cj)
    edge_weights<H2_><<<cdiv_i(NE_ * H2_, TB), TB, 0, stream>>>(ssrc_um, sdst_um, es2um, ed2um, wbuf, NE_);
    gat_agg_l2<<<cdiv_i(NM_, 4), TB, 0, stream>>>(q2um, wbuf, rp_um, ssrc_um, cj, pm16, NM_);
    // mu: src=movie q2mu -> user pu16 (bias16 = 0)
    edge_weights<H2_><<<cdiv_i(NE_ * H2_, TB), TB, 0, stream>>>(ssrc_mu, sdst_mu, es2mu, ed2mu, wbuf, NE_);
    gat_agg_l2<<<cdiv_i(NU_, 4), TB, 0, stream>>>(q2mu, wbuf, rp_mu, ssrc_mu, zero16, pu16, NU_);

    // -------- decoder --------
    decoder16<<<cdiv_i(EL_ * 16, TB), TB, 0, stream>>>(
        pu16, pm16, lab_u, lab_m, dw2, db2, out, EL_);
}

// Round 5
// 556.974 us; speedup vs baseline: 1.7463x; 1.2292x over previous
//
#include <hip/hip_runtime.h>
#include <hip/hip_bf16.h>
#include <cstdio>

#define NU_ 100000
#define NM_ 20000
#define FU_ 32
#define FM_ 128
#define H1_ 8
#define C1_ 16
#define D1_ 128
#define H2_ 4
#define C2_ 128
#define D2_ 512
#define NE_ 250000
#define EL_ 200000
#define SCHUNK 2048

static inline int cdiv_i(int a, int b) { return (a + b - 1) / b; }

// ---------------- CSR build ----------------

__global__ void copy_i32(const int* __restrict__ a, int* __restrict__ b, int n) {
    int i = blockIdx.x * blockDim.x + threadIdx.x;
    if (i < n) b[i] = a[i];
}

__global__ void count_dst(const int* __restrict__ dst, int* __restrict__ cnt, int E) {
    int i = blockIdx.x * blockDim.x + threadIdx.x;
    if (i < E) atomicAdd(&cnt[dst[i]], 1);
}

__global__ void fill_perm2(const int* __restrict__ dst, const int* __restrict__ src,
                           int* __restrict__ ofs, int* __restrict__ sdst,
                           int* __restrict__ ssrc, int E) {
    int i = blockIdx.x * blockDim.x + threadIdx.x;
    if (i < E) {
        int d = dst[i];
        int p = atomicAdd(&ofs[d], 1);
        ssrc[p] = src[i];
        sdst[p] = d;
    }
}

// ---------------- 3-phase exclusive scan ----------------

__global__ __launch_bounds__(256) void scan_phaseA(const int* __restrict__ in,
                                                   int* __restrict__ partial, int n) {
    __shared__ int red[256];
    int b = blockIdx.x, tid = threadIdx.x;
    int base = b * SCHUNK + tid * 8;
    int s = 0;
#pragma unroll
    for (int j = 0; j < 8; ++j) { int i = base + j; if (i < n) s += in[i]; }
    red[tid] = s;
    __syncthreads();
    for (int off = 128; off; off >>= 1) {
        if (tid < off) red[tid] += red[tid + off];
        __syncthreads();
    }
    if (tid == 0) partial[b] = red[0];
}

__global__ void scan_phaseB(int* __restrict__ partial, int nb, int* __restrict__ rp, int n) {
    if (threadIdx.x == 0 && blockIdx.x == 0) {
        int run = 0;
        for (int i = 0; i < nb; ++i) { int v = partial[i]; partial[i] = run; run += v; }
        rp[n] = run;
    }
}

__global__ __launch_bounds__(256) void scan_phaseC(const int* __restrict__ in,
                                                   const int* __restrict__ partial,
                                                   int* __restrict__ out, int n) {
    __shared__ int tsum[256];
    int b = blockIdx.x, tid = threadIdx.x;
    int base = b * SCHUNK + tid * 8;
    int v[8];
    int s = 0;
#pragma unroll
    for (int j = 0; j < 8; ++j) { int i = base + j; v[j] = (i < n) ? in[i] : 0; s += v[j]; }
    tsum[tid] = s;
    __syncthreads();
    for (int off = 1; off < 256; off <<= 1) {
        int y = (tid >= off) ? tsum[tid - off] : 0;
        __syncthreads();
        tsum[tid] += y;
        __syncthreads();
    }
    int run = partial[b] + tsum[tid] - s;
#pragma unroll
    for (int j = 0; j < 8; ++j) { int i = base + j; if (i < n) out[i] = run; run += v[j]; }
}

// ---------------- B-matrix builders ----------------

// B[k*stride + c] = W[k*128 + c]   (c in 0..127)
__global__ void copy_w_strided(const float* __restrict__ W, float* __restrict__ B,
                               int K, int stride) {
    int i = blockIdx.x * blockDim.x + threadIdx.x;
    if (i >= K * 128) return;
    int k = i >> 7, c = i & 127;
    B[(size_t)k * stride + c] = W[i];
}

// B[k*stride + coloff + h] = sum_c W[k, h*C+c] * a[h,c]
__global__ void fold_a_strided(const float* __restrict__ W, const float* __restrict__ a,
                               float* __restrict__ B, int K, int H, int C,
                               int coloff, int stride) {
    int i = blockIdx.x * blockDim.x + threadIdx.x;
    if (i >= K * H) return;
    int k = i / H, h = i % H;
    float s = 0.f;
    for (int c = 0; c < C; ++c) s += W[(size_t)k * (H * C) + h * C + c] * a[h * C + c];
    B[(size_t)k * stride + coloff + h] = s;
}

// B[k*stride + h*16+j] = sum_c W2s[k, h*128+c] * dw1[(rowoff + h*128 + c)*16 + j]
__global__ void fold_w2_strided(const float* __restrict__ W2s, const float* __restrict__ dw1,
                                int rowoff, float* __restrict__ B, int stride) {
    int i = blockIdx.x * blockDim.x + threadIdx.x;
    if (i >= 128 * 64) return;
    int k = i >> 6, hj = i & 63, h = hj >> 4, j = hj & 15;
    float s = 0.f;
    for (int c = 0; c < 128; ++c)
        s += W2s[(size_t)k * 512 + h * 128 + c] * dw1[(size_t)(rowoff + h * 128 + c) * 16 + j];
    B[(size_t)k * stride + hj] = s;
}

__global__ void fold_cj(const float* __restrict__ b2mu, const float* __restrict__ b2um,
                        const float* __restrict__ dw1, const float* __restrict__ db1,
                        float* __restrict__ cj) {
    int j = threadIdx.x;
    if (j >= 16) return;
    float s = db1[j];
    for (int col = 0; col < 512; ++col)
        s += b2mu[col] * dw1[col * 16 + j] + b2um[col] * dw1[(512 + col) * 16 + j];
    cj[j] = s;
}

// ---------------- edge weights: w[i,h] = exp(leaky(es[src,h] + ed[dst,h])) ----------------
template <int H>
__global__ __launch_bounds__(256) void edge_weights(
    const int* __restrict__ ssrc, const int* __restrict__ sdst,
    const float* __restrict__ es, const float* __restrict__ ed,
    int ses, int sed, float* __restrict__ w, int E) {
    constexpr int SH = (H == 8) ? 3 : 2;
    int t = blockIdx.x * 256 + threadIdx.x;
    if (t >= E * H) return;
    int i = t >> SH, h = t & (H - 1);
    int s = ssrc[i], d = sdst[i];
    float x = es[(size_t)s * ses + h] + ed[(size_t)d * sed + h];
    x = x > 0.f ? x : 0.2f * x;
    w[t] = __expf(x);
}

// ---------------- layer-1 aggregation: 128-wide, relu, H=8 C=16 ----------------
__global__ __launch_bounds__(256) void gat_agg_l1(
    const float* __restrict__ hs, int shs, const float* __restrict__ w,
    const int* __restrict__ rowptr, const int* __restrict__ ssrc,
    const float* __restrict__ bias, float* __restrict__ out, int Nd) {
    int wid = (blockIdx.x * 256 + threadIdx.x) >> 6;
    int lane = threadIdx.x & 63;
    if (wid >= Nd) return;
    int r0 = rowptr[wid], r1 = rowptr[wid + 1];
    int hm = lane & 7, slot = lane >> 3;

    float ssum = 0.f;
    for (int i = r0 + slot; i < r1; i += 8) ssum += w[(size_t)i * 8 + hm];
#pragma unroll
    for (int off = 8; off < 64; off <<= 1) ssum += __shfl_xor(ssum, off, 64);
    float inv = 1.f / (ssum + 1e-16f);

    float acc0 = 0.f, acc1 = 0.f;
    int hh0 = lane >> 4, hh1 = 4 + (lane >> 4);
    for (int i = r0; i < r1; ++i) {
        int s = ssrc[i];
        float am = (lane < 8) ? w[(size_t)i * 8 + lane] * inv : 0.f;
        const float* hr = hs + (size_t)s * shs;
        float al0 = __shfl(am, hh0, 64);
        float al1 = __shfl(am, hh1, 64);
        acc0 = fmaf(hr[lane], al0, acc0);
        acc1 = fmaf(hr[lane + 64], al1, acc1);
    }
    float v0 = fmaxf(acc0 + bias[lane], 0.f);
    float v1 = fmaxf(acc1 + bias[lane + 64], 0.f);
    out[(size_t)wid * 128 + lane] = v0;
    out[(size_t)wid * 128 + lane + 64] = v1;
}

// ---------------- layer-2 aggregation: 64-wide in (stride sq), head-summed 16-wide out ----------------
__global__ __launch_bounds__(256) void gat_agg_l2(
    const float* __restrict__ q, int sq, const float* __restrict__ w,
    const int* __restrict__ rowptr, const int* __restrict__ ssrc,
    const float* __restrict__ bias16, float* __restrict__ out16, int Nd) {
    int wid = (blockIdx.x * 256 + threadIdx.x) >> 6;
    int lane = threadIdx.x & 63;
    if (wid >= Nd) return;
    int r0 = rowptr[wid], r1 = rowptr[wid + 1];
    int hm = lane & 3, slot = lane >> 2;

    float ssum = 0.f;
    for (int i = r0 + slot; i < r1; i += 16) ssum += w[(size_t)i * 4 + hm];
#pragma unroll
    for (int off = 4; off < 64; off <<= 1) ssum += __shfl_xor(ssum, off, 64);
    float inv = 1.f / (ssum + 1e-16f);

    float acc = 0.f;
    int hh = lane >> 4;
    for (int i = r0; i < r1; ++i) {
        int s = ssrc[i];
        float am = (lane < 4) ? w[(size_t)i * 4 + lane] * inv : 0.f;
        float al = __shfl(am, hh, 64);
        acc = fmaf(q[(size_t)s * sq + lane], al, acc);
    }
    acc += __shfl_xor(acc, 16, 64);
    acc += __shfl_xor(acc, 32, 64);
    if (lane < 16) out16[(size_t)wid * 16 + lane] = acc + bias16[lane];
}

// ---------------- fp32 tiled GEMM: C = A[NxK] @ B[KxM], K%16==0, M%64==0 ----------------
__global__ __launch_bounds__(256) void gemm_f32(const float* __restrict__ A,
                                                const float* __restrict__ B,
                                                float* __restrict__ C,
                                                int N, int K, int M) {
    __shared__ float As[16][65];
    __shared__ float Bs[16][64];
    int bm = blockIdx.y * 64;
    int bn = blockIdx.x * 64;
    int tid = threadIdx.x;
    int tr = tid >> 4, tc = tid & 15;
    float acc[4][4];
#pragma unroll
    for (int i = 0; i < 4; ++i)
#pragma unroll
        for (int j = 0; j < 4; ++j) acc[i][j] = 0.f;

    for (int k0 = 0; k0 < K; k0 += 16) {
        {
            int r = tid >> 2;
            int c4 = (tid & 3) * 4;
            int gr = bm + r;
            float4 v4 = make_float4(0.f, 0.f, 0.f, 0.f);
            if (gr < N) v4 = *(const float4*)(A + (size_t)gr * K + k0 + c4);
            As[c4 + 0][r] = v4.x;
            As[c4 + 1][r] = v4.y;
            As[c4 + 2][r] = v4.z;
            As[c4 + 3][r] = v4.w;
        }
        {
            int r = tid >> 4, c = tid & 15;
            float4 v4 = *(const float4*)(B + (size_t)(k0 + r) * M + bn + c * 4);
            *(float4*)&Bs[r][c * 4] = v4;
        }
        __syncthreads();
#pragma unroll
        for (int kk = 0; kk < 16; ++kk) {
            float a0 = As[kk][tr * 4 + 0], a1 = As[kk][tr * 4 + 1];
            float a2 = As[kk][tr * 4 + 2], a3 = As[kk][tr * 4 + 3];
            float b0 = Bs[kk][tc * 4 + 0], b1 = Bs[kk][tc * 4 + 1];
            float b2 = Bs[kk][tc * 4 + 2], b3 = Bs[kk][tc * 4 + 3];
            acc[0][0] = fmaf(a0, b0, acc[0][0]); acc[0][1] = fmaf(a0, b1, acc[0][1]);
            acc[0][2] = fmaf(a0, b2, acc[0][2]); acc[0][3] = fmaf(a0, b3, acc[0][3]);
            acc[1][0] = fmaf(a1, b0, acc[1][0]); acc[1][1] = fmaf(a1, b1, acc[1][1]);
            acc[1][2] = fmaf(a1, b2, acc[1][2]); acc[1][3] = fmaf(a1, b3, acc[1][3]);
            acc[2][0] = fmaf(a2, b0, acc[2][0]); acc[2][1] = fmaf(a2, b1, acc[2][1]);
            acc[2][2] = fmaf(a2, b2, acc[2][2]); acc[2][3] = fmaf(a2, b3, acc[2][3]);
            acc[3][0] = fmaf(a3, b0, acc[3][0]); acc[3][1] = fmaf(a3, b1, acc[3][1]);
            acc[3][2] = fmaf(a3, b2, acc[3][2]); acc[3][3] = fmaf(a3, b3, acc[3][3]);
        }
        __syncthreads();
    }
#pragma unroll
    for (int i = 0; i < 4; ++i) {
        int r = bm + tr * 4 + i;
        if (r < N) {
            float4 o4 = make_float4(acc[i][0], acc[i][1], acc[i][2], acc[i][3]);
            *(float4*)(C + (size_t)r * M + bn + tc * 4) = o4;
        }
    }
}

// ---------------- decoder: 16 lanes per label edge ----------------
__global__ __launch_bounds__(256) void decoder16(
    const float* __restrict__ pu16, const float* __restrict__ pm16,
    const int* __restrict__ lab_u, const int* __restrict__ lab_m,
    const float* __restrict__ dw2, const float* __restrict__ db2,
    float* __restrict__ out, int nE) {
    int t = blockIdx.x * 256 + threadIdx.x;
    int e = t >> 4, j = t & 15;
    if (e >= nE) return;
    int u = lab_u[e], m = lab_m[e];
    float v = pu16[(size_t)u * 16 + j] + pm16[(size_t)m * 16 + j];
    float r = fmaxf(v, 0.f) * dw2[j];
    r += __shfl_xor(r, 1, 16);
    r += __shfl_xor(r, 2, 16);
    r += __shfl_xor(r, 4, 16);
    r += __shfl_xor(r, 8, 16);
    if (j == 0) out[e] = r + db2[0];
}

// ---------------- host ----------------

extern "C" void kernel_launch(void* const* d_in, const int* in_sizes, int n_in,
                              void* d_out, int out_size, void* d_ws, size_t ws_size,
                              hipStream_t stream) {
    const float* xu = (const float*)d_in[0];
    const float* xm = (const float*)d_in[1];
    const int* um_src = (const int*)d_in[2];
    const int* um_dst = (const int*)d_in[3];
    const int* mu_src = (const int*)d_in[4];
    const int* mu_dst = (const int*)d_in[5];
    const int* lab_u = (const int*)d_in[6];
    const int* lab_m = (const int*)d_in[7];
    const float* w1um_s = (const float*)d_in[8];
    const float* w1um_d = (const float*)d_in[9];
    const float* a1um_s = (const float*)d_in[10];
    const float* a1um_d = (const float*)d_in[11];
    const float* b1um = (const float*)d_in[12];
    const float* w1mu_s = (const float*)d_in[13];
    const float* w1mu_d = (const float*)d_in[14];
    const float* a1mu_s = (const float*)d_in[15];
    const float* a1mu_d = (const float*)d_in[16];
    const float* b1mu = (const float*)d_in[17];
    const float* w2um_s = (const float*)d_in[18];
    const float* w2um_d = (const float*)d_in[19];
    const float* a2um_s = (const float*)d_in[20];
    const float* a2um_d = (const float*)d_in[21];
    const float* b2um = (const float*)d_in[22];
    const float* w2mu_s = (const float*)d_in[23];
    const float* w2mu_d = (const float*)d_in[24];
    const float* a2mu_s = (const float*)d_in[25];
    const float* a2mu_d = (const float*)d_in[26];
    const float* b2mu = (const float*)d_in[27];
    const float* dw1 = (const float*)d_in[28];
    const float* db1 = (const float*)d_in[29];
    const float* dw2 = (const float*)d_in[30];
    const float* db2 = (const float*)d_in[31];
    float* out = (float*)d_out;

    // -------- workspace layout (floats) --------
    float* ws = (float*)d_ws;
    size_t o = 0;
    float* zm    = ws + o; o += (size_t)NM_ * D1_;     // 2.56M
    float* zu    = ws + o; o += (size_t)NU_ * D1_;     // 12.8M
    float* hx_u  = ws + o; o += (size_t)NU_ * 192;     // 19.2M  [proj|es|ed]
    float* hx_m  = ws + o; o += (size_t)NM_ * 192;     // 3.84M
    float* qx_u  = ws + o; o += (size_t)NU_ * 128;     // 12.8M  [q|es|ed|pad]
    float* qx_m  = ws + o; o += (size_t)NM_ * 128;     // 2.56M
    float* pu16  = ws + o; o += (size_t)NU_ * 16;      // 1.6M
    float* pm16  = ws + o; o += (size_t)NM_ * 16;      // 0.32M
    float* wbuf  = ws + o; o += (size_t)NE_ * H1_;     // 2M
    float* B1u   = ws + o; o += 32 * 192;
    float* B1m   = ws + o; o += 128 * 192;
    float* B2u   = ws + o; o += 128 * 128;
    float* B2m   = ws + o; o += 128 * 128;
    float* zero16= ws + o; o += 16;
    float* cj    = ws + o; o += 16;
    int* rp_um    = (int*)(ws + o);
    int* rp_mu    = rp_um + (NM_ + 1);
    int* ssrc_um  = rp_mu + (NU_ + 1);
    int* sdst_um  = ssrc_um + NE_;
    int* ssrc_mu  = sdst_um + NE_;
    int* sdst_mu  = ssrc_mu + NE_;
    int* ofs      = sdst_mu + NE_;
    int* partials = ofs + (NU_ + 1);
    size_t need = o * sizeof(float) +
                  (size_t)(NM_ + 1 + NU_ + 1 + 4 * NE_ + NU_ + 1 + 64) * sizeof(int);
    if (ws_size < need) {
        fprintf(stderr, "kernel_launch: ws too small (%zu < %zu)\n", ws_size, need);
        return;
    }

    const int TB = 256;

    // -------- CSR (dst-sorted src/dst arrays) --------
    hipMemsetAsync(ofs, 0, NM_ * sizeof(int), stream);
    count_dst<<<cdiv_i(NE_, TB), TB, 0, stream>>>(um_dst, ofs, NE_);
    {
        int nb = cdiv_i(NM_, SCHUNK);
        scan_phaseA<<<nb, 256, 0, stream>>>(ofs, partials, NM_);
        scan_phaseB<<<1, 64, 0, stream>>>(partials, nb, rp_um, NM_);
        scan_phaseC<<<nb, 256, 0, stream>>>(ofs, partials, rp_um, NM_);
    }
    copy_i32<<<cdiv_i(NM_, TB), TB, 0, stream>>>(rp_um, ofs, NM_);
    fill_perm2<<<cdiv_i(NE_, TB), TB, 0, stream>>>(um_dst, um_src, ofs, sdst_um, ssrc_um, NE_);

    hipMemsetAsync(ofs, 0, NU_ * sizeof(int), stream);
    count_dst<<<cdiv_i(NE_, TB), TB, 0, stream>>>(mu_dst, ofs, NE_);
    {
        int nb = cdiv_i(NU_, SCHUNK);
        scan_phaseA<<<nb, 256, 0, stream>>>(ofs, partials, NU_);
        scan_phaseB<<<1, 64, 0, stream>>>(partials, nb, rp_mu, NU_);
        scan_phaseC<<<nb, 256, 0, stream>>>(ofs, partials, rp_mu, NU_);
    }
    copy_i32<<<cdiv_i(NU_, TB), TB, 0, stream>>>(rp_mu, ofs, NU_);
    fill_perm2<<<cdiv_i(NE_, TB), TB, 0, stream>>>(mu_dst, mu_src, ofs, sdst_mu, ssrc_mu, NE_);

    hipMemsetAsync(zero16, 0, 16 * sizeof(float), stream);

    // -------- build combined B matrices --------
    hipMemsetAsync(B1u, 0, (32 * 192) * sizeof(float), stream);
    hipMemsetAsync(B1m, 0, (128 * 192) * sizeof(float), stream);
    hipMemsetAsync(B2u, 0, (128 * 128) * sizeof(float), stream);
    hipMemsetAsync(B2m, 0, (128 * 128) * sizeof(float), stream);

    copy_w_strided<<<cdiv_i(32 * 128, TB), TB, 0, stream>>>(w1um_s, B1u, 32, 192);
    fold_a_strided<<<1, 256, 0, stream>>>(w1um_s, a1um_s, B1u, 32, 8, 16, 128, 192);
    fold_a_strided<<<1, 256, 0, stream>>>(w1mu_d, a1mu_d, B1u, 32, 8, 16, 136, 192);

    copy_w_strided<<<cdiv_i(128 * 128, TB), TB, 0, stream>>>(w1mu_s, B1m, 128, 192);
    fold_a_strided<<<cdiv_i(128 * 8, TB), TB, 0, stream>>>(w1mu_s, a1mu_s, B1m, 128, 8, 16, 128, 192);
    fold_a_strided<<<cdiv_i(128 * 8, TB), TB, 0, stream>>>(w1um_d, a1um_d, B1m, 128, 8, 16, 136, 192);

    fold_w2_strided<<<cdiv_i(128 * 64, TB), TB, 0, stream>>>(w2um_s, dw1, 512, B2u, 128);
    fold_a_strided<<<cdiv_i(128 * 4, TB), TB, 0, stream>>>(w2um_s, a2um_s, B2u, 128, 4, 128, 64, 128);
    fold_a_strided<<<cdiv_i(128 * 4, TB), TB, 0, stream>>>(w2mu_d, a2mu_d, B2u, 128, 4, 128, 68, 128);

    fold_w2_strided<<<cdiv_i(128 * 64, TB), TB, 0, stream>>>(w2mu_s, dw1, 0, B2m, 128);
    fold_a_strided<<<cdiv_i(128 * 4, TB), TB, 0, stream>>>(w2mu_s, a2mu_s, B2m, 128, 4, 128, 64, 128);
    fold_a_strided<<<cdiv_i(128 * 4, TB), TB, 0, stream>>>(w2um_d, a2um_d, B2m, 128, 4, 128, 68, 128);

    fold_cj<<<1, 64, 0, stream>>>(b2mu, b2um, dw1, db1, cj);

    // -------- layer-1 projections + logits (one GEMM per node type) --------
    gemm_f32<<<dim3(3, cdiv_i(NU_, 64)), TB, 0, stream>>>(xu, B1u, hx_u, NU_, FU_, 192);
    gemm_f32<<<dim3(3, cdiv_i(NM_, 64)), TB, 0, stream>>>(xm, B1m, hx_m, NM_, FM_, 192);

    // layer-1 um: src=user es@hx_u+128, dst=movie ed@hx_m+136
    edge_weights<H1_><<<cdiv_i(NE_ * H1_, TB), TB, 0, stream>>>(
        ssrc_um, sdst_um, hx_u + 128, hx_m + 136, 192, 192, wbuf, NE_);
    gat_agg_l1<<<cdiv_i(NM_, 4), TB, 0, stream>>>(hx_u, 192, wbuf, rp_um, ssrc_um, b1um, zm, NM_);

    // layer-1 mu: src=movie es@hx_m+128, dst=user ed@hx_u+136
    edge_weights<H1_><<<cdiv_i(NE_ * H1_, TB), TB, 0, stream>>>(
        ssrc_mu, sdst_mu, hx_m + 128, hx_u + 136, 192, 192, wbuf, NE_);
    gat_agg_l1<<<cdiv_i(NU_, 4), TB, 0, stream>>>(hx_m, 192, wbuf, rp_mu, ssrc_mu, b1mu, zu, NU_);

    // -------- layer-2 projections + logits --------
    gemm_f32<<<dim3(2, cdiv_i(NU_, 64)), TB, 0, stream>>>(zu, B2u, qx_u, NU_, D1_, 128);
    gemm_f32<<<dim3(2, cdiv_i(NM_, 64)), TB, 0, stream>>>(zm, B2m, qx_m, NM_, D1_, 128);

    // layer-2 um: src=user es@qx_u+64, dst=movie ed@qx_m+68 -> pm16 (bias cj)
    edge_weights<H2_><<<cdiv_i(NE_ * H2_, TB), TB, 0, stream>>>(
        ssrc_um, sdst_um, qx_u + 64, qx_m + 68, 128, 128, wbuf, NE_);
    gat_agg_l2<<<cdiv_i(NM_, 4), TB, 0, stream>>>(qx_u, 128, wbuf, rp_um, ssrc_um, cj, pm16, NM_);

    // layer-2 mu: src=movie es@qx_m+64, dst=user ed@qx_u+68 -> pu16 (bias 0)
    edge_weights<H2_><<<cdiv_i(NE_ * H2_, TB), TB, 0, stream>>>(
        ssrc_mu, sdst_mu, qx_m + 64, qx_u + 68, 128, 128, wbuf, NE_);
    gat_agg_l2<<<cdiv_i(NU_, 4), TB, 0, stream>>>(qx_m, 128, wbuf, rp_mu, ssrc_mu, zero16, pu16, NU_);

    // -------- decoder --------
    decoder16<<<cdiv_i(EL_ * 16, TB), TB, 0, stream>>>(
        pu16, pm16, lab_u, lab_m, dw2, db2, out, EL_);
}

// Round 6
// 391.966 us; speedup vs baseline: 2.4815x; 1.4210x over previous
//
#include <hip/hip_runtime.h>
#include <hip/hip_bf16.h>
#include <cstdio>

#define NU_ 100000
#define NM_ 20000
#define FU_ 32
#define FM_ 128
#define H1_ 8
#define C1_ 16
#define D1_ 128
#define H2_ 4
#define NE_ 250000
#define EL_ 200000
#define SCHUNK 2048

static inline int cdiv_i(int a, int b) { return (a + b - 1) / b; }

typedef __attribute__((ext_vector_type(8))) short bf16x8;
typedef __attribute__((ext_vector_type(4))) float f32x4;

__device__ __forceinline__ float bf2f(ushort u) {
    unsigned x = ((unsigned)u) << 16;
    return __builtin_bit_cast(float, x);
}
__device__ __forceinline__ ushort f2bf(float f) {
    unsigned x = __builtin_bit_cast(unsigned, f);
    x += 0x7fff + ((x >> 16) & 1);   // RNE
    return (ushort)(x >> 16);
}

// ---------------- CSR build ----------------

__global__ void copy_i32(const int* __restrict__ a, int* __restrict__ b, int n) {
    int i = blockIdx.x * blockDim.x + threadIdx.x;
    if (i < n) b[i] = a[i];
}

__global__ void count_dst(const int* __restrict__ dst, int* __restrict__ cnt, int E) {
    int i = blockIdx.x * blockDim.x + threadIdx.x;
    if (i < E) atomicAdd(&cnt[dst[i]], 1);
}

__global__ void fill_perm2(const int* __restrict__ dst, const int* __restrict__ src,
                           int* __restrict__ ofs, int* __restrict__ sdst,
                           int* __restrict__ ssrc, int E) {
    int i = blockIdx.x * blockDim.x + threadIdx.x;
    if (i < E) {
        int d = dst[i];
        int p = atomicAdd(&ofs[d], 1);
        ssrc[p] = src[i];
        sdst[p] = d;
    }
}

__global__ __launch_bounds__(256) void scan_phaseA(const int* __restrict__ in,
                                                   int* __restrict__ partial, int n) {
    __shared__ int red[256];
    int b = blockIdx.x, tid = threadIdx.x;
    int base = b * SCHUNK + tid * 8;
    int s = 0;
#pragma unroll
    for (int j = 0; j < 8; ++j) { int i = base + j; if (i < n) s += in[i]; }
    red[tid] = s;
    __syncthreads();
    for (int off = 128; off; off >>= 1) {
        if (tid < off) red[tid] += red[tid + off];
        __syncthreads();
    }
    if (tid == 0) partial[b] = red[0];
}

__global__ void scan_phaseB(int* __restrict__ partial, int nb, int* __restrict__ rp, int n) {
    if (threadIdx.x == 0 && blockIdx.x == 0) {
        int run = 0;
        for (int i = 0; i < nb; ++i) { int v = partial[i]; partial[i] = run; run += v; }
        rp[n] = run;
    }
}

__global__ __launch_bounds__(256) void scan_phaseC(const int* __restrict__ in,
                                                   const int* __restrict__ partial,
                                                   int* __restrict__ out, int n) {
    __shared__ int tsum[256];
    int b = blockIdx.x, tid = threadIdx.x;
    int base = b * SCHUNK + tid * 8;
    int v[8];
    int s = 0;
#pragma unroll
    for (int j = 0; j < 8; ++j) { int i = base + j; v[j] = (i < n) ? in[i] : 0; s += v[j]; }
    tsum[tid] = s;
    __syncthreads();
    for (int off = 1; off < 256; off <<= 1) {
        int y = (tid >= off) ? tsum[tid - off] : 0;
        __syncthreads();
        tsum[tid] += y;
        __syncthreads();
    }
    int run = partial[b] + tsum[tid] - s;
#pragma unroll
    for (int j = 0; j < 8; ++j) { int i = base + j; if (i < n) out[i] = run; run += v[j]; }
}

// ---------------- fp32 -> bf16 convert ----------------
__global__ void conv_f2bf4(const float* __restrict__ s, ushort* __restrict__ d, int n4) {
    int i = blockIdx.x * blockDim.x + threadIdx.x;
    if (i >= n4) return;
    float4 v = ((const float4*)s)[i];
    ushort4 o;
    o.x = f2bf(v.x); o.y = f2bf(v.y); o.z = f2bf(v.z); o.w = f2bf(v.w);
    ((ushort4*)d)[i] = o;
}

// ---------------- B^T builders (bf16, [col][k]) ----------------
// layer-1: 144 cols = [128 proj | 8 es | 8 ed]
__global__ void build_bt1(const float* __restrict__ Ws, const float* __restrict__ as_,
                          const float* __restrict__ Wd, const float* __restrict__ ad,
                          ushort* __restrict__ Bt, int K) {
    int i = blockIdx.x * blockDim.x + threadIdx.x;
    if (i >= 144 * K) return;
    int c = i / K, k = i % K;
    float v;
    if (c < 128) {
        v = Ws[(size_t)k * 128 + c];
    } else if (c < 136) {
        int h = c - 128; v = 0.f;
        for (int cc = 0; cc < 16; ++cc) v += Ws[(size_t)k * 128 + h * 16 + cc] * as_[h * 16 + cc];
    } else {
        int h = c - 136; v = 0.f;
        for (int cc = 0; cc < 16; ++cc) v += Wd[(size_t)k * 128 + h * 16 + cc] * ad[h * 16 + cc];
    }
    Bt[(size_t)c * K + k] = f2bf(v);
}

// layer-2: 80 cols = [64 q (dw1-folded) | 4 es | 4 ed | 8 zero-pad], K=128
__global__ void build_bt2(const float* __restrict__ Ws, const float* __restrict__ as_,
                          const float* __restrict__ Wd, const float* __restrict__ ad,
                          const float* __restrict__ dw1, int rowoff, ushort* __restrict__ Bt) {
    int i = blockIdx.x * blockDim.x + threadIdx.x;
    if (i >= 80 * 128) return;
    int c = i >> 7, k = i & 127;
    float v = 0.f;
    if (c < 64) {
        int h = c >> 4, j = c & 15;
        for (int cc = 0; cc < 128; ++cc)
            v += Ws[(size_t)k * 512 + h * 128 + cc] * dw1[(size_t)(rowoff + h * 128 + cc) * 16 + j];
    } else if (c < 68) {
        int h = c - 64;
        for (int cc = 0; cc < 128; ++cc) v += Ws[(size_t)k * 512 + h * 128 + cc] * as_[h * 128 + cc];
    } else if (c < 72) {
        int h = c - 68;
        for (int cc = 0; cc < 128; ++cc) v += Wd[(size_t)k * 512 + h * 128 + cc] * ad[h * 128 + cc];
    }
    Bt[(size_t)c * 128 + k] = f2bf(v);
}

__global__ void fold_cj(const float* __restrict__ b2mu, const float* __restrict__ b2um,
                        const float* __restrict__ dw1, const float* __restrict__ db1,
                        float* __restrict__ cj) {
    int j = threadIdx.x;
    if (j >= 16) return;
    float s = db1[j];
    for (int col = 0; col < 512; ++col)
        s += b2mu[col] * dw1[col * 16 + j] + b2um[col] * dw1[(512 + col) * 16 + j];
    cj[j] = s;
}

// ---------------- MFMA GEMM: out = A[N][K]_bf16 @ Bt[ncols][K]_bf16^T ----------------
// cols < splitc -> bf16 out (stride sb); splitc <= col < maxc -> f32 out (stride sf)
template <int K, int NT>
__global__ __launch_bounds__(256) void mfma_gemm(
    const ushort* __restrict__ A, const ushort* __restrict__ Bt,
    ushort* __restrict__ outb, int sb, float* __restrict__ outf, int sf,
    int splitc, int maxc, int Nrows) {
    int wave = threadIdx.x >> 6;
    int lane = threadIdx.x & 63;
    int row0 = (blockIdx.x * 4 + wave) * 16;
    if (row0 >= Nrows) return;
    int r = lane & 15;
    int kb = lane >> 4;
    bf16x8 afrag[K / 32];
    int arow = row0 + r;
    bool rowok = (arow < Nrows);
#pragma unroll
    for (int ks = 0; ks < K / 32; ++ks) {
        if (rowok)
            afrag[ks] = *(const bf16x8*)(A + (size_t)arow * K + ks * 32 + kb * 8);
        else
            afrag[ks] = (bf16x8){0, 0, 0, 0, 0, 0, 0, 0};
    }
#pragma unroll
    for (int nt = 0; nt < NT; ++nt) {
        f32x4 acc = {0.f, 0.f, 0.f, 0.f};
#pragma unroll
        for (int ks = 0; ks < K / 32; ++ks) {
            bf16x8 bfrag = *(const bf16x8*)(Bt + (size_t)(nt * 16 + r) * K + ks * 32 + kb * 8);
            acc = __builtin_amdgcn_mfma_f32_16x16x32_bf16(afrag[ks], bfrag, acc, 0, 0, 0);
        }
        int col = nt * 16 + r;
#pragma unroll
        for (int reg = 0; reg < 4; ++reg) {
            int rr = row0 + kb * 4 + reg;
            if (rr < Nrows) {
                if (col < splitc)
                    outb[(size_t)rr * sb + col] = f2bf(acc[reg]);
                else if (col < maxc)
                    outf[(size_t)rr * sf + (col - splitc)] = acc[reg];
            }
        }
    }
}

// ---------------- edge weights: w[i,h] = exp(leaky(es[src]+ed[dst])) ----------------
template <int H>
__global__ __launch_bounds__(256) void edge_weights(
    const int* __restrict__ ssrc, const int* __restrict__ sdst,
    const float* __restrict__ es, const float* __restrict__ ed,
    int ses, int sed, float* __restrict__ w, int E) {
    constexpr int SH = (H == 8) ? 3 : 2;
    int t = blockIdx.x * 256 + threadIdx.x;
    if (t >= E * H) return;
    int i = t >> SH, h = t & (H - 1);
    int s = ssrc[i], d = sdst[i];
    float x = es[(size_t)s * ses + h] + ed[(size_t)d * sed + h];
    x = x > 0.f ? x : 0.2f * x;
    w[t] = __expf(x);
}

// ---------------- layer-1 aggregation: bf16 in [Ns][128], bf16 out, relu ----------------
__global__ __launch_bounds__(256) void gat_agg_l1b(
    const ushort* __restrict__ hs, const float* __restrict__ w,
    const int* __restrict__ rowptr, const int* __restrict__ ssrc,
    const float* __restrict__ bias, ushort* __restrict__ outz, int Nd) {
    int wid = (blockIdx.x * 256 + threadIdx.x) >> 6;
    int lane = threadIdx.x & 63;
    if (wid >= Nd) return;
    int r0 = rowptr[wid], r1 = rowptr[wid + 1];
    int hm = lane & 7, slot = lane >> 3;

    float ssum = 0.f;
    for (int i = r0 + slot; i < r1; i += 8) ssum += w[(size_t)i * 8 + hm];
#pragma unroll
    for (int off = 8; off < 64; off <<= 1) ssum += __shfl_xor(ssum, off, 64);
    float inv = 1.f / (ssum + 1e-16f);

    float acc0 = 0.f, acc1 = 0.f;
    int hh = lane >> 3;  // head of columns {2*lane, 2*lane+1}
    for (int i = r0; i < r1; ++i) {
        int s = ssrc[i];
        float am = (lane < 8) ? w[(size_t)i * 8 + lane] * inv : 0.f;
        float al = __shfl(am, hh, 64);
        unsigned hv = *(const unsigned*)(hs + (size_t)s * 128 + 2 * lane);
        acc0 = fmaf(bf2f((ushort)(hv & 0xffffu)), al, acc0);
        acc1 = fmaf(bf2f((ushort)(hv >> 16)), al, acc1);
    }
    float v0 = fmaxf(acc0 + bias[2 * lane], 0.f);
    float v1 = fmaxf(acc1 + bias[2 * lane + 1], 0.f);
    unsigned o = (unsigned)f2bf(v0) | ((unsigned)f2bf(v1) << 16);
    *(unsigned*)(outz + (size_t)wid * 128 + 2 * lane) = o;
}

// ---------------- layer-2 aggregation: bf16 q [Ns][64], head-summed f32 out16 ----------------
__global__ __launch_bounds__(256) void gat_agg_l2b(
    const ushort* __restrict__ q, const float* __restrict__ w,
    const int* __restrict__ rowptr, const int* __restrict__ ssrc,
    const float* __restrict__ bias16, float* __restrict__ out16, int Nd) {
    int wid = (blockIdx.x * 256 + threadIdx.x) >> 6;
    int lane = threadIdx.x & 63;
    if (wid >= Nd) return;
    int r0 = rowptr[wid], r1 = rowptr[wid + 1];
    int hm = lane & 3, slot = lane >> 2;

    float ssum = 0.f;
    for (int i = r0 + slot; i < r1; i += 16) ssum += w[(size_t)i * 4 + hm];
#pragma unroll
    for (int off = 4; off < 64; off <<= 1) ssum += __shfl_xor(ssum, off, 64);
    float inv = 1.f / (ssum + 1e-16f);

    float acc = 0.f;
    int hh = lane >> 4;
    for (int i = r0; i < r1; ++i) {
        int s = ssrc[i];
        float am = (lane < 4) ? w[(size_t)i * 4 + lane] * inv : 0.f;
        float al = __shfl(am, hh, 64);
        acc = fmaf(bf2f(q[(size_t)s * 64 + lane]), al, acc);
    }
    acc += __shfl_xor(acc, 16, 64);
    acc += __shfl_xor(acc, 32, 64);
    if (lane < 16) out16[(size_t)wid * 16 + lane] = acc + bias16[lane];
}

// ---------------- decoder: 16 lanes per label edge ----------------
__global__ __launch_bounds__(256) void decoder16(
    const float* __restrict__ pu16, const float* __restrict__ pm16,
    const int* __restrict__ lab_u, const int* __restrict__ lab_m,
    const float* __restrict__ dw2, const float* __restrict__ db2,
    float* __restrict__ out, int nE) {
    int t = blockIdx.x * 256 + threadIdx.x;
    int e = t >> 4, j = t & 15;
    if (e >= nE) return;
    int u = lab_u[e], m = lab_m[e];
    float v = pu16[(size_t)u * 16 + j] + pm16[(size_t)m * 16 + j];
    float r = fmaxf(v, 0.f) * dw2[j];
    r += __shfl_xor(r, 1, 16);
    r += __shfl_xor(r, 2, 16);
    r += __shfl_xor(r, 4, 16);
    r += __shfl_xor(r, 8, 16);
    if (j == 0) out[e] = r + db2[0];
}

// ---------------- host ----------------

extern "C" void kernel_launch(void* const* d_in, const int* in_sizes, int n_in,
                              void* d_out, int out_size, void* d_ws, size_t ws_size,
                              hipStream_t stream) {
    const float* xu = (const float*)d_in[0];
    const float* xm = (const float*)d_in[1];
    const int* um_src = (const int*)d_in[2];
    const int* um_dst = (const int*)d_in[3];
    const int* mu_src = (const int*)d_in[4];
    const int* mu_dst = (const int*)d_in[5];
    const int* lab_u = (const int*)d_in[6];
    const int* lab_m = (const int*)d_in[7];
    const float* w1um_s = (const float*)d_in[8];
    const float* w1um_d = (const float*)d_in[9];
    const float* a1um_s = (const float*)d_in[10];
    const float* a1um_d = (const float*)d_in[11];
    const float* b1um = (const float*)d_in[12];
    const float* w1mu_s = (const float*)d_in[13];
    const float* w1mu_d = (const float*)d_in[14];
    const float* a1mu_s = (const float*)d_in[15];
    const float* a1mu_d = (const float*)d_in[16];
    const float* b1mu = (const float*)d_in[17];
    const float* w2um_s = (const float*)d_in[18];
    const float* w2um_d = (const float*)d_in[19];
    const float* a2um_s = (const float*)d_in[20];
    const float* a2um_d = (const float*)d_in[21];
    const float* b2um = (const float*)d_in[22];
    const float* w2mu_s = (const float*)d_in[23];
    const float* w2mu_d = (const float*)d_in[24];
    const float* a2mu_s = (const float*)d_in[25];
    const float* a2mu_d = (const float*)d_in[26];
    const float* b2mu = (const float*)d_in[27];
    const float* dw1 = (const float*)d_in[28];
    const float* db1 = (const float*)d_in[29];
    const float* dw2 = (const float*)d_in[30];
    const float* db2 = (const float*)d_in[31];
    float* out = (float*)d_out;
    (void)w2um_d; (void)w2mu_d; (void)b2um; (void)b2mu;

    // -------- workspace carving (byte cursor, 64B aligned) --------
    char* base = (char*)d_ws;
    size_t off = 0;
    auto alloc = [&](size_t bytes) -> void* {
        void* p = base + off;
        off = (off + bytes + 63) & ~(size_t)63;
        return p;
    };
    ushort* xu_bf   = (ushort*)alloc((size_t)NU_ * 32 * 2);
    ushort* xm_bf   = (ushort*)alloc((size_t)NM_ * 128 * 2);
    ushort* hproj_u = (ushort*)alloc((size_t)NU_ * 128 * 2);
    ushort* hproj_m = (ushort*)alloc((size_t)NM_ * 128 * 2);
    ushort* zu_bf   = (ushort*)alloc((size_t)NU_ * 128 * 2);
    ushort* zm_bf   = (ushort*)alloc((size_t)NM_ * 128 * 2);
    ushort* qq_u    = (ushort*)alloc((size_t)NU_ * 64 * 2);
    ushort* qq_m    = (ushort*)alloc((size_t)NM_ * 64 * 2);
    ushort* Bt1u    = (ushort*)alloc((size_t)144 * 32 * 2);
    ushort* Bt1m    = (ushort*)alloc((size_t)144 * 128 * 2);
    ushort* Bt2u    = (ushort*)alloc((size_t)80 * 128 * 2);
    ushort* Bt2m    = (ushort*)alloc((size_t)80 * 128 * 2);
    float* hlog_u = (float*)alloc((size_t)NU_ * 16 * 4);
    float* hlog_m = (float*)alloc((size_t)NM_ * 16 * 4);
    float* qlog_u = (float*)alloc((size_t)NU_ * 8 * 4);
    float* qlog_m = (float*)alloc((size_t)NM_ * 8 * 4);
    float* pu16   = (float*)alloc((size_t)NU_ * 16 * 4);
    float* pm16   = (float*)alloc((size_t)NM_ * 16 * 4);
    float* wbuf   = (float*)alloc((size_t)NE_ * 8 * 4);
    float* cj     = (float*)alloc(16 * 4);
    float* zero16 = (float*)alloc(16 * 4);
    int* rp_um    = (int*)alloc((NM_ + 1) * 4);
    int* rp_mu    = (int*)alloc((NU_ + 1) * 4);
    int* ssrc_um  = (int*)alloc((size_t)NE_ * 4);
    int* sdst_um  = (int*)alloc((size_t)NE_ * 4);
    int* ssrc_mu  = (int*)alloc((size_t)NE_ * 4);
    int* sdst_mu  = (int*)alloc((size_t)NE_ * 4);
    int* ofs      = (int*)alloc((NU_ + 1) * 4);
    int* partials = (int*)alloc(64 * 4);
    if (ws_size < off) {
        fprintf(stderr, "kernel_launch: ws too small (%zu < %zu)\n", ws_size, off);
        return;
    }

    const int TB = 256;

    // -------- CSR (dst-sorted src/dst arrays) --------
    hipMemsetAsync(ofs, 0, NM_ * sizeof(int), stream);
    count_dst<<<cdiv_i(NE_, TB), TB, 0, stream>>>(um_dst, ofs, NE_);
    {
        int nb = cdiv_i(NM_, SCHUNK);
        scan_phaseA<<<nb, 256, 0, stream>>>(ofs, partials, NM_);
        scan_phaseB<<<1, 64, 0, stream>>>(partials, nb, rp_um, NM_);
        scan_phaseC<<<nb, 256, 0, stream>>>(ofs, partials, rp_um, NM_);
    }
    copy_i32<<<cdiv_i(NM_, TB), TB, 0, stream>>>(rp_um, ofs, NM_);
    fill_perm2<<<cdiv_i(NE_, TB), TB, 0, stream>>>(um_dst, um_src, ofs, sdst_um, ssrc_um, NE_);

    hipMemsetAsync(ofs, 0, NU_ * sizeof(int), stream);
    count_dst<<<cdiv_i(NE_, TB), TB, 0, stream>>>(mu_dst, ofs, NE_);
    {
        int nb = cdiv_i(NU_, SCHUNK);
        scan_phaseA<<<nb, 256, 0, stream>>>(ofs, partials, NU_);
        scan_phaseB<<<1, 64, 0, stream>>>(partials, nb, rp_mu, NU_);
        scan_phaseC<<<nb, 256, 0, stream>>>(ofs, partials, rp_mu, NU_);
    }
    copy_i32<<<cdiv_i(NU_, TB), TB, 0, stream>>>(rp_mu, ofs, NU_);
    fill_perm2<<<cdiv_i(NE_, TB), TB, 0, stream>>>(mu_dst, mu_src, ofs, sdst_mu, ssrc_mu, NE_);

    hipMemsetAsync(zero16, 0, 16 * sizeof(float), stream);

    // -------- input casts + B^T builders --------
    conv_f2bf4<<<cdiv_i(NU_ * 32 / 4, TB), TB, 0, stream>>>(xu, xu_bf, NU_ * 32 / 4);
    conv_f2bf4<<<cdiv_i(NM_ * 128 / 4, TB), TB, 0, stream>>>(xm, xm_bf, NM_ * 128 / 4);

    build_bt1<<<cdiv_i(144 * 32, TB), TB, 0, stream>>>(w1um_s, a1um_s, w1mu_d, a1mu_d, Bt1u, 32);
    build_bt1<<<cdiv_i(144 * 128, TB), TB, 0, stream>>>(w1mu_s, a1mu_s, w1um_d, a1um_d, Bt1m, 128);
    build_bt2<<<cdiv_i(80 * 128, TB), TB, 0, stream>>>(w2um_s, a2um_s, w2mu_d, a2mu_d, dw1, 512, Bt2u);
    build_bt2<<<cdiv_i(80 * 128, TB), TB, 0, stream>>>(w2mu_s, a2mu_s, w2um_d, a2um_d, dw1, 0, Bt2m);
    fold_cj<<<1, 64, 0, stream>>>(b2mu, b2um, dw1, db1, cj);

    // -------- layer-1 projections + logits (MFMA) --------
    mfma_gemm<32, 9><<<cdiv_i(NU_, 64), TB, 0, stream>>>(
        xu_bf, Bt1u, hproj_u, 128, hlog_u, 16, 128, 144, NU_);
    mfma_gemm<128, 9><<<cdiv_i(NM_, 64), TB, 0, stream>>>(
        xm_bf, Bt1m, hproj_m, 128, hlog_m, 16, 128, 144, NM_);

    // layer-1 um: es = user cols 0-7, ed = movie cols 8-15
    edge_weights<H1_><<<cdiv_i(NE_ * H1_, TB), TB, 0, stream>>>(
        ssrc_um, sdst_um, hlog_u, hlog_m + 8, 16, 16, wbuf, NE_);
    gat_agg_l1b<<<cdiv_i(NM_, 4), TB, 0, stream>>>(hproj_u, wbuf, rp_um, ssrc_um, b1um, zm_bf, NM_);

    // layer-1 mu
    edge_weights<H1_><<<cdiv_i(NE_ * H1_, TB), TB, 0, stream>>>(
        ssrc_mu, sdst_mu, hlog_m, hlog_u + 8, 16, 16, wbuf, NE_);
    gat_agg_l1b<<<cdiv_i(NU_, 4), TB, 0, stream>>>(hproj_m, wbuf, rp_mu, ssrc_mu, b1mu, zu_bf, NU_);

    // -------- layer-2 projections + logits (MFMA) --------
    mfma_gemm<128, 5><<<cdiv_i(NU_, 64), TB, 0, stream>>>(
        zu_bf, Bt2u, qq_u, 64, qlog_u, 8, 64, 72, NU_);
    mfma_gemm<128, 5><<<cdiv_i(NM_, 64), TB, 0, stream>>>(
        zm_bf, Bt2m, qq_m, 64, qlog_m, 8, 64, 72, NM_);

    // layer-2 um: es = user qlog cols 0-3, ed = movie qlog cols 4-7 -> pm16 (bias cj)
    edge_weights<H2_><<<cdiv_i(NE_ * H2_, TB), TB, 0, stream>>>(
        ssrc_um, sdst_um, qlog_u, qlog_m + 4, 8, 8, wbuf, NE_);
    gat_agg_l2b<<<cdiv_i(NM_, 4), TB, 0, stream>>>(qq_u, wbuf, rp_um, ssrc_um, cj, pm16, NM_);

    // layer-2 mu -> pu16 (bias 0)
    edge_weights<H2_><<<cdiv_i(NE_ * H2_, TB), TB, 0, stream>>>(
        ssrc_mu, sdst_mu, qlog_m, qlog_u + 4, 8, 8, wbuf, NE_);
    gat_agg_l2b<<<cdiv_i(NU_, 4), TB, 0, stream>>>(qq_m, wbuf, rp_mu, ssrc_mu, zero16, pu16, NU_);

    // -------- decoder --------
    decoder16<<<cdiv_i(EL_ * 16, TB), TB, 0, stream>>>(
        pu16, pm16, lab_u, lab_m, dw2, db2, out, EL_);
}

// Round 7
// 348.733 us; speedup vs baseline: 2.7891x; 1.1240x over previous
//
#include <hip/hip_runtime.h>
#include <hip/hip_bf16.h>
#include <cstdio>

#define NU_ 100000
#define NM_ 20000
#define FU_ 32
#define FM_ 128
#define H1_ 8
#define H2_ 4
#define NE_ 250000
#define EL_ 200000
#define SCHUNK 2048

static inline int cdiv_i(int a, int b) { return (a + b - 1) / b; }

typedef __attribute__((ext_vector_type(8))) short bf16x8;
typedef __attribute__((ext_vector_type(4))) float f32x4;

__device__ __forceinline__ float bf2f(ushort u) {
    unsigned x = ((unsigned)u) << 16;
    return __builtin_bit_cast(float, x);
}
__device__ __forceinline__ ushort f2bf(float f) {
    unsigned x = __builtin_bit_cast(unsigned, f);
    x += 0x7fff + ((x >> 16) & 1);   // RNE
    return (ushort)(x >> 16);
}

// ---------------- CSR build ----------------

__global__ void copy_i32(const int* __restrict__ a, int* __restrict__ b, int n) {
    int i = blockIdx.x * blockDim.x + threadIdx.x;
    if (i < n) b[i] = a[i];
}

__global__ void count_dst(const int* __restrict__ dst, int* __restrict__ cnt, int E) {
    int i = blockIdx.x * blockDim.x + threadIdx.x;
    if (i < E) atomicAdd(&cnt[dst[i]], 1);
}

__global__ void fill_perm2(const int* __restrict__ dst, const int* __restrict__ src,
                           int* __restrict__ ofs, int* __restrict__ sdst,
                           int* __restrict__ ssrc, int E) {
    int i = blockIdx.x * blockDim.x + threadIdx.x;
    if (i < E) {
        int d = dst[i];
        int p = atomicAdd(&ofs[d], 1);
        ssrc[p] = src[i];
        sdst[p] = d;
    }
}

__global__ __launch_bounds__(256) void scan_phaseA(const int* __restrict__ in,
                                                   int* __restrict__ partial, int n) {
    __shared__ int red[256];
    int b = blockIdx.x, tid = threadIdx.x;
    int base = b * SCHUNK + tid * 8;
    int s = 0;
#pragma unroll
    for (int j = 0; j < 8; ++j) { int i = base + j; if (i < n) s += in[i]; }
    red[tid] = s;
    __syncthreads();
    for (int off = 128; off; off >>= 1) {
        if (tid < off) red[tid] += red[tid + off];
        __syncthreads();
    }
    if (tid == 0) partial[b] = red[0];
}

__global__ void scan_phaseB(int* __restrict__ partial, int nb, int* __restrict__ rp, int n) {
    if (threadIdx.x == 0 && blockIdx.x == 0) {
        int run = 0;
        for (int i = 0; i < nb; ++i) { int v = partial[i]; partial[i] = run; run += v; }
        rp[n] = run;
    }
}

__global__ __launch_bounds__(256) void scan_phaseC(const int* __restrict__ in,
                                                   const int* __restrict__ partial,
                                                   int* __restrict__ out, int n) {
    __shared__ int tsum[256];
    int b = blockIdx.x, tid = threadIdx.x;
    int base = b * SCHUNK + tid * 8;
    int v[8];
    int s = 0;
#pragma unroll
    for (int j = 0; j < 8; ++j) { int i = base + j; v[j] = (i < n) ? in[i] : 0; s += v[j]; }
    tsum[tid] = s;
    __syncthreads();
    for (int off = 1; off < 256; off <<= 1) {
        int y = (tid >= off) ? tsum[tid - off] : 0;
        __syncthreads();
        tsum[tid] += y;
        __syncthreads();
    }
    int run = partial[b] + tsum[tid] - s;
#pragma unroll
    for (int j = 0; j < 8; ++j) { int i = base + j; if (i < n) out[i] = run; run += v[j]; }
}

// ---------------- fp32 -> bf16 convert ----------------
__global__ void conv_f2bf4(const float* __restrict__ s, ushort* __restrict__ d, int n4) {
    int i = blockIdx.x * blockDim.x + threadIdx.x;
    if (i >= n4) return;
    float4 v = ((const float4*)s)[i];
    ushort4 o;
    o.x = f2bf(v.x); o.y = f2bf(v.y); o.z = f2bf(v.z); o.w = f2bf(v.w);
    ((ushort4*)d)[i] = o;
}

// ---------------- B^T builders (bf16, [col][k]) ----------------
__global__ void build_bt1(const float* __restrict__ Ws, const float* __restrict__ as_,
                          const float* __restrict__ Wd, const float* __restrict__ ad,
                          ushort* __restrict__ Bt, int K) {
    int i = blockIdx.x * blockDim.x + threadIdx.x;
    if (i >= 144 * K) return;
    int c = i / K, k = i % K;
    float v;
    if (c < 128) {
        v = Ws[(size_t)k * 128 + c];
    } else if (c < 136) {
        int h = c - 128; v = 0.f;
        for (int cc = 0; cc < 16; ++cc) v += Ws[(size_t)k * 128 + h * 16 + cc] * as_[h * 16 + cc];
    } else {
        int h = c - 136; v = 0.f;
        for (int cc = 0; cc < 16; ++cc) v += Wd[(size_t)k * 128 + h * 16 + cc] * ad[h * 16 + cc];
    }
    Bt[(size_t)c * K + k] = f2bf(v);
}

__global__ void build_bt2(const float* __restrict__ Ws, const float* __restrict__ as_,
                          const float* __restrict__ Wd, const float* __restrict__ ad,
                          const float* __restrict__ dw1, int rowoff, ushort* __restrict__ Bt) {
    int i = blockIdx.x * blockDim.x + threadIdx.x;
    if (i >= 80 * 128) return;
    int c = i >> 7, k = i & 127;
    float v = 0.f;
    if (c < 64) {
        int h = c >> 4, j = c & 15;
        for (int cc = 0; cc < 128; ++cc)
            v += Ws[(size_t)k * 512 + h * 128 + cc] * dw1[(size_t)(rowoff + h * 128 + cc) * 16 + j];
    } else if (c < 68) {
        int h = c - 64;
        for (int cc = 0; cc < 128; ++cc) v += Ws[(size_t)k * 512 + h * 128 + cc] * as_[h * 128 + cc];
    } else if (c < 72) {
        int h = c - 68;
        for (int cc = 0; cc < 128; ++cc) v += Wd[(size_t)k * 512 + h * 128 + cc] * ad[h * 128 + cc];
    }
    Bt[(size_t)c * 128 + k] = f2bf(v);
}

__global__ void fold_cj(const float* __restrict__ b2mu, const float* __restrict__ b2um,
                        const float* __restrict__ dw1, const float* __restrict__ db1,
                        float* __restrict__ cj) {
    int j = threadIdx.x;
    if (j >= 16) return;
    float s = db1[j];
    for (int col = 0; col < 512; ++col)
        s += b2mu[col] * dw1[col * 16 + j] + b2um[col] * dw1[(512 + col) * 16 + j];
    cj[j] = s;
}

// ---------------- MFMA GEMM ----------------
template <int K, int NT>
__global__ __launch_bounds__(256) void mfma_gemm(
    const ushort* __restrict__ A, const ushort* __restrict__ Bt,
    ushort* __restrict__ outb, int sb, float* __restrict__ outf, int sf,
    int splitc, int maxc, int Nrows) {
    int wave = threadIdx.x >> 6;
    int lane = threadIdx.x & 63;
    int row0 = (blockIdx.x * 4 + wave) * 16;
    if (row0 >= Nrows) return;
    int r = lane & 15;
    int kb = lane >> 4;
    bf16x8 afrag[K / 32];
    int arow = row0 + r;
    bool rowok = (arow < Nrows);
#pragma unroll
    for (int ks = 0; ks < K / 32; ++ks) {
        if (rowok)
            afrag[ks] = *(const bf16x8*)(A + (size_t)arow * K + ks * 32 + kb * 8);
        else
            afrag[ks] = (bf16x8){0, 0, 0, 0, 0, 0, 0, 0};
    }
#pragma unroll
    for (int nt = 0; nt < NT; ++nt) {
        f32x4 acc = {0.f, 0.f, 0.f, 0.f};
#pragma unroll
        for (int ks = 0; ks < K / 32; ++ks) {
            bf16x8 bfrag = *(const bf16x8*)(Bt + (size_t)(nt * 16 + r) * K + ks * 32 + kb * 8);
            acc = __builtin_amdgcn_mfma_f32_16x16x32_bf16(afrag[ks], bfrag, acc, 0, 0, 0);
        }
        int col = nt * 16 + r;
#pragma unroll
        for (int reg = 0; reg < 4; ++reg) {
            int rr = row0 + kb * 4 + reg;
            if (rr < Nrows) {
                if (col < splitc)
                    outb[(size_t)rr * sb + col] = f2bf(acc[reg]);
                else if (col < maxc)
                    outf[(size_t)rr * sf + (col - splitc)] = acc[reg];
            }
        }
    }
}

// ---------------- fused layer-1 aggregation (single pass, H=8, D=128) ----------------
// eslog: src logit cols (stride 16); edlog: dst logit cols (stride 16, offset pre-added)
__global__ __launch_bounds__(256) void gat_agg_l1f(
    const ushort* __restrict__ hs, const float* __restrict__ eslog,
    const float* __restrict__ edlog, const int* __restrict__ rowptr,
    const int* __restrict__ ssrc, const float* __restrict__ bias,
    ushort* __restrict__ outz, int Nd) {
    int wid = (blockIdx.x * 256 + threadIdx.x) >> 6;
    int lane = threadIdx.x & 63;
    if (wid >= Nd) return;
    int r0 = rowptr[wid], r1 = rowptr[wid + 1];
    float edv = (lane < 8) ? edlog[(size_t)wid * 16 + lane] : 0.f;
    int hh = lane >> 3;   // head of cols {2*lane, 2*lane+1}
    float ssum = 0.f, acc0 = 0.f, acc1 = 0.f;

    int i = r0;
    for (; i + 2 <= r1; i += 2) {
        int s0 = ssrc[i], s1 = ssrc[i + 1];
        float w0 = 0.f, w1 = 0.f;
        if (lane < 8) {
            float x0 = eslog[(size_t)s0 * 16 + lane] + edv;
            float x1 = eslog[(size_t)s1 * 16 + lane] + edv;
            x0 = x0 > 0.f ? x0 : 0.2f * x0;
            x1 = x1 > 0.f ? x1 : 0.2f * x1;
            w0 = __expf(x0); w1 = __expf(x1);
            ssum += w0 + w1;
        }
        float al0 = __shfl(w0, hh, 64);
        float al1 = __shfl(w1, hh, 64);
        unsigned hv0 = *(const unsigned*)(hs + (size_t)s0 * 128 + 2 * lane);
        unsigned hv1 = *(const unsigned*)(hs + (size_t)s1 * 128 + 2 * lane);
        acc0 = fmaf(bf2f((ushort)(hv0 & 0xffffu)), al0, acc0);
        acc1 = fmaf(bf2f((ushort)(hv0 >> 16)), al0, acc1);
        acc0 = fmaf(bf2f((ushort)(hv1 & 0xffffu)), al1, acc0);
        acc1 = fmaf(bf2f((ushort)(hv1 >> 16)), al1, acc1);
    }
    if (i < r1) {
        int s0 = ssrc[i];
        float w0 = 0.f;
        if (lane < 8) {
            float x0 = eslog[(size_t)s0 * 16 + lane] + edv;
            x0 = x0 > 0.f ? x0 : 0.2f * x0;
            w0 = __expf(x0);
            ssum += w0;
        }
        float al0 = __shfl(w0, hh, 64);
        unsigned hv0 = *(const unsigned*)(hs + (size_t)s0 * 128 + 2 * lane);
        acc0 = fmaf(bf2f((ushort)(hv0 & 0xffffu)), al0, acc0);
        acc1 = fmaf(bf2f((ushort)(hv0 >> 16)), al0, acc1);
    }
    float inv = 1.f / (__shfl(ssum, hh, 64) + 1e-16f);
    float v0 = fmaxf(fmaf(acc0, inv, bias[2 * lane]), 0.f);
    float v1 = fmaxf(fmaf(acc1, inv, bias[2 * lane + 1]), 0.f);
    unsigned o = (unsigned)f2bf(v0) | ((unsigned)f2bf(v1) << 16);
    *(unsigned*)(outz + (size_t)wid * 128 + 2 * lane) = o;
}

// ---------------- fused layer-2 aggregation (single pass, H=4, 64-wide, head-summed 16) ----------------
__global__ __launch_bounds__(256) void gat_agg_l2f(
    const ushort* __restrict__ q, const float* __restrict__ eslog,
    const float* __restrict__ edlog, const int* __restrict__ rowptr,
    const int* __restrict__ ssrc, const float* __restrict__ bias16,
    float* __restrict__ out16, int Nd) {
    int wid = (blockIdx.x * 256 + threadIdx.x) >> 6;
    int lane = threadIdx.x & 63;
    if (wid >= Nd) return;
    int r0 = rowptr[wid], r1 = rowptr[wid + 1];
    float edv = (lane < 4) ? edlog[(size_t)wid * 8 + lane] : 0.f;
    int hh = lane >> 4;
    float ssum = 0.f, acc = 0.f;

    int i = r0;
    for (; i + 2 <= r1; i += 2) {
        int s0 = ssrc[i], s1 = ssrc[i + 1];
        float w0 = 0.f, w1 = 0.f;
        if (lane < 4) {
            float x0 = eslog[(size_t)s0 * 8 + lane] + edv;
            float x1 = eslog[(size_t)s1 * 8 + lane] + edv;
            x0 = x0 > 0.f ? x0 : 0.2f * x0;
            x1 = x1 > 0.f ? x1 : 0.2f * x1;
            w0 = __expf(x0); w1 = __expf(x1);
            ssum += w0 + w1;
        }
        float al0 = __shfl(w0, hh, 64);
        float al1 = __shfl(w1, hh, 64);
        float q0 = bf2f(q[(size_t)s0 * 64 + lane]);
        float q1 = bf2f(q[(size_t)s1 * 64 + lane]);
        acc = fmaf(q0, al0, acc);
        acc = fmaf(q1, al1, acc);
    }
    if (i < r1) {
        int s0 = ssrc[i];
        float w0 = 0.f;
        if (lane < 4) {
            float x0 = eslog[(size_t)s0 * 8 + lane] + edv;
            x0 = x0 > 0.f ? x0 : 0.2f * x0;
            w0 = __expf(x0);
            ssum += w0;
        }
        float al0 = __shfl(w0, hh, 64);
        acc = fmaf(bf2f(q[(size_t)s0 * 64 + lane]), al0, acc);
    }
    float inv = 1.f / (__shfl(ssum, hh, 64) + 1e-16f);
    acc *= inv;
    acc += __shfl_xor(acc, 16, 64);
    acc += __shfl_xor(acc, 32, 64);
    if (lane < 16) out16[(size_t)wid * 16 + lane] = acc + bias16[lane];
}

// ---------------- decoder: 16 lanes per label edge ----------------
__global__ __launch_bounds__(256) void decoder16(
    const float* __restrict__ pu16, const float* __restrict__ pm16,
    const int* __restrict__ lab_u, const int* __restrict__ lab_m,
    const float* __restrict__ dw2, const float* __restrict__ db2,
    float* __restrict__ out, int nE) {
    int t = blockIdx.x * 256 + threadIdx.x;
    int e = t >> 4, j = t & 15;
    if (e >= nE) return;
    int u = lab_u[e], m = lab_m[e];
    float v = pu16[(size_t)u * 16 + j] + pm16[(size_t)m * 16 + j];
    float r = fmaxf(v, 0.f) * dw2[j];
    r += __shfl_xor(r, 1, 16);
    r += __shfl_xor(r, 2, 16);
    r += __shfl_xor(r, 4, 16);
    r += __shfl_xor(r, 8, 16);
    if (j == 0) out[e] = r + db2[0];
}

// ---------------- host ----------------

extern "C" void kernel_launch(void* const* d_in, const int* in_sizes, int n_in,
                              void* d_out, int out_size, void* d_ws, size_t ws_size,
                              hipStream_t stream) {
    const float* xu = (const float*)d_in[0];
    const float* xm = (const float*)d_in[1];
    const int* um_src = (const int*)d_in[2];
    const int* um_dst = (const int*)d_in[3];
    const int* mu_src = (const int*)d_in[4];
    const int* mu_dst = (const int*)d_in[5];
    const int* lab_u = (const int*)d_in[6];
    const int* lab_m = (const int*)d_in[7];
    const float* w1um_s = (const float*)d_in[8];
    const float* w1um_d = (const float*)d_in[9];
    const float* a1um_s = (const float*)d_in[10];
    const float* a1um_d = (const float*)d_in[11];
    const float* b1um = (const float*)d_in[12];
    const float* w1mu_s = (const float*)d_in[13];
    const float* w1mu_d = (const float*)d_in[14];
    const float* a1mu_s = (const float*)d_in[15];
    const float* a1mu_d = (const float*)d_in[16];
    const float* b1mu = (const float*)d_in[17];
    const float* w2um_s = (const float*)d_in[18];
    const float* w2um_d = (const float*)d_in[19];
    const float* a2um_s = (const float*)d_in[20];
    const float* a2um_d = (const float*)d_in[21];
    const float* b2um = (const float*)d_in[22];
    const float* w2mu_s = (const float*)d_in[23];
    const float* w2mu_d = (const float*)d_in[24];
    const float* a2mu_s = (const float*)d_in[25];
    const float* a2mu_d = (const float*)d_in[26];
    const float* b2mu = (const float*)d_in[27];
    const float* dw1 = (const float*)d_in[28];
    const float* db1 = (const float*)d_in[29];
    const float* dw2 = (const float*)d_in[30];
    const float* db2 = (const float*)d_in[31];
    float* out = (float*)d_out;

    // -------- workspace carving --------
    char* base = (char*)d_ws;
    size_t off = 0;
    auto alloc = [&](size_t bytes) -> void* {
        void* p = base + off;
        off = (off + bytes + 63) & ~(size_t)63;
        return p;
    };
    ushort* xu_bf   = (ushort*)alloc((size_t)NU_ * 32 * 2);
    ushort* xm_bf   = (ushort*)alloc((size_t)NM_ * 128 * 2);
    ushort* hproj_u = (ushort*)alloc((size_t)NU_ * 128 * 2);
    ushort* hproj_m = (ushort*)alloc((size_t)NM_ * 128 * 2);
    ushort* zu_bf   = (ushort*)alloc((size_t)NU_ * 128 * 2);
    ushort* zm_bf   = (ushort*)alloc((size_t)NM_ * 128 * 2);
    ushort* qq_u    = (ushort*)alloc((size_t)NU_ * 64 * 2);
    ushort* qq_m    = (ushort*)alloc((size_t)NM_ * 64 * 2);
    ushort* Bt1u    = (ushort*)alloc((size_t)144 * 32 * 2);
    ushort* Bt1m    = (ushort*)alloc((size_t)144 * 128 * 2);
    ushort* Bt2u    = (ushort*)alloc((size_t)80 * 128 * 2);
    ushort* Bt2m    = (ushort*)alloc((size_t)80 * 128 * 2);
    float* hlog_u = (float*)alloc((size_t)NU_ * 16 * 4);
    float* hlog_m = (float*)alloc((size_t)NM_ * 16 * 4);
    float* qlog_u = (float*)alloc((size_t)NU_ * 8 * 4);
    float* qlog_m = (float*)alloc((size_t)NM_ * 8 * 4);
    float* pu16   = (float*)alloc((size_t)NU_ * 16 * 4);
    float* pm16   = (float*)alloc((size_t)NM_ * 16 * 4);
    float* cj     = (float*)alloc(16 * 4);
    float* zero16 = (float*)alloc(16 * 4);
    int* rp_um    = (int*)alloc((NM_ + 1) * 4);
    int* rp_mu    = (int*)alloc((NU_ + 1) * 4);
    int* ssrc_um  = (int*)alloc((size_t)NE_ * 4);
    int* sdst_um  = (int*)alloc((size_t)NE_ * 4);
    int* ssrc_mu  = (int*)alloc((size_t)NE_ * 4);
    int* sdst_mu  = (int*)alloc((size_t)NE_ * 4);
    int* ofs      = (int*)alloc((NU_ + 1) * 4);
    int* partials = (int*)alloc(64 * 4);
    if (ws_size < off) {
        fprintf(stderr, "kernel_launch: ws too small (%zu < %zu)\n", ws_size, off);
        return;
    }

    const int TB = 256;

    // -------- CSR (dst-sorted src arrays) --------
    hipMemsetAsync(ofs, 0, NM_ * sizeof(int), stream);
    count_dst<<<cdiv_i(NE_, TB), TB, 0, stream>>>(um_dst, ofs, NE_);
    {
        int nb = cdiv_i(NM_, SCHUNK);
        scan_phaseA<<<nb, 256, 0, stream>>>(ofs, partials, NM_);
        scan_phaseB<<<1, 64, 0, stream>>>(partials, nb, rp_um, NM_);
        scan_phaseC<<<nb, 256, 0, stream>>>(ofs, partials, rp_um, NM_);
    }
    copy_i32<<<cdiv_i(NM_, TB), TB, 0, stream>>>(rp_um, ofs, NM_);
    fill_perm2<<<cdiv_i(NE_, TB), TB, 0, stream>>>(um_dst, um_src, ofs, sdst_um, ssrc_um, NE_);

    hipMemsetAsync(ofs, 0, NU_ * sizeof(int), stream);
    count_dst<<<cdiv_i(NE_, TB), TB, 0, stream>>>(mu_dst, ofs, NE_);
    {
        int nb = cdiv_i(NU_, SCHUNK);
        scan_phaseA<<<nb, 256, 0, stream>>>(ofs, partials, NU_);
        scan_phaseB<<<1, 64, 0, stream>>>(partials, nb, rp_mu, NU_);
        scan_phaseC<<<nb, 256, 0, stream>>>(ofs, partials, rp_mu, NU_);
    }
    copy_i32<<<cdiv_i(NU_, TB), TB, 0, stream>>>(rp_mu, ofs, NU_);
    fill_perm2<<<cdiv_i(NE_, TB), TB, 0, stream>>>(mu_dst, mu_src, ofs, sdst_mu, ssrc_mu, NE_);

    hipMemsetAsync(zero16, 0, 16 * sizeof(float), stream);

    // -------- input casts + B^T builders --------
    conv_f2bf4<<<cdiv_i(NU_ * 32 / 4, TB), TB, 0, stream>>>(xu, xu_bf, NU_ * 32 / 4);
    conv_f2bf4<<<cdiv_i(NM_ * 128 / 4, TB), TB, 0, stream>>>(xm, xm_bf, NM_ * 128 / 4);

    build_bt1<<<cdiv_i(144 * 32, TB), TB, 0, stream>>>(w1um_s, a1um_s, w1mu_d, a1mu_d, Bt1u, 32);
    build_bt1<<<cdiv_i(144 * 128, TB), TB, 0, stream>>>(w1mu_s, a1mu_s, w1um_d, a1um_d, Bt1m, 128);
    build_bt2<<<cdiv_i(80 * 128, TB), TB, 0, stream>>>(w2um_s, a2um_s, w2mu_d, a2mu_d, dw1, 512, Bt2u);
    build_bt2<<<cdiv_i(80 * 128, TB), TB, 0, stream>>>(w2mu_s, a2mu_s, w2um_d, a2um_d, dw1, 0, Bt2m);
    fold_cj<<<1, 64, 0, stream>>>(b2mu, b2um, dw1, db1, cj);

    // -------- layer-1 projections + logits (MFMA) --------
    mfma_gemm<32, 9><<<cdiv_i(NU_, 64), TB, 0, stream>>>(
        xu_bf, Bt1u, hproj_u, 128, hlog_u, 16, 128, 144, NU_);
    mfma_gemm<128, 9><<<cdiv_i(NM_, 64), TB, 0, stream>>>(
        xm_bf, Bt1m, hproj_m, 128, hlog_m, 16, 128, 144, NM_);

    // layer-1 um: src user (es = hlog_u cols 0-7), dst movie (ed = hlog_m cols 8-15)
    gat_agg_l1f<<<cdiv_i(NM_, 4), TB, 0, stream>>>(
        hproj_u, hlog_u, hlog_m + 8, rp_um, ssrc_um, b1um, zm_bf, NM_);
    // layer-1 mu
    gat_agg_l1f<<<cdiv_i(NU_, 4), TB, 0, stream>>>(
        hproj_m, hlog_m, hlog_u + 8, rp_mu, ssrc_mu, b1mu, zu_bf, NU_);

    // -------- layer-2 projections + logits (MFMA) --------
    mfma_gemm<128, 5><<<cdiv_i(NU_, 64), TB, 0, stream>>>(
        zu_bf, Bt2u, qq_u, 64, qlog_u, 8, 64, 72, NU_);
    mfma_gemm<128, 5><<<cdiv_i(NM_, 64), TB, 0, stream>>>(
        zm_bf, Bt2m, qq_m, 64, qlog_m, 8, 64, 72, NM_);

    // layer-2 um -> pm16 (bias cj)
    gat_agg_l2f<<<cdiv_i(NM_, 4), TB, 0, stream>>>(
        qq_u, qlog_u, qlog_m + 4, rp_um, ssrc_um, cj, pm16, NM_);
    // layer-2 mu -> pu16 (bias 0)
    gat_agg_l2f<<<cdiv_i(NU_, 4), TB, 0, stream>>>(
        qq_m, qlog_m, qlog_u + 4, rp_mu, ssrc_mu, zero16, pu16, NU_);

    // -------- decoder --------
    decoder16<<<cdiv_i(EL_ * 16, TB), TB, 0, stream>>>(
        pu16, pm16, lab_u, lab_m, dw2, db2, out, EL_);
}

// Round 8
// 307.769 us; speedup vs baseline: 3.1603x; 1.1331x over previous
//
#include <hip/hip_runtime.h>
#include <hip/hip_bf16.h>
#include <cstdio>

#define NU_ 100000
#define NM_ 20000
#define NE_ 250000
#define EL_ 200000
#define SCHUNK 2048

static inline int cdiv_i(int a, int b) { return (a + b - 1) / b; }

typedef __attribute__((ext_vector_type(8))) short bf16x8;
typedef __attribute__((ext_vector_type(4))) float f32x4;

__device__ __forceinline__ float bf2f(ushort u) {
    unsigned x = ((unsigned)u) << 16;
    return __builtin_bit_cast(float, x);
}
__device__ __forceinline__ ushort f2bf(float f) {
    unsigned x = __builtin_bit_cast(unsigned, f);
    x += 0x7fff + ((x >> 16) & 1);   // RNE
    return (ushort)(x >> 16);
}

// ---------------- CSR build (both graphs fused) ----------------

__global__ void count_both(const int* __restrict__ um_dst, const int* __restrict__ mu_dst,
                           int* __restrict__ cnt) {   // cnt: [NM_ | NU_]
    int i = blockIdx.x * blockDim.x + threadIdx.x;
    if (i < NE_) atomicAdd(&cnt[um_dst[i]], 1);
    else if (i < 2 * NE_) atomicAdd(&cnt[NM_ + mu_dst[i - NE_]], 1);
}

__global__ void copy_both(const int* __restrict__ rp_um, const int* __restrict__ rp_mu,
                          int* __restrict__ ofs) {
    int i = blockIdx.x * blockDim.x + threadIdx.x;
    if (i < NM_) ofs[i] = rp_um[i];
    else if (i < NM_ + NU_) ofs[i] = rp_mu[i - NM_];
}

__global__ void fill_both(const int* __restrict__ um_dst, const int* __restrict__ um_src,
                          const int* __restrict__ mu_dst, const int* __restrict__ mu_src,
                          int* __restrict__ ofs, int* __restrict__ ssrc_um,
                          int* __restrict__ ssrc_mu) {
    int i = blockIdx.x * blockDim.x + threadIdx.x;
    if (i < NE_) {
        int p = atomicAdd(&ofs[um_dst[i]], 1);
        ssrc_um[p] = um_src[i];
    } else if (i < 2 * NE_) {
        int j = i - NE_;
        int p = atomicAdd(&ofs[NM_ + mu_dst[j]], 1);
        ssrc_mu[p] = mu_src[j];
    }
}

// two-segment 3-phase scan: in = [NM_ | NU_]
__global__ __launch_bounds__(256) void scan_phaseA2(const int* __restrict__ in,
                                                    int* __restrict__ partial, int nbM) {
    __shared__ int red[256];
    int b = blockIdx.x, tid = threadIdx.x;
    const int* src; int n; int* part; int bb;
    if (b < nbM) { src = in; n = NM_; part = partial; bb = b; }
    else { src = in + NM_; n = NU_; part = partial + nbM; bb = b - nbM; }
    int base = bb * SCHUNK + tid * 8;
    int s = 0;
#pragma unroll
    for (int j = 0; j < 8; ++j) { int i = base + j; if (i < n) s += src[i]; }
    red[tid] = s;
    __syncthreads();
    for (int off = 128; off; off >>= 1) {
        if (tid < off) red[tid] += red[tid + off];
        __syncthreads();
    }
    if (tid == 0) part[bb] = red[0];
}

__global__ void scan_phaseB2(int* __restrict__ partial, int nbM, int nbU,
                             int* __restrict__ rp_um, int* __restrict__ rp_mu) {
    if (threadIdx.x == 0 && blockIdx.x == 0) {
        int run = 0;
        for (int i = 0; i < nbM; ++i) { int v = partial[i]; partial[i] = run; run += v; }
        rp_um[NM_] = run;
        run = 0;
        for (int i = 0; i < nbU; ++i) { int v = partial[nbM + i]; partial[nbM + i] = run; run += v; }
        rp_mu[NU_] = run;
    }
}

__global__ __launch_bounds__(256) void scan_phaseC2(const int* __restrict__ in,
                                                    const int* __restrict__ partial,
                                                    int* __restrict__ rp_um,
                                                    int* __restrict__ rp_mu, int nbM) {
    __shared__ int tsum[256];
    int b = blockIdx.x, tid = threadIdx.x;
    const int* src; int n; const int* part; int* outp; int bb;
    if (b < nbM) { src = in; n = NM_; part = partial; outp = rp_um; bb = b; }
    else { src = in + NM_; n = NU_; part = partial + nbM; outp = rp_mu; bb = b - nbM; }
    int base = bb * SCHUNK + tid * 8;
    int v[8];
    int s = 0;
#pragma unroll
    for (int j = 0; j < 8; ++j) { int i = base + j; v[j] = (i < n) ? src[i] : 0; s += v[j]; }
    tsum[tid] = s;
    __syncthreads();
    for (int off = 1; off < 256; off <<= 1) {
        int y = (tid >= off) ? tsum[tid - off] : 0;
        __syncthreads();
        tsum[tid] += y;
        __syncthreads();
    }
    int run = part[bb] + tsum[tid] - s;
#pragma unroll
    for (int j = 0; j < 8; ++j) { int i = base + j; if (i < n) outp[i] = run; run += v[j]; }
}

// ---------------- fp32 -> bf16 convert (both inputs fused) ----------------
__global__ void conv_two(const float* __restrict__ a, ushort* __restrict__ da, int n4a,
                         const float* __restrict__ b, ushort* __restrict__ db, int n4b) {
    int i = blockIdx.x * blockDim.x + threadIdx.x;
    const float* s; ushort* d; int idx;
    if (i < n4a) { s = a; d = da; idx = i; }
    else { idx = i - n4a; if (idx >= n4b) return; s = b; d = db; }
    float4 v = ((const float4*)s)[idx];
    ushort4 o;
    o.x = f2bf(v.x); o.y = f2bf(v.y); o.z = f2bf(v.z); o.w = f2bf(v.w);
    ((ushort4*)d)[idx] = o;
}

// ---------------- B^T builders (bf16, [col][k]) ----------------
__global__ void build_bt1(const float* __restrict__ Ws, const float* __restrict__ as_,
                          const float* __restrict__ Wd, const float* __restrict__ ad,
                          ushort* __restrict__ Bt, int K) {
    int i = blockIdx.x * blockDim.x + threadIdx.x;
    if (i >= 144 * K) return;
    int c = i / K, k = i % K;
    float v;
    if (c < 128) {
        v = Ws[(size_t)k * 128 + c];
    } else if (c < 136) {
        int h = c - 128; v = 0.f;
        for (int cc = 0; cc < 16; ++cc) v += Ws[(size_t)k * 128 + h * 16 + cc] * as_[h * 16 + cc];
    } else {
        int h = c - 136; v = 0.f;
        for (int cc = 0; cc < 16; ++cc) v += Wd[(size_t)k * 128 + h * 16 + cc] * ad[h * 16 + cc];
    }
    Bt[(size_t)c * K + k] = f2bf(v);
}

__global__ void build_bt2(const float* __restrict__ Ws, const float* __restrict__ as_,
                          const float* __restrict__ Wd, const float* __restrict__ ad,
                          const float* __restrict__ dw1, int rowoff, ushort* __restrict__ Bt) {
    int i = blockIdx.x * blockDim.x + threadIdx.x;
    if (i >= 80 * 128) return;
    int c = i >> 7, k = i & 127;
    float v = 0.f;
    if (c < 64) {
        int h = c >> 4, j = c & 15;
        for (int cc = 0; cc < 128; ++cc)
            v += Ws[(size_t)k * 512 + h * 128 + cc] * dw1[(size_t)(rowoff + h * 128 + cc) * 16 + j];
    } else if (c < 68) {
        int h = c - 64;
        for (int cc = 0; cc < 128; ++cc) v += Ws[(size_t)k * 512 + h * 128 + cc] * as_[h * 128 + cc];
    } else if (c < 72) {
        int h = c - 68;
        for (int cc = 0; cc < 128; ++cc) v += Wd[(size_t)k * 512 + h * 128 + cc] * ad[h * 128 + cc];
    }
    Bt[(size_t)c * 128 + k] = f2bf(v);
}

__global__ void fold_cj(const float* __restrict__ b2mu, const float* __restrict__ b2um,
                        const float* __restrict__ dw1, const float* __restrict__ db1,
                        float* __restrict__ cj) {
    int j = threadIdx.x;
    if (j >= 16) return;
    float s = db1[j];
    for (int col = 0; col < 512; ++col)
        s += b2mu[col] * dw1[col * 16 + j] + b2um[col] * dw1[(512 + col) * 16 + j];
    cj[j] = s;
}

// ---------------- MFMA GEMM ----------------
template <int K, int NT>
__global__ __launch_bounds__(256) void mfma_gemm(
    const ushort* __restrict__ A, const ushort* __restrict__ Bt,
    ushort* __restrict__ outb, int sb, float* __restrict__ outf, int sf,
    int splitc, int maxc, int Nrows) {
    int wave = threadIdx.x >> 6;
    int lane = threadIdx.x & 63;
    int row0 = (blockIdx.x * 4 + wave) * 16;
    if (row0 >= Nrows) return;
    int r = lane & 15;
    int kb = lane >> 4;
    bf16x8 afrag[K / 32];
    int arow = row0 + r;
    bool rowok = (arow < Nrows);
#pragma unroll
    for (int ks = 0; ks < K / 32; ++ks) {
        if (rowok)
            afrag[ks] = *(const bf16x8*)(A + (size_t)arow * K + ks * 32 + kb * 8);
        else
            afrag[ks] = (bf16x8){0, 0, 0, 0, 0, 0, 0, 0};
    }
#pragma unroll
    for (int nt = 0; nt < NT; ++nt) {
        f32x4 acc = {0.f, 0.f, 0.f, 0.f};
#pragma unroll
        for (int ks = 0; ks < K / 32; ++ks) {
            bf16x8 bfrag = *(const bf16x8*)(Bt + (size_t)(nt * 16 + r) * K + ks * 32 + kb * 8);
            acc = __builtin_amdgcn_mfma_f32_16x16x32_bf16(afrag[ks], bfrag, acc, 0, 0, 0);
        }
        int col = nt * 16 + r;
#pragma unroll
        for (int reg = 0; reg < 4; ++reg) {
            int rr = row0 + kb * 4 + reg;
            if (rr < Nrows) {
                if (col < splitc)
                    outb[(size_t)rr * sb + col] = f2bf(acc[reg]);
                else if (col < maxc)
                    outf[(size_t)rr * sf + (col - splitc)] = acc[reg];
            }
        }
    }
}

// ---------------- merged layer-1 aggregation (both directions, per-lane heads) ----------------
// lane owns cols {2l, 2l+1}, head hh = l>>3; no cross-lane ops in edge loop
__global__ __launch_bounds__(256) void gat_agg_l1m(
    const ushort* __restrict__ hsA, const float* __restrict__ esA,
    const float* __restrict__ edA, const int* __restrict__ rpA,
    const int* __restrict__ srcA, const float* __restrict__ biasA,
    ushort* __restrict__ outA, int NdA,
    const ushort* __restrict__ hsB, const float* __restrict__ esB,
    const float* __restrict__ edB, const int* __restrict__ rpB,
    const int* __restrict__ srcB, const float* __restrict__ biasB,
    ushort* __restrict__ outB, int NdB) {
    int wid = (blockIdx.x * 256 + threadIdx.x) >> 6;
    int lane = threadIdx.x & 63;
    const ushort* hs; const float* eslog; const float* edlog; const int* rowptr;
    const int* ssrc; const float* bias; ushort* outz; int nd;
    if (wid < NdA) {
        hs = hsA; eslog = esA; edlog = edA; rowptr = rpA; ssrc = srcA;
        bias = biasA; outz = outA; nd = wid;
    } else {
        nd = wid - NdA;
        if (nd >= NdB) return;
        hs = hsB; eslog = esB; edlog = edB; rowptr = rpB; ssrc = srcB;
        bias = biasB; outz = outB;
    }
    int r0 = rowptr[nd], r1 = rowptr[nd + 1];
    int hh = lane >> 3;
    float edv = edlog[(size_t)nd * 16 + hh];
    float ssum = 0.f, acc0 = 0.f, acc1 = 0.f;
    for (int base = r0; base < r1; base += 64) {
        int cnt = min(64, r1 - base);
        int sv = (base + lane < r1) ? ssrc[base + lane] : 0;
#pragma unroll 4
        for (int j = 0; j < cnt; ++j) {
            int s = __shfl(sv, j, 64);
            float x = eslog[(size_t)s * 16 + hh] + edv;
            x = x > 0.f ? x : 0.2f * x;
            float w = __expf(x);
            ssum += w;
            unsigned hv = *(const unsigned*)(hs + (size_t)s * 128 + 2 * lane);
            acc0 = fmaf(bf2f((ushort)(hv & 0xffffu)), w, acc0);
            acc1 = fmaf(bf2f((ushort)(hv >> 16)), w, acc1);
        }
    }
    float inv = 1.f / (ssum + 1e-16f);
    float v0 = fmaxf(fmaf(acc0, inv, bias[2 * lane]), 0.f);
    float v1 = fmaxf(fmaf(acc1, inv, bias[2 * lane + 1]), 0.f);
    unsigned o = (unsigned)f2bf(v0) | ((unsigned)f2bf(v1) << 16);
    *(unsigned*)(outz + (size_t)nd * 128 + 2 * lane) = o;
}

// ---------------- merged layer-2 aggregation (both directions, per-lane heads) ----------------
// lane owns col l of 64; head hh = l>>4; head-summed 16-wide f32 out
__global__ __launch_bounds__(256) void gat_agg_l2m(
    const ushort* __restrict__ qA, const float* __restrict__ esA,
    const float* __restrict__ edA, const int* __restrict__ rpA,
    const int* __restrict__ srcA, const float* __restrict__ biasA,
    float* __restrict__ outA, int NdA,
    const ushort* __restrict__ qB, const float* __restrict__ esB,
    const float* __restrict__ edB, const int* __restrict__ rpB,
    const int* __restrict__ srcB, const float* __restrict__ biasB,
    float* __restrict__ outB, int NdB) {
    int wid = (blockIdx.x * 256 + threadIdx.x) >> 6;
    int lane = threadIdx.x & 63;
    const ushort* q; const float* eslog; const float* edlog; const int* rowptr;
    const int* ssrc; const float* bias16; float* out16; int nd;
    if (wid < NdA) {
        q = qA; eslog = esA; edlog = edA; rowptr = rpA; ssrc = srcA;
        bias16 = biasA; out16 = outA; nd = wid;
    } else {
        nd = wid - NdA;
        if (nd >= NdB) return;
        q = qB; eslog = esB; edlog = edB; rowptr = rpB; ssrc = srcB;
        bias16 = biasB; out16 = outB;
    }
    int r0 = rowptr[nd], r1 = rowptr[nd + 1];
    int hh = lane >> 4;
    float edv = edlog[(size_t)nd * 8 + hh];
    float ssum = 0.f, acc = 0.f;
    for (int base = r0; base < r1; base += 64) {
        int cnt = min(64, r1 - base);
        int sv = (base + lane < r1) ? ssrc[base + lane] : 0;
#pragma unroll 4
        for (int j = 0; j < cnt; ++j) {
            int s = __shfl(sv, j, 64);
            float x = eslog[(size_t)s * 8 + hh] + edv;
            x = x > 0.f ? x : 0.2f * x;
            float w = __expf(x);
            ssum += w;
            acc = fmaf(bf2f(q[(size_t)s * 64 + lane]), w, acc);
        }
    }
    float inv = 1.f / (ssum + 1e-16f);
    acc *= inv;
    acc += __shfl_xor(acc, 16, 64);
    acc += __shfl_xor(acc, 32, 64);
    if (lane < 16) out16[(size_t)nd * 16 + lane] = acc + bias16[lane];
}

// ---------------- decoder: 16 lanes per label edge ----------------
__global__ __launch_bounds__(256) void decoder16(
    const float* __restrict__ pu16, const float* __restrict__ pm16,
    const int* __restrict__ lab_u, const int* __restrict__ lab_m,
    const float* __restrict__ dw2, const float* __restrict__ db2,
    float* __restrict__ out, int nE) {
    int t = blockIdx.x * 256 + threadIdx.x;
    int e = t >> 4, j = t & 15;
    if (e >= nE) return;
    int u = lab_u[e], m = lab_m[e];
    float v = pu16[(size_t)u * 16 + j] + pm16[(size_t)m * 16 + j];
    float r = fmaxf(v, 0.f) * dw2[j];
    r += __shfl_xor(r, 1, 16);
    r += __shfl_xor(r, 2, 16);
    r += __shfl_xor(r, 4, 16);
    r += __shfl_xor(r, 8, 16);
    if (j == 0) out[e] = r + db2[0];
}

// ---------------- host ----------------

extern "C" void kernel_launch(void* const* d_in, const int* in_sizes, int n_in,
                              void* d_out, int out_size, void* d_ws, size_t ws_size,
                              hipStream_t stream) {
    const float* xu = (const float*)d_in[0];
    const float* xm = (const float*)d_in[1];
    const int* um_src = (const int*)d_in[2];
    const int* um_dst = (const int*)d_in[3];
    const int* mu_src = (const int*)d_in[4];
    const int* mu_dst = (const int*)d_in[5];
    const int* lab_u = (const int*)d_in[6];
    const int* lab_m = (const int*)d_in[7];
    const float* w1um_s = (const float*)d_in[8];
    const float* w1um_d = (const float*)d_in[9];
    const float* a1um_s = (const float*)d_in[10];
    const float* a1um_d = (const float*)d_in[11];
    const float* b1um = (const float*)d_in[12];
    const float* w1mu_s = (const float*)d_in[13];
    const float* w1mu_d = (const float*)d_in[14];
    const float* a1mu_s = (const float*)d_in[15];
    const float* a1mu_d = (const float*)d_in[16];
    const float* b1mu = (const float*)d_in[17];
    const float* w2um_s = (const float*)d_in[18];
    const float* w2um_d = (const float*)d_in[19];
    const float* a2um_s = (const float*)d_in[20];
    const float* a2um_d = (const float*)d_in[21];
    const float* b2um = (const float*)d_in[22];
    const float* w2mu_s = (const float*)d_in[23];
    const float* w2mu_d = (const float*)d_in[24];
    const float* a2mu_s = (const float*)d_in[25];
    const float* a2mu_d = (const float*)d_in[26];
    const float* b2mu = (const float*)d_in[27];
    const float* dw1 = (const float*)d_in[28];
    const float* db1 = (const float*)d_in[29];
    const float* dw2 = (const float*)d_in[30];
    const float* db2 = (const float*)d_in[31];
    float* out = (float*)d_out;

    // -------- workspace carving --------
    char* base = (char*)d_ws;
    size_t off = 0;
    auto alloc = [&](size_t bytes) -> void* {
        void* p = base + off;
        off = (off + bytes + 63) & ~(size_t)63;
        return p;
    };
    ushort* xu_bf   = (ushort*)alloc((size_t)NU_ * 32 * 2);
    ushort* xm_bf   = (ushort*)alloc((size_t)NM_ * 128 * 2);
    ushort* hproj_u = (ushort*)alloc((size_t)NU_ * 128 * 2);
    ushort* hproj_m = (ushort*)alloc((size_t)NM_ * 128 * 2);
    ushort* zu_bf   = (ushort*)alloc((size_t)NU_ * 128 * 2);
    ushort* zm_bf   = (ushort*)alloc((size_t)NM_ * 128 * 2);
    ushort* qq_u    = (ushort*)alloc((size_t)NU_ * 64 * 2);
    ushort* qq_m    = (ushort*)alloc((size_t)NM_ * 64 * 2);
    ushort* Bt1u    = (ushort*)alloc((size_t)144 * 32 * 2);
    ushort* Bt1m    = (ushort*)alloc((size_t)144 * 128 * 2);
    ushort* Bt2u    = (ushort*)alloc((size_t)80 * 128 * 2);
    ushort* Bt2m    = (ushort*)alloc((size_t)80 * 128 * 2);
    float* hlog_u = (float*)alloc((size_t)NU_ * 16 * 4);
    float* hlog_m = (float*)alloc((size_t)NM_ * 16 * 4);
    float* qlog_u = (float*)alloc((size_t)NU_ * 8 * 4);
    float* qlog_m = (float*)alloc((size_t)NM_ * 8 * 4);
    float* pu16   = (float*)alloc((size_t)NU_ * 16 * 4);
    float* pm16   = (float*)alloc((size_t)NM_ * 16 * 4);
    float* cj     = (float*)alloc(16 * 4);
    float* zero16 = (float*)alloc(16 * 4);
    int* rp_um    = (int*)alloc((NM_ + 1) * 4);
    int* rp_mu    = (int*)alloc((NU_ + 1) * 4);
    int* ssrc_um  = (int*)alloc((size_t)NE_ * 4);
    int* ssrc_mu  = (int*)alloc((size_t)NE_ * 4);
    int* ofs      = (int*)alloc((size_t)(NM_ + NU_) * 4);   // [NM_ | NU_]
    int* partials = (int*)alloc(128 * 4);
    if (ws_size < off) {
        fprintf(stderr, "kernel_launch: ws too small (%zu < %zu)\n", ws_size, off);
        return;
    }

    const int TB = 256;
    const int nbM = cdiv_i(NM_, SCHUNK);   // 10
    const int nbU = cdiv_i(NU_, SCHUNK);   // 49

    // -------- CSR (both graphs, fused) --------
    hipMemsetAsync(ofs, 0, (size_t)(NM_ + NU_) * sizeof(int), stream);
    count_both<<<cdiv_i(2 * NE_, TB), TB, 0, stream>>>(um_dst, mu_dst, ofs);
    scan_phaseA2<<<nbM + nbU, 256, 0, stream>>>(ofs, partials, nbM);
    scan_phaseB2<<<1, 64, 0, stream>>>(partials, nbM, nbU, rp_um, rp_mu);
    scan_phaseC2<<<nbM + nbU, 256, 0, stream>>>(ofs, partials, rp_um, rp_mu, nbM);
    copy_both<<<cdiv_i(NM_ + NU_, TB), TB, 0, stream>>>(rp_um, rp_mu, ofs);
    fill_both<<<cdiv_i(2 * NE_, TB), TB, 0, stream>>>(
        um_dst, um_src, mu_dst, mu_src, ofs, ssrc_um, ssrc_mu);

    hipMemsetAsync(zero16, 0, 16 * sizeof(float), stream);

    // -------- input casts + B^T builders --------
    conv_two<<<cdiv_i((NU_ * 32 + NM_ * 128) / 4, TB), TB, 0, stream>>>(
        xu, xu_bf, NU_ * 32 / 4, xm, xm_bf, NM_ * 128 / 4);

    build_bt1<<<cdiv_i(144 * 32, TB), TB, 0, stream>>>(w1um_s, a1um_s, w1mu_d, a1mu_d, Bt1u, 32);
    build_bt1<<<cdiv_i(144 * 128, TB), TB, 0, stream>>>(w1mu_s, a1mu_s, w1um_d, a1um_d, Bt1m, 128);
    build_bt2<<<cdiv_i(80 * 128, TB), TB, 0, stream>>>(w2um_s, a2um_s, w2mu_d, a2mu_d, dw1, 512, Bt2u);
    build_bt2<<<cdiv_i(80 * 128, TB), TB, 0, stream>>>(w2mu_s, a2mu_s, w2um_d, a2um_d, dw1, 0, Bt2m);
    fold_cj<<<1, 64, 0, stream>>>(b2mu, b2um, dw1, db1, cj);

    // -------- layer-1 projections + logits (MFMA) --------
    mfma_gemm<32, 9><<<cdiv_i(NU_, 64), TB, 0, stream>>>(
        xu_bf, Bt1u, hproj_u, 128, hlog_u, 16, 128, 144, NU_);
    mfma_gemm<128, 9><<<cdiv_i(NM_, 64), TB, 0, stream>>>(
        xm_bf, Bt1m, hproj_m, 128, hlog_m, 16, 128, 144, NM_);

    // -------- layer-1 aggregation, both directions in one dispatch --------
    // A: dst=movie (um): hs=hproj_u, es=hlog_u(0-7), ed=hlog_m(8-15), out zm_bf
    // B: dst=user  (mu): hs=hproj_m, es=hlog_m(0-7), ed=hlog_u(8-15), out zu_bf
    gat_agg_l1m<<<cdiv_i(NM_ + NU_, 4), TB, 0, stream>>>(
        hproj_u, hlog_u, hlog_m + 8, rp_um, ssrc_um, b1um, zm_bf, NM_,
        hproj_m, hlog_m, hlog_u + 8, rp_mu, ssrc_mu, b1mu, zu_bf, NU_);

    // -------- layer-2 projections + logits (MFMA) --------
    mfma_gemm<128, 5><<<cdiv_i(NU_, 64), TB, 0, stream>>>(
        zu_bf, Bt2u, qq_u, 64, qlog_u, 8, 64, 72, NU_);
    mfma_gemm<128, 5><<<cdiv_i(NM_, 64), TB, 0, stream>>>(
        zm_bf, Bt2m, qq_m, 64, qlog_m, 8, 64, 72, NM_);

    // -------- layer-2 aggregation, both directions in one dispatch --------
    gat_agg_l2m<<<cdiv_i(NM_ + NU_, 4), TB, 0, stream>>>(
        qq_u, qlog_u, qlog_m + 4, rp_um, ssrc_um, cj, pm16, NM_,
        qq_m, qlog_m, qlog_u + 4, rp_mu, ssrc_mu, zero16, pu16, NU_);

    // -------- decoder --------
    decoder16<<<cdiv_i(EL_ * 16, TB), TB, 0, stream>>>(
        pu16, pm16, lab_u, lab_m, dw2, db2, out, EL_);
}

// Round 9
// 283.572 us; speedup vs baseline: 3.4300x; 1.0853x over previous
//
#include <hip/hip_runtime.h>
#include <hip/hip_bf16.h>
#include <cstdio>

#define NU_ 100000
#define NM_ 20000
#define NE_ 250000
#define EL_ 200000
#define SCHUNK 2048

static inline int cdiv_i(int a, int b) { return (a + b - 1) / b; }

typedef __attribute__((ext_vector_type(8))) short bf16x8;
typedef __attribute__((ext_vector_type(4))) float f32x4;

__device__ __forceinline__ float bf2f(ushort u) {
    unsigned x = ((unsigned)u) << 16;
    return __builtin_bit_cast(float, x);
}
__device__ __forceinline__ ushort f2bf(float f) {
    unsigned x = __builtin_bit_cast(unsigned, f);
    x += 0x7fff + ((x >> 16) & 1);   // RNE
    return (ushort)(x >> 16);
}

// ---------------- CSR build (both graphs fused) ----------------

__global__ void count_both(const int* __restrict__ um_dst, const int* __restrict__ mu_dst,
                           int* __restrict__ cnt) {   // cnt: [NM_ | NU_]
    int i = blockIdx.x * blockDim.x + threadIdx.x;
    if (i < NE_) atomicAdd(&cnt[um_dst[i]], 1);
    else if (i < 2 * NE_) atomicAdd(&cnt[NM_ + mu_dst[i - NE_]], 1);
}

__global__ void copy_both(const int* __restrict__ rp_um, const int* __restrict__ rp_mu,
                          int* __restrict__ ofs) {
    int i = blockIdx.x * blockDim.x + threadIdx.x;
    if (i < NM_) ofs[i] = rp_um[i];
    else if (i < NM_ + NU_) ofs[i] = rp_mu[i - NM_];
}

__global__ void fill_both(const int* __restrict__ um_dst, const int* __restrict__ um_src,
                          const int* __restrict__ mu_dst, const int* __restrict__ mu_src,
                          int* __restrict__ ofs, int* __restrict__ ssrc_um,
                          int* __restrict__ ssrc_mu) {
    int i = blockIdx.x * blockDim.x + threadIdx.x;
    if (i < NE_) {
        int p = atomicAdd(&ofs[um_dst[i]], 1);
        ssrc_um[p] = um_src[i];
    } else if (i < 2 * NE_) {
        int j = i - NE_;
        int p = atomicAdd(&ofs[NM_ + mu_dst[j]], 1);
        ssrc_mu[p] = mu_src[j];
    }
}

__global__ __launch_bounds__(256) void scan_phaseA2(const int* __restrict__ in,
                                                    int* __restrict__ partial, int nbM) {
    __shared__ int red[256];
    int b = blockIdx.x, tid = threadIdx.x;
    const int* src; int n; int* part; int bb;
    if (b < nbM) { src = in; n = NM_; part = partial; bb = b; }
    else { src = in + NM_; n = NU_; part = partial + nbM; bb = b - nbM; }
    int base = bb * SCHUNK + tid * 8;
    int s = 0;
#pragma unroll
    for (int j = 0; j < 8; ++j) { int i = base + j; if (i < n) s += src[i]; }
    red[tid] = s;
    __syncthreads();
    for (int off = 128; off; off >>= 1) {
        if (tid < off) red[tid] += red[tid + off];
        __syncthreads();
    }
    if (tid == 0) part[bb] = red[0];
}

__global__ void scan_phaseB2(int* __restrict__ partial, int nbM, int nbU,
                             int* __restrict__ rp_um, int* __restrict__ rp_mu) {
    if (threadIdx.x == 0 && blockIdx.x == 0) {
        int run = 0;
        for (int i = 0; i < nbM; ++i) { int v = partial[i]; partial[i] = run; run += v; }
        rp_um[NM_] = run;
        run = 0;
        for (int i = 0; i < nbU; ++i) { int v = partial[nbM + i]; partial[nbM + i] = run; run += v; }
        rp_mu[NU_] = run;
    }
}

__global__ __launch_bounds__(256) void scan_phaseC2(const int* __restrict__ in,
                                                    const int* __restrict__ partial,
                                                    int* __restrict__ rp_um,
                                                    int* __restrict__ rp_mu, int nbM) {
    __shared__ int tsum[256];
    int b = blockIdx.x, tid = threadIdx.x;
    const int* src; int n; const int* part; int* outp; int bb;
    if (b < nbM) { src = in; n = NM_; part = partial; outp = rp_um; bb = b; }
    else { src = in + NM_; n = NU_; part = partial + nbM; outp = rp_mu; bb = b - nbM; }
    int base = bb * SCHUNK + tid * 8;
    int v[8];
    int s = 0;
#pragma unroll
    for (int j = 0; j < 8; ++j) { int i = base + j; v[j] = (i < n) ? src[i] : 0; s += v[j]; }
    tsum[tid] = s;
    __syncthreads();
    for (int off = 1; off < 256; off <<= 1) {
        int y = (tid >= off) ? tsum[tid - off] : 0;
        __syncthreads();
        tsum[tid] += y;
        __syncthreads();
    }
    int run = part[bb] + tsum[tid] - s;
#pragma unroll
    for (int j = 0; j < 8; ++j) { int i = base + j; if (i < n) outp[i] = run; run += v[j]; }
}

// ---------------- fp32 -> bf16 convert (both inputs fused) ----------------
__global__ void conv_two(const float* __restrict__ a, ushort* __restrict__ da, int n4a,
                         const float* __restrict__ b, ushort* __restrict__ db, int n4b) {
    int i = blockIdx.x * blockDim.x + threadIdx.x;
    const float* s; ushort* d; int idx;
    if (i < n4a) { s = a; d = da; idx = i; }
    else { idx = i - n4a; if (idx >= n4b) return; s = b; d = db; }
    float4 v = ((const float4*)s)[idx];
    ushort4 o;
    o.x = f2bf(v.x); o.y = f2bf(v.y); o.z = f2bf(v.z); o.w = f2bf(v.w);
    ((ushort4*)d)[idx] = o;
}

// ---------------- B^T builders (bf16, [col][k]) ----------------
// NU layer-1: only 16 logit cols, K=32
__global__ void build_bt1u_log(const float* __restrict__ Ws, const float* __restrict__ as_,
                               const float* __restrict__ Wd, const float* __restrict__ ad,
                               ushort* __restrict__ Bt) {
    int i = blockIdx.x * blockDim.x + threadIdx.x;
    if (i >= 16 * 32) return;
    int c = i >> 5, k = i & 31;
    float v = 0.f;
    if (c < 8) {
        for (int cc = 0; cc < 16; ++cc) v += Ws[(size_t)k * 128 + c * 16 + cc] * as_[c * 16 + cc];
    } else {
        int h = c - 8;
        for (int cc = 0; cc < 16; ++cc) v += Wd[(size_t)k * 128 + h * 16 + cc] * ad[h * 16 + cc];
    }
    Bt[c * 32 + k] = f2bf(v);
}

// NM layer-1: 144 cols = [128 proj | 8 es | 8 ed], K=128
__global__ void build_bt1(const float* __restrict__ Ws, const float* __restrict__ as_,
                          const float* __restrict__ Wd, const float* __restrict__ ad,
                          ushort* __restrict__ Bt, int K) {
    int i = blockIdx.x * blockDim.x + threadIdx.x;
    if (i >= 144 * K) return;
    int c = i / K, k = i % K;
    float v;
    if (c < 128) {
        v = Ws[(size_t)k * 128 + c];
    } else if (c < 136) {
        int h = c - 128; v = 0.f;
        for (int cc = 0; cc < 16; ++cc) v += Ws[(size_t)k * 128 + h * 16 + cc] * as_[h * 16 + cc];
    } else {
        int h = c - 136; v = 0.f;
        for (int cc = 0; cc < 16; ++cc) v += Wd[(size_t)k * 128 + h * 16 + cc] * ad[h * 16 + cc];
    }
    Bt[(size_t)c * K + k] = f2bf(v);
}

// projection of per-head aggregated raw x: 128 cols, K=256 (block-diag over heads)
__global__ void build_btp(const float* __restrict__ W, ushort* __restrict__ Bt) {
    int i = blockIdx.x * blockDim.x + threadIdx.x;
    if (i >= 128 * 256) return;
    int c = i >> 8, kk = i & 255;
    int h = kk >> 5, k = kk & 31;
    float v = ((c >> 4) == h) ? W[(size_t)k * 128 + c] : 0.f;
    Bt[(size_t)c * 256 + kk] = f2bf(v);
}

__global__ void build_bt2(const float* __restrict__ Ws, const float* __restrict__ as_,
                          const float* __restrict__ Wd, const float* __restrict__ ad,
                          const float* __restrict__ dw1, int rowoff, ushort* __restrict__ Bt) {
    int i = blockIdx.x * blockDim.x + threadIdx.x;
    if (i >= 80 * 128) return;
    int c = i >> 7, k = i & 127;
    float v = 0.f;
    if (c < 64) {
        int h = c >> 4, j = c & 15;
        for (int cc = 0; cc < 128; ++cc)
            v += Ws[(size_t)k * 512 + h * 128 + cc] * dw1[(size_t)(rowoff + h * 128 + cc) * 16 + j];
    } else if (c < 68) {
        int h = c - 64;
        for (int cc = 0; cc < 128; ++cc) v += Ws[(size_t)k * 512 + h * 128 + cc] * as_[h * 128 + cc];
    } else if (c < 72) {
        int h = c - 68;
        for (int cc = 0; cc < 128; ++cc) v += Wd[(size_t)k * 512 + h * 128 + cc] * ad[h * 128 + cc];
    }
    Bt[(size_t)c * 128 + k] = f2bf(v);
}

__global__ void fold_cj(const float* __restrict__ b2mu, const float* __restrict__ b2um,
                        const float* __restrict__ dw1, const float* __restrict__ db1,
                        float* __restrict__ cj) {
    int j = threadIdx.x;
    if (j >= 16) return;
    float s = db1[j];
    for (int col = 0; col < 512; ++col)
        s += b2mu[col] * dw1[col * 16 + j] + b2um[col] * dw1[(512 + col) * 16 + j];
    cj[j] = s;
}

// ---------------- MFMA GEMM (optional bias+relu on bf16 cols) ----------------
template <int K, int NT>
__global__ __launch_bounds__(256) void mfma_gemm(
    const ushort* __restrict__ A, const ushort* __restrict__ Bt,
    ushort* __restrict__ outb, int sb, float* __restrict__ outf, int sf,
    int splitc, int maxc, int Nrows, const float* __restrict__ bias, int dorelu) {
    int wave = threadIdx.x >> 6;
    int lane = threadIdx.x & 63;
    int row0 = (blockIdx.x * 4 + wave) * 16;
    if (row0 >= Nrows) return;
    int r = lane & 15;
    int kb = lane >> 4;
    bf16x8 afrag[K / 32];
    int arow = row0 + r;
    bool rowok = (arow < Nrows);
#pragma unroll
    for (int ks = 0; ks < K / 32; ++ks) {
        if (rowok)
            afrag[ks] = *(const bf16x8*)(A + (size_t)arow * K + ks * 32 + kb * 8);
        else
            afrag[ks] = (bf16x8){0, 0, 0, 0, 0, 0, 0, 0};
    }
#pragma unroll
    for (int nt = 0; nt < NT; ++nt) {
        f32x4 acc = {0.f, 0.f, 0.f, 0.f};
#pragma unroll
        for (int ks = 0; ks < K / 32; ++ks) {
            bf16x8 bfrag = *(const bf16x8*)(Bt + (size_t)(nt * 16 + r) * K + ks * 32 + kb * 8);
            acc = __builtin_amdgcn_mfma_f32_16x16x32_bf16(afrag[ks], bfrag, acc, 0, 0, 0);
        }
        int col = nt * 16 + r;
        float bv = (bias && col < splitc) ? bias[col] : 0.f;
#pragma unroll
        for (int reg = 0; reg < 4; ++reg) {
            int rr = row0 + kb * 4 + reg;
            if (rr < Nrows) {
                if (col < splitc) {
                    float v = acc[reg] + bv;
                    if (dorelu) v = fmaxf(v, 0.f);
                    outb[(size_t)rr * sb + col] = f2bf(v);
                } else if (col < maxc) {
                    outf[(size_t)rr * sf + (col - splitc)] = acc[reg];
                }
            }
        }
    }
}

// ---------------- layer-1 um: per-head aggregation of RAW xu (32-dim) ----------------
// one wave per movie dst; lane: head h=lane>>3, cols c4=(lane&7)*4 of x
__global__ __launch_bounds__(256) void agg_raw_um(
    const ushort* __restrict__ xu_bf, const float* __restrict__ hlog_u,
    const float* __restrict__ hlog_m, const int* __restrict__ rp,
    const int* __restrict__ ssrc, ushort* __restrict__ aggx, int Nd) {
    int wid = (blockIdx.x * 256 + threadIdx.x) >> 6;
    int lane = threadIdx.x & 63;
    if (wid >= Nd) return;
    int h = lane >> 3, c4 = (lane & 7) * 4;
    int r0 = rp[wid], r1 = rp[wid + 1];
    float edv = hlog_m[(size_t)wid * 16 + 8 + h];
    float ssum = 0.f, a0 = 0.f, a1 = 0.f, a2 = 0.f, a3 = 0.f;
    for (int base = r0; base < r1; base += 64) {
        int cnt = min(64, r1 - base);
        int sv = (base + lane < r1) ? ssrc[base + lane] : 0;
        for (int j = 0; j < cnt; ++j) {
            int s = __shfl(sv, j, 64);
            float x = hlog_u[(size_t)s * 16 + h] + edv;
            x = x > 0.f ? x : 0.2f * x;
            float w = __expf(x);
            ssum += w;
            ushort4 xv = *(const ushort4*)(xu_bf + (size_t)s * 32 + c4);
            a0 = fmaf(bf2f(xv.x), w, a0);
            a1 = fmaf(bf2f(xv.y), w, a1);
            a2 = fmaf(bf2f(xv.z), w, a2);
            a3 = fmaf(bf2f(xv.w), w, a3);
        }
    }
    float inv = 1.f / (ssum + 1e-16f);
    ushort4 o;
    o.x = f2bf(a0 * inv); o.y = f2bf(a1 * inv);
    o.z = f2bf(a2 * inv); o.w = f2bf(a3 * inv);
    *(ushort4*)(aggx + (size_t)wid * 256 + h * 32 + c4) = o;
}

// ---------------- layer-1 mu: gather hproj_m (L2-resident), 2 dsts/wave ----------------
// 32 lanes per dst; lane owns cols 4l..4l+3 (head h=l>>2); bias+relu fused
__global__ __launch_bounds__(256) void agg_l1_mu(
    const ushort* __restrict__ hproj_m, const float* __restrict__ hlog_m,
    const float* __restrict__ hlog_u, const int* __restrict__ rp,
    const int* __restrict__ ssrc, const float* __restrict__ bias,
    ushort* __restrict__ zu, int Nd) {
    int wid = (blockIdx.x * 256 + threadIdx.x) >> 6;
    int lane = threadIdx.x & 63;
    int g = lane >> 5, l = lane & 31;
    int dst = wid * 2 + g;
    if (dst >= Nd) return;
    int h = l >> 2, c4 = l * 4;
    int r0 = rp[dst], r1 = rp[dst + 1];
    float edv = hlog_u[(size_t)dst * 16 + 8 + h];
    float ssum = 0.f, a0 = 0.f, a1 = 0.f, a2 = 0.f, a3 = 0.f;
    for (int base = r0; base < r1; base += 32) {
        int cnt = min(32, r1 - base);
        int sv = (base + l < r1) ? ssrc[base + l] : 0;
        for (int j = 0; j < cnt; ++j) {
            int s = __shfl(sv, (g << 5) | j, 64);
            float x = hlog_m[(size_t)s * 16 + h] + edv;
            x = x > 0.f ? x : 0.2f * x;
            float w = __expf(x);
            ssum += w;
            ushort4 hv = *(const ushort4*)(hproj_m + (size_t)s * 128 + c4);
            a0 = fmaf(bf2f(hv.x), w, a0);
            a1 = fmaf(bf2f(hv.y), w, a1);
            a2 = fmaf(bf2f(hv.z), w, a2);
            a3 = fmaf(bf2f(hv.w), w, a3);
        }
    }
    float inv = 1.f / (ssum + 1e-16f);
    float v0 = fmaxf(fmaf(a0, inv, bias[c4 + 0]), 0.f);
    float v1 = fmaxf(fmaf(a1, inv, bias[c4 + 1]), 0.f);
    float v2 = fmaxf(fmaf(a2, inv, bias[c4 + 2]), 0.f);
    float v3 = fmaxf(fmaf(a3, inv, bias[c4 + 3]), 0.f);
    ushort4 o;
    o.x = f2bf(v0); o.y = f2bf(v1); o.z = f2bf(v2); o.w = f2bf(v3);
    *(ushort4*)(zu + (size_t)dst * 128 + c4) = o;
}

// ---------------- layer-2 aggregation, both directions, 4 dsts/wave ----------------
// 16 lanes per dst; lane owns q cols 4l..4l+3 (head h=l>>2); head-sum via 2 shfl_xor
__global__ __launch_bounds__(256) void agg_l2_m(
    const ushort* __restrict__ qA, const float* __restrict__ esA,
    const float* __restrict__ edA, const int* __restrict__ rpA,
    const int* __restrict__ srcA, const float* __restrict__ biasA,
    float* __restrict__ outA, int NdA,
    const ushort* __restrict__ qB, const float* __restrict__ esB,
    const float* __restrict__ edB, const int* __restrict__ rpB,
    const int* __restrict__ srcB, const float* __restrict__ biasB,
    float* __restrict__ outB, int NdB) {
    int wid = (blockIdx.x * 256 + threadIdx.x) >> 6;
    int lane = threadIdx.x & 63;
    int g = lane >> 4, l = lane & 15;
    int nwA = (NdA + 3) >> 2;
    const ushort* q; const float* es; const float* ed; const int* rp;
    const int* src; const float* bias16; float* o16; int dst, Nd;
    if (wid < nwA) {
        q = qA; es = esA; ed = edA; rp = rpA; src = srcA;
        bias16 = biasA; o16 = outA; Nd = NdA; dst = wid * 4 + g;
    } else {
        int w2 = wid - nwA;
        q = qB; es = esB; ed = edB; rp = rpB; src = srcB;
        bias16 = biasB; o16 = outB; Nd = NdB; dst = w2 * 4 + g;
    }
    if (dst >= Nd) return;
    int h = l >> 2, c4 = l * 4;
    int r0 = rp[dst], r1 = rp[dst + 1];
    float edv = ed[(size_t)dst * 8 + h];
    float ssum = 0.f, a0 = 0.f, a1 = 0.f, a2 = 0.f, a3 = 0.f;
    for (int base = r0; base < r1; base += 16) {
        int cnt = min(16, r1 - base);
        int sv = (base + l < r1) ? src[base + l] : 0;
        for (int j = 0; j < cnt; ++j) {
            int s = __shfl(sv, (g << 4) | j, 64);
            float x = es[(size_t)s * 8 + h] + edv;
            x = x > 0.f ? x : 0.2f * x;
            float w = __expf(x);
            ssum += w;
            ushort4 qv = *(const ushort4*)(q + (size_t)s * 64 + c4);
            a0 = fmaf(bf2f(qv.x), w, a0);
            a1 = fmaf(bf2f(qv.y), w, a1);
            a2 = fmaf(bf2f(qv.z), w, a2);
            a3 = fmaf(bf2f(qv.w), w, a3);
        }
    }
    float inv = 1.f / (ssum + 1e-16f);
    float r0v = a0 * inv, r1v = a1 * inv, r2v = a2 * inv, r3v = a3 * inv;
    // head-sum: lanes l, l^4, l^8 hold other heads with same j-range
    r0v += __shfl_xor(r0v, 4, 64); r1v += __shfl_xor(r1v, 4, 64);
    r2v += __shfl_xor(r2v, 4, 64); r3v += __shfl_xor(r3v, 4, 64);
    r0v += __shfl_xor(r0v, 8, 64); r1v += __shfl_xor(r1v, 8, 64);
    r2v += __shfl_xor(r2v, 8, 64); r3v += __shfl_xor(r3v, 8, 64);
    if (l < 4) {
        int jb = 4 * l;
        float4 o = make_float4(r0v + bias16[jb + 0], r1v + bias16[jb + 1],
                               r2v + bias16[jb + 2], r3v + bias16[jb + 3]);
        *(float4*)(o16 + (size_t)dst * 16 + jb) = o;
    }
}

// ---------------- decoder: 16 lanes per label edge ----------------
__global__ __launch_bounds__(256) void decoder16(
    const float* __restrict__ pu16, const float* __restrict__ pm16,
    const int* __restrict__ lab_u, const int* __restrict__ lab_m,
    const float* __restrict__ dw2, const float* __restrict__ db2,
    float* __restrict__ out, int nE) {
    int t = blockIdx.x * 256 + threadIdx.x;
    int e = t >> 4, j = t & 15;
    if (e >= nE) return;
    int u = lab_u[e], m = lab_m[e];
    float v = pu16[(size_t)u * 16 + j] + pm16[(size_t)m * 16 + j];
    float r = fmaxf(v, 0.f) * dw2[j];
    r += __shfl_xor(r, 1, 16);
    r += __shfl_xor(r, 2, 16);
    r += __shfl_xor(r, 4, 16);
    r += __shfl_xor(r, 8, 16);
    if (j == 0) out[e] = r + db2[0];
}

// ---------------- host ----------------

extern "C" void kernel_launch(void* const* d_in, const int* in_sizes, int n_in,
                              void* d_out, int out_size, void* d_ws, size_t ws_size,
                              hipStream_t stream) {
    const float* xu = (const float*)d_in[0];
    const float* xm = (const float*)d_in[1];
    const int* um_src = (const int*)d_in[2];
    const int* um_dst = (const int*)d_in[3];
    const int* mu_src = (const int*)d_in[4];
    const int* mu_dst = (const int*)d_in[5];
    const int* lab_u = (const int*)d_in[6];
    const int* lab_m = (const int*)d_in[7];
    const float* w1um_s = (const float*)d_in[8];
    const float* w1um_d = (const float*)d_in[9];
    const float* a1um_s = (const float*)d_in[10];
    const float* a1um_d = (const float*)d_in[11];
    const float* b1um = (const float*)d_in[12];
    const float* w1mu_s = (const float*)d_in[13];
    const float* w1mu_d = (const float*)d_in[14];
    const float* a1mu_s = (const float*)d_in[15];
    const float* a1mu_d = (const float*)d_in[16];
    const float* b1mu = (const float*)d_in[17];
    const float* w2um_s = (const float*)d_in[18];
    const float* w2um_d = (const float*)d_in[19];
    const float* a2um_s = (const float*)d_in[20];
    const float* a2um_d = (const float*)d_in[21];
    const float* b2um = (const float*)d_in[22];
    const float* w2mu_s = (const float*)d_in[23];
    const float* w2mu_d = (const float*)d_in[24];
    const float* a2mu_s = (const float*)d_in[25];
    const float* a2mu_d = (const float*)d_in[26];
    const float* b2mu = (const float*)d_in[27];
    const float* dw1 = (const float*)d_in[28];
    const float* db1 = (const float*)d_in[29];
    const float* dw2 = (const float*)d_in[30];
    const float* db2 = (const float*)d_in[31];
    float* out = (float*)d_out;

    // -------- workspace carving --------
    char* base = (char*)d_ws;
    size_t off = 0;
    auto alloc = [&](size_t bytes) -> void* {
        void* p = base + off;
        off = (off + bytes + 63) & ~(size_t)63;
        return p;
    };
    ushort* xu_bf   = (ushort*)alloc((size_t)NU_ * 32 * 2);
    ushort* xm_bf   = (ushort*)alloc((size_t)NM_ * 128 * 2);
    ushort* hproj_m = (ushort*)alloc((size_t)NM_ * 128 * 2);
    ushort* aggx    = (ushort*)alloc((size_t)NM_ * 256 * 2);
    ushort* zu_bf   = (ushort*)alloc((size_t)NU_ * 128 * 2);
    ushort* zm_bf   = (ushort*)alloc((size_t)NM_ * 128 * 2);
    ushort* qq_u    = (ushort*)alloc((size_t)NU_ * 64 * 2);
    ushort* qq_m    = (ushort*)alloc((size_t)NM_ * 64 * 2);
    ushort* Bt1u    = (ushort*)alloc((size_t)16 * 32 * 2);
    ushort* Bt1m    = (ushort*)alloc((size_t)144 * 128 * 2);
    ushort* Btp     = (ushort*)alloc((size_t)128 * 256 * 2);
    ushort* Bt2u    = (ushort*)alloc((size_t)80 * 128 * 2);
    ushort* Bt2m    = (ushort*)alloc((size_t)80 * 128 * 2);
    float* hlog_u = (float*)alloc((size_t)NU_ * 16 * 4);
    float* hlog_m = (float*)alloc((size_t)NM_ * 16 * 4);
    float* qlog_u = (float*)alloc((size_t)NU_ * 8 * 4);
    float* qlog_m = (float*)alloc((size_t)NM_ * 8 * 4);
    float* pu16   = (float*)alloc((size_t)NU_ * 16 * 4);
    float* pm16   = (float*)alloc((size_t)NM_ * 16 * 4);
    float* cj     = (float*)alloc(16 * 4);
    float* zero16 = (float*)alloc(16 * 4);
    int* rp_um    = (int*)alloc((NM_ + 1) * 4);
    int* rp_mu    = (int*)alloc((NU_ + 1) * 4);
    int* ssrc_um  = (int*)alloc((size_t)NE_ * 4);
    int* ssrc_mu  = (int*)alloc((size_t)NE_ * 4);
    int* ofs      = (int*)alloc((size_t)(NM_ + NU_) * 4);
    int* partials = (int*)alloc(128 * 4);
    if (ws_size < off) {
        fprintf(stderr, "kernel_launch: ws too small (%zu < %zu)\n", ws_size, off);
        return;
    }

    const int TB = 256;
    const int nbM = cdiv_i(NM_, SCHUNK);
    const int nbU = cdiv_i(NU_, SCHUNK);

    // -------- CSR (both graphs, fused) --------
    hipMemsetAsync(ofs, 0, (size_t)(NM_ + NU_) * sizeof(int), stream);
    count_both<<<cdiv_i(2 * NE_, TB), TB, 0, stream>>>(um_dst, mu_dst, ofs);
    scan_phaseA2<<<nbM + nbU, 256, 0, stream>>>(ofs, partials, nbM);
    scan_phaseB2<<<1, 64, 0, stream>>>(partials, nbM, nbU, rp_um, rp_mu);
    scan_phaseC2<<<nbM + nbU, 256, 0, stream>>>(ofs, partials, rp_um, rp_mu, nbM);
    copy_both<<<cdiv_i(NM_ + NU_, TB), TB, 0, stream>>>(rp_um, rp_mu, ofs);
    fill_both<<<cdiv_i(2 * NE_, TB), TB, 0, stream>>>(
        um_dst, um_src, mu_dst, mu_src, ofs, ssrc_um, ssrc_mu);

    hipMemsetAsync(zero16, 0, 16 * sizeof(float), stream);

    // -------- input casts + B^T builders --------
    conv_two<<<cdiv_i((NU_ * 32 + NM_ * 128) / 4, TB), TB, 0, stream>>>(
        xu, xu_bf, NU_ * 32 / 4, xm, xm_bf, NM_ * 128 / 4);

    build_bt1u_log<<<cdiv_i(16 * 32, TB), TB, 0, stream>>>(w1um_s, a1um_s, w1mu_d, a1mu_d, Bt1u);
    build_bt1<<<cdiv_i(144 * 128, TB), TB, 0, stream>>>(w1mu_s, a1mu_s, w1um_d, a1um_d, Bt1m, 128);
    build_btp<<<cdiv_i(128 * 256, TB), TB, 0, stream>>>(w1um_s, Btp);
    build_bt2<<<cdiv_i(80 * 128, TB), TB, 0, stream>>>(w2um_s, a2um_s, w2mu_d, a2mu_d, dw1, 512, Bt2u);
    build_bt2<<<cdiv_i(80 * 128, TB), TB, 0, stream>>>(w2mu_s, a2mu_s, w2um_d, a2um_d, dw1, 0, Bt2m);
    fold_cj<<<1, 64, 0, stream>>>(b2mu, b2um, dw1, db1, cj);

    // -------- layer-1 GEMMs --------
    // NU: logits only (16 f32 cols)
    mfma_gemm<32, 1><<<cdiv_i(NU_, 64), TB, 0, stream>>>(
        xu_bf, Bt1u, nullptr, 0, hlog_u, 16, 0, 16, NU_, nullptr, 0);
    // NM: hproj_m (128 bf16) + hlog_m (16 f32)
    mfma_gemm<128, 9><<<cdiv_i(NM_, 64), TB, 0, stream>>>(
        xm_bf, Bt1m, hproj_m, 128, hlog_m, 16, 128, 144, NM_, nullptr, 0);

    // -------- layer-1 aggregations --------
    // um: per-head raw-x aggregation -> aggx[NM,256], then project (bias+relu) -> zm
    agg_raw_um<<<cdiv_i(NM_, 4), TB, 0, stream>>>(
        xu_bf, hlog_u, hlog_m, rp_um, ssrc_um, aggx, NM_);
    mfma_gemm<256, 8><<<cdiv_i(NM_, 64), TB, 0, stream>>>(
        aggx, Btp, zm_bf, 128, nullptr, 0, 128, 128, NM_, b1um, 1);
    // mu: gather projected hproj_m (L2-resident), bias+relu fused -> zu
    agg_l1_mu<<<cdiv_i(NU_, 8), TB, 0, stream>>>(
        hproj_m, hlog_m, hlog_u, rp_mu, ssrc_mu, b1mu, zu_bf, NU_);

    // -------- layer-2 projections + logits (MFMA) --------
    mfma_gemm<128, 5><<<cdiv_i(NU_, 64), TB, 0, stream>>>(
        zu_bf, Bt2u, qq_u, 64, qlog_u, 8, 64, 72, NU_, nullptr, 0);
    mfma_gemm<128, 5><<<cdiv_i(NM_, 64), TB, 0, stream>>>(
        zm_bf, Bt2m, qq_m, 64, qlog_m, 8, 64, 72, NM_, nullptr, 0);

    // -------- layer-2 aggregation, both directions, 4 dsts/wave --------
    {
        int nwA = cdiv_i(NM_, 4), nwB = cdiv_i(NU_, 4);
        agg_l2_m<<<cdiv_i(nwA + nwB, 4), TB, 0, stream>>>(
            qq_u, qlog_u, qlog_m + 4, rp_um, ssrc_um, cj, pm16, NM_,
            qq_m, qlog_m, qlog_u + 4, rp_mu, ssrc_mu, zero16, pu16, NU_);
    }

    // -------- decoder --------
    decoder16<<<cdiv_i(EL_ * 16, TB), TB, 0, stream>>>(
        pu16, pm16, lab_u, lab_m, dw2, db2, out, EL_);
}

// Round 10
// 237.247 us; speedup vs baseline: 4.0997x; 1.1953x over previous
//
#include <hip/hip_runtime.h>
#include <hip/hip_bf16.h>
#include <cstdio>

#define NU_ 100000
#define NM_ 20000
#define NE_ 250000
#define EL_ 200000
#define SCHUNK 2048

static inline int cdiv_i(int a, int b) { return (a + b - 1) / b; }

typedef __attribute__((ext_vector_type(8))) short bf16x8;
typedef __attribute__((ext_vector_type(4))) float f32x4;

__device__ __forceinline__ float bf2f(ushort u) {
    unsigned x = ((unsigned)u) << 16;
    return __builtin_bit_cast(float, x);
}
__device__ __forceinline__ ushort f2bf(float f) {
    unsigned x = __builtin_bit_cast(unsigned, f);
    x += 0x7fff + ((x >> 16) & 1);   // RNE
    return (ushort)(x >> 16);
}

// ---------------- CSR build (both graphs fused) ----------------

__global__ void count_both(const int* __restrict__ um_dst, const int* __restrict__ mu_dst,
                           int* __restrict__ cnt) {   // cnt: [NM_ | NU_]
    int i = blockIdx.x * blockDim.x + threadIdx.x;
    if (i < NE_) atomicAdd(&cnt[um_dst[i]], 1);
    else if (i < 2 * NE_) atomicAdd(&cnt[NM_ + mu_dst[i - NE_]], 1);
}

__global__ void copy_both(const int* __restrict__ rp_um, const int* __restrict__ rp_mu,
                          int* __restrict__ ofs) {
    int i = blockIdx.x * blockDim.x + threadIdx.x;
    if (i < NM_) ofs[i] = rp_um[i];
    else if (i < NM_ + NU_) ofs[i] = rp_mu[i - NM_];
}

__global__ void fill_both(const int* __restrict__ um_dst, const int* __restrict__ um_src,
                          const int* __restrict__ mu_dst, const int* __restrict__ mu_src,
                          int* __restrict__ ofs, int* __restrict__ ssrc_um,
                          int* __restrict__ ssrc_mu) {
    int i = blockIdx.x * blockDim.x + threadIdx.x;
    if (i < NE_) {
        int p = atomicAdd(&ofs[um_dst[i]], 1);
        ssrc_um[p] = um_src[i];
    } else if (i < 2 * NE_) {
        int j = i - NE_;
        int p = atomicAdd(&ofs[NM_ + mu_dst[j]], 1);
        ssrc_mu[p] = mu_src[j];
    }
}

__global__ __launch_bounds__(256) void scan_phaseA2(const int* __restrict__ in,
                                                    int* __restrict__ partial, int nbM) {
    __shared__ int red[256];
    int b = blockIdx.x, tid = threadIdx.x;
    const int* src; int n; int* part; int bb;
    if (b < nbM) { src = in; n = NM_; part = partial; bb = b; }
    else { src = in + NM_; n = NU_; part = partial + nbM; bb = b - nbM; }
    int base = bb * SCHUNK + tid * 8;
    int s = 0;
#pragma unroll
    for (int j = 0; j < 8; ++j) { int i = base + j; if (i < n) s += src[i]; }
    red[tid] = s;
    __syncthreads();
    for (int off = 128; off; off >>= 1) {
        if (tid < off) red[tid] += red[tid + off];
        __syncthreads();
    }
    if (tid == 0) part[bb] = red[0];
}

// wave-parallel scan of both partial segments (nbM, nbU <= 64)
__global__ void scan_phaseB2(int* __restrict__ partial, int nbM, int nbU,
                             int* __restrict__ rp_um, int* __restrict__ rp_mu) {
    int lane = threadIdx.x & 63;
    int vm = (lane < nbM) ? partial[lane] : 0;
    int om = vm;
#pragma unroll
    for (int off = 1; off < 64; off <<= 1) {
        int y = __shfl_up(vm, off, 64);
        if (lane >= off) vm += y;
    }
    if (lane < nbM) partial[lane] = vm - om;
    if (lane == nbM - 1) rp_um[NM_] = vm;
    int vu = (lane < nbU) ? partial[nbM + lane] : 0;
    int ou = vu;
#pragma unroll
    for (int off = 1; off < 64; off <<= 1) {
        int y = __shfl_up(vu, off, 64);
        if (lane >= off) vu += y;
    }
    if (lane < nbU) partial[nbM + lane] = vu - ou;
    if (lane == nbU - 1) rp_mu[NU_] = vu;
}

__global__ __launch_bounds__(256) void scan_phaseC2(const int* __restrict__ in,
                                                    const int* __restrict__ partial,
                                                    int* __restrict__ rp_um,
                                                    int* __restrict__ rp_mu, int nbM) {
    __shared__ int tsum[256];
    int b = blockIdx.x, tid = threadIdx.x;
    const int* src; int n; const int* part; int* outp; int bb;
    if (b < nbM) { src = in; n = NM_; part = partial; outp = rp_um; bb = b; }
    else { src = in + NM_; n = NU_; part = partial + nbM; outp = rp_mu; bb = b - nbM; }
    int base = bb * SCHUNK + tid * 8;
    int v[8];
    int s = 0;
#pragma unroll
    for (int j = 0; j < 8; ++j) { int i = base + j; v[j] = (i < n) ? src[i] : 0; s += v[j]; }
    tsum[tid] = s;
    __syncthreads();
    for (int off = 1; off < 256; off <<= 1) {
        int y = (tid >= off) ? tsum[tid - off] : 0;
        __syncthreads();
        tsum[tid] += y;
        __syncthreads();
    }
    int run = part[bb] + tsum[tid] - s;
#pragma unroll
    for (int j = 0; j < 8; ++j) { int i = base + j; if (i < n) outp[i] = run; run += v[j]; }
}

// ---------------- fused setup: bf16 casts + all B^T builders + cj + zero16 ----------------

#define N_CONV ((NU_ * 32 + NM_ * 128) / 4)
#define N_BT1U (16 * 32)
#define N_BT1M (144 * 128)
#define N_BTP  (128 * 256)
#define N_BT2  (80 * 128)

__global__ __launch_bounds__(256) void setup_all(
    const float* __restrict__ xu, ushort* __restrict__ xu_bf,
    const float* __restrict__ xm, ushort* __restrict__ xm_bf,
    const float* __restrict__ w1um_s, const float* __restrict__ a1um_s,
    const float* __restrict__ w1mu_d, const float* __restrict__ a1mu_d,
    ushort* __restrict__ Bt1u,
    const float* __restrict__ w1mu_s, const float* __restrict__ a1mu_s,
    const float* __restrict__ w1um_d, const float* __restrict__ a1um_d,
    ushort* __restrict__ Bt1m, ushort* __restrict__ Btp,
    const float* __restrict__ w2um_s, const float* __restrict__ a2um_s,
    const float* __restrict__ w2mu_d, const float* __restrict__ a2mu_d,
    ushort* __restrict__ Bt2u,
    const float* __restrict__ w2mu_s, const float* __restrict__ a2mu_s,
    const float* __restrict__ w2um_d, const float* __restrict__ a2um_d,
    ushort* __restrict__ Bt2m,
    const float* __restrict__ b2mu, const float* __restrict__ b2um,
    const float* __restrict__ dw1, const float* __restrict__ db1,
    float* __restrict__ cj, float* __restrict__ zero16) {
    int i = blockIdx.x * blockDim.x + threadIdx.x;
    // S0: bf16 casts
    if (i < N_CONV) {
        const float* s; ushort* d; int idx;
        int n4a = NU_ * 32 / 4;
        if (i < n4a) { s = xu; d = xu_bf; idx = i; }
        else { s = xm; d = xm_bf; idx = i - n4a; }
        float4 v = ((const float4*)s)[idx];
        ushort4 o;
        o.x = f2bf(v.x); o.y = f2bf(v.y); o.z = f2bf(v.z); o.w = f2bf(v.w);
        ((ushort4*)d)[idx] = o;
        return;
    }
    i -= N_CONV;
    // S1: Bt1u (16 logit cols, K=32)
    if (i < N_BT1U) {
        int c = i >> 5, k = i & 31;
        float v = 0.f;
        if (c < 8) {
            for (int cc = 0; cc < 16; ++cc)
                v += w1um_s[(size_t)k * 128 + c * 16 + cc] * a1um_s[c * 16 + cc];
        } else {
            int h = c - 8;
            for (int cc = 0; cc < 16; ++cc)
                v += w1mu_d[(size_t)k * 128 + h * 16 + cc] * a1mu_d[h * 16 + cc];
        }
        Bt1u[c * 32 + k] = f2bf(v);
        return;
    }
    i -= N_BT1U;
    // S2: Bt1m (144 cols, K=128)
    if (i < N_BT1M) {
        int c = i >> 7, k = i & 127;
        float v;
        if (c < 128) {
            v = w1mu_s[(size_t)k * 128 + c];
        } else if (c < 136) {
            int h = c - 128; v = 0.f;
            for (int cc = 0; cc < 16; ++cc)
                v += w1mu_s[(size_t)k * 128 + h * 16 + cc] * a1mu_s[h * 16 + cc];
        } else {
            int h = c - 136; v = 0.f;
            for (int cc = 0; cc < 16; ++cc)
                v += w1um_d[(size_t)k * 128 + h * 16 + cc] * a1um_d[h * 16 + cc];
        }
        Bt1m[(size_t)c * 128 + k] = f2bf(v);
        return;
    }
    i -= N_BT1M;
    // S3: Btp (block-diag projection of w1um_s, 128 cols, K=256)
    if (i < N_BTP) {
        int c = i >> 8, kk = i & 255;
        int h = kk >> 5, k = kk & 31;
        float v = ((c >> 4) == h) ? w1um_s[(size_t)k * 128 + c] : 0.f;
        Btp[(size_t)c * 256 + kk] = f2bf(v);
        return;
    }
    i -= N_BTP;
    // S4: Bt2u
    if (i < N_BT2) {
        int c = i >> 7, k = i & 127;
        float v = 0.f;
        if (c < 64) {
            int h = c >> 4, j = c & 15;
            for (int cc = 0; cc < 128; ++cc)
                v += w2um_s[(size_t)k * 512 + h * 128 + cc] * dw1[(size_t)(512 + h * 128 + cc) * 16 + j];
        } else if (c < 68) {
            int h = c - 64;
            for (int cc = 0; cc < 128; ++cc)
                v += w2um_s[(size_t)k * 512 + h * 128 + cc] * a2um_s[h * 128 + cc];
        } else if (c < 72) {
            int h = c - 68;
            for (int cc = 0; cc < 128; ++cc)
                v += w2mu_d[(size_t)k * 512 + h * 128 + cc] * a2mu_d[h * 128 + cc];
        }
        Bt2u[(size_t)c * 128 + k] = f2bf(v);
        return;
    }
    i -= N_BT2;
    // S5: Bt2m
    if (i < N_BT2) {
        int c = i >> 7, k = i & 127;
        float v = 0.f;
        if (c < 64) {
            int h = c >> 4, j = c & 15;
            for (int cc = 0; cc < 128; ++cc)
                v += w2mu_s[(size_t)k * 512 + h * 128 + cc] * dw1[(size_t)(h * 128 + cc) * 16 + j];
        } else if (c < 68) {
            int h = c - 64;
            for (int cc = 0; cc < 128; ++cc)
                v += w2mu_s[(size_t)k * 512 + h * 128 + cc] * a2mu_s[h * 128 + cc];
        } else if (c < 72) {
            int h = c - 68;
            for (int cc = 0; cc < 128; ++cc)
                v += w2um_d[(size_t)k * 512 + h * 128 + cc] * a2um_d[h * 128 + cc];
        }
        Bt2m[(size_t)c * 128 + k] = f2bf(v);
        return;
    }
    i -= N_BT2;
    // S6: cj (16) + zero16 (16)
    if (i < 16) {
        float s = db1[i];
        for (int col = 0; col < 512; ++col)
            s += b2mu[col] * dw1[col * 16 + i] + b2um[col] * dw1[(512 + col) * 16 + i];
        cj[i] = s;
    } else if (i < 32) {
        zero16[i - 16] = 0.f;
    }
}

// ---------------- MFMA GEMM body ----------------
template <int K, int NT>
__device__ __forceinline__ void mfma_body(
    int blk, const ushort* __restrict__ A, const ushort* __restrict__ Bt,
    ushort* __restrict__ outb, int sb, float* __restrict__ outf, int sf,
    int splitc, int maxc, int Nrows, const float* __restrict__ bias, int dorelu) {
    int wave = threadIdx.x >> 6;
    int lane = threadIdx.x & 63;
    int row0 = (blk * 4 + wave) * 16;
    if (row0 >= Nrows) return;
    int r = lane & 15;
    int kb = lane >> 4;
    bf16x8 afrag[K / 32];
    int arow = row0 + r;
    bool rowok = (arow < Nrows);
#pragma unroll
    for (int ks = 0; ks < K / 32; ++ks) {
        if (rowok)
            afrag[ks] = *(const bf16x8*)(A + (size_t)arow * K + ks * 32 + kb * 8);
        else
            afrag[ks] = (bf16x8){0, 0, 0, 0, 0, 0, 0, 0};
    }
#pragma unroll
    for (int nt = 0; nt < NT; ++nt) {
        f32x4 acc = {0.f, 0.f, 0.f, 0.f};
#pragma unroll
        for (int ks = 0; ks < K / 32; ++ks) {
            bf16x8 bfrag = *(const bf16x8*)(Bt + (size_t)(nt * 16 + r) * K + ks * 32 + kb * 8);
            acc = __builtin_amdgcn_mfma_f32_16x16x32_bf16(afrag[ks], bfrag, acc, 0, 0, 0);
        }
        int col = nt * 16 + r;
        float bv = (bias && col < splitc) ? bias[col] : 0.f;
#pragma unroll
        for (int reg = 0; reg < 4; ++reg) {
            int rr = row0 + kb * 4 + reg;
            if (rr < Nrows) {
                if (col < splitc) {
                    float v = acc[reg] + bv;
                    if (dorelu) v = fmaxf(v, 0.f);
                    outb[(size_t)rr * sb + col] = f2bf(v);
                } else if (col < maxc) {
                    outf[(size_t)rr * sf + (col - splitc)] = acc[reg];
                }
            }
        }
    }
}

// merged layer-1 GEMMs: [0,gNU) -> NU logits (K=32,NT=1); rest -> NM proj+logits (K=128,NT=9)
__global__ __launch_bounds__(256) void gemm_l1(
    const ushort* __restrict__ xu_bf, const ushort* __restrict__ Bt1u,
    float* __restrict__ hlog_u,
    const ushort* __restrict__ xm_bf, const ushort* __restrict__ Bt1m,
    ushort* __restrict__ hproj_m, float* __restrict__ hlog_m, int gNU) {
    int b = blockIdx.x;
    if (b < gNU)
        mfma_body<32, 1>(b, xu_bf, Bt1u, nullptr, 0, hlog_u, 16, 0, 16, NU_, nullptr, 0);
    else
        mfma_body<128, 9>(b - gNU, xm_bf, Bt1m, hproj_m, 128, hlog_m, 16, 128, 144, NM_, nullptr, 0);
}

// projection of aggregated raw x -> zm (bias+relu)
__global__ __launch_bounds__(256) void gemm_proj(
    const ushort* __restrict__ aggx, const ushort* __restrict__ Btp,
    ushort* __restrict__ zm_bf, const float* __restrict__ b1um) {
    mfma_body<256, 8>(blockIdx.x, aggx, Btp, zm_bf, 128, nullptr, 0, 128, 128, NM_, b1um, 1);
}

// merged layer-2 GEMMs
__global__ __launch_bounds__(256) void gemm_l2(
    const ushort* __restrict__ zu_bf, const ushort* __restrict__ Bt2u,
    ushort* __restrict__ qq_u, float* __restrict__ qlog_u,
    const ushort* __restrict__ zm_bf, const ushort* __restrict__ Bt2m,
    ushort* __restrict__ qq_m, float* __restrict__ qlog_m, int gNU) {
    int b = blockIdx.x;
    if (b < gNU)
        mfma_body<128, 5>(b, zu_bf, Bt2u, qq_u, 64, qlog_u, 8, 64, 72, NU_, nullptr, 0);
    else
        mfma_body<128, 5>(b - gNU, zm_bf, Bt2m, qq_m, 64, qlog_m, 8, 64, 72, NM_, nullptr, 0);
}

// ---------------- merged layer-1 aggregations ----------------
// A-part: agg_raw_um (1 dst/wave, raw 32-dim per-head) ; B-part: agg_l1_mu (2 dst/wave)
__global__ __launch_bounds__(256) void agg_l1(
    const ushort* __restrict__ xu_bf, const float* __restrict__ hlog_u,
    const float* __restrict__ hlog_m, const int* __restrict__ rp_um,
    const int* __restrict__ ssrc_um, ushort* __restrict__ aggx,
    const ushort* __restrict__ hproj_m, const int* __restrict__ rp_mu,
    const int* __restrict__ ssrc_mu, const float* __restrict__ b1mu,
    ushort* __restrict__ zu_bf, int gA) {
    int b = blockIdx.x;
    int lane = threadIdx.x & 63;
    if (b < gA) {
        // raw-x per-head aggregation for um (dst = movie)
        int wid = (b * 256 + (int)threadIdx.x) >> 6;
        if (wid >= NM_) return;
        int h = lane >> 3, c4 = (lane & 7) * 4;
        int r0 = rp_um[wid], r1 = rp_um[wid + 1];
        float edv = hlog_m[(size_t)wid * 16 + 8 + h];
        float ssum = 0.f, a0 = 0.f, a1 = 0.f, a2 = 0.f, a3 = 0.f;
        for (int base = r0; base < r1; base += 64) {
            int cnt = min(64, r1 - base);
            int sv = (base + lane < r1) ? ssrc_um[base + lane] : 0;
            for (int j = 0; j < cnt; ++j) {
                int s = __shfl(sv, j, 64);
                float x = hlog_u[(size_t)s * 16 + h] + edv;
                x = x > 0.f ? x : 0.2f * x;
                float w = __expf(x);
                ssum += w;
                ushort4 xv = *(const ushort4*)(xu_bf + (size_t)s * 32 + c4);
                a0 = fmaf(bf2f(xv.x), w, a0);
                a1 = fmaf(bf2f(xv.y), w, a1);
                a2 = fmaf(bf2f(xv.z), w, a2);
                a3 = fmaf(bf2f(xv.w), w, a3);
            }
        }
        float inv = 1.f / (ssum + 1e-16f);
        ushort4 o;
        o.x = f2bf(a0 * inv); o.y = f2bf(a1 * inv);
        o.z = f2bf(a2 * inv); o.w = f2bf(a3 * inv);
        *(ushort4*)(aggx + (size_t)wid * 256 + h * 32 + c4) = o;
    } else {
        // hproj_m gather for mu (dst = user), 2 dsts/wave
        int wid = ((b - gA) * 256 + (int)threadIdx.x) >> 6;
        int g = lane >> 5, l = lane & 31;
        int dst = wid * 2 + g;
        if (dst >= NU_) return;
        int h = l >> 2, c4 = l * 4;
        int r0 = rp_mu[dst], r1 = rp_mu[dst + 1];
        float edv = hlog_u[(size_t)dst * 16 + 8 + h];
        float ssum = 0.f, a0 = 0.f, a1 = 0.f, a2 = 0.f, a3 = 0.f;
        for (int base = r0; base < r1; base += 32) {
            int cnt = min(32, r1 - base);
            int sv = (base + l < r1) ? ssrc_mu[base + l] : 0;
            for (int j = 0; j < cnt; ++j) {
                int s = __shfl(sv, (g << 5) | j, 64);
                float x = hlog_m[(size_t)s * 16 + h] + edv;
                x = x > 0.f ? x : 0.2f * x;
                float w = __expf(x);
                ssum += w;
                ushort4 hv = *(const ushort4*)(hproj_m + (size_t)s * 128 + c4);
                a0 = fmaf(bf2f(hv.x), w, a0);
                a1 = fmaf(bf2f(hv.y), w, a1);
                a2 = fmaf(bf2f(hv.z), w, a2);
                a3 = fmaf(bf2f(hv.w), w, a3);
            }
        }
        float inv = 1.f / (ssum + 1e-16f);
        float v0 = fmaxf(fmaf(a0, inv, b1mu[c4 + 0]), 0.f);
        float v1 = fmaxf(fmaf(a1, inv, b1mu[c4 + 1]), 0.f);
        float v2 = fmaxf(fmaf(a2, inv, b1mu[c4 + 2]), 0.f);
        float v3 = fmaxf(fmaf(a3, inv, b1mu[c4 + 3]), 0.f);
        ushort4 o;
        o.x = f2bf(v0); o.y = f2bf(v1); o.z = f2bf(v2); o.w = f2bf(v3);
        *(ushort4*)(zu_bf + (size_t)dst * 128 + c4) = o;
    }
}

// ---------------- layer-2 aggregation, both directions, 4 dsts/wave ----------------
__global__ __launch_bounds__(256) void agg_l2_m(
    const ushort* __restrict__ qA, const float* __restrict__ esA,
    const float* __restrict__ edA, const int* __restrict__ rpA,
    const int* __restrict__ srcA, const float* __restrict__ biasA,
    float* __restrict__ outA, int NdA,
    const ushort* __restrict__ qB, const float* __restrict__ esB,
    const float* __restrict__ edB, const int* __restrict__ rpB,
    const int* __restrict__ srcB, const float* __restrict__ biasB,
    float* __restrict__ outB, int NdB) {
    int wid = (blockIdx.x * 256 + threadIdx.x) >> 6;
    int lane = threadIdx.x & 63;
    int g = lane >> 4, l = lane & 15;
    int nwA = (NdA + 3) >> 2;
    const ushort* q; const float* es; const float* ed; const int* rp;
    const int* src; const float* bias16; float* o16; int dst, Nd;
    if (wid < nwA) {
        q = qA; es = esA; ed = edA; rp = rpA; src = srcA;
        bias16 = biasA; o16 = outA; Nd = NdA; dst = wid * 4 + g;
    } else {
        int w2 = wid - nwA;
        q = qB; es = esB; ed = edB; rp = rpB; src = srcB;
        bias16 = biasB; o16 = outB; Nd = NdB; dst = w2 * 4 + g;
    }
    if (dst >= Nd) return;
    int h = l >> 2, c4 = l * 4;
    int r0 = rp[dst], r1 = rp[dst + 1];
    float edv = ed[(size_t)dst * 8 + h];
    float ssum = 0.f, a0 = 0.f, a1 = 0.f, a2 = 0.f, a3 = 0.f;
    for (int base = r0; base < r1; base += 16) {
        int cnt = min(16, r1 - base);
        int sv = (base + l < r1) ? src[base + l] : 0;
        for (int j = 0; j < cnt; ++j) {
            int s = __shfl(sv, (g << 4) | j, 64);
            float x = es[(size_t)s * 8 + h] + edv;
            x = x > 0.f ? x : 0.2f * x;
            float w = __expf(x);
            ssum += w;
            ushort4 qv = *(const ushort4*)(q + (size_t)s * 64 + c4);
            a0 = fmaf(bf2f(qv.x), w, a0);
            a1 = fmaf(bf2f(qv.y), w, a1);
            a2 = fmaf(bf2f(qv.z), w, a2);
            a3 = fmaf(bf2f(qv.w), w, a3);
        }
    }
    float inv = 1.f / (ssum + 1e-16f);
    float r0v = a0 * inv, r1v = a1 * inv, r2v = a2 * inv, r3v = a3 * inv;
    r0v += __shfl_xor(r0v, 4, 64); r1v += __shfl_xor(r1v, 4, 64);
    r2v += __shfl_xor(r2v, 4, 64); r3v += __shfl_xor(r3v, 4, 64);
    r0v += __shfl_xor(r0v, 8, 64); r1v += __shfl_xor(r1v, 8, 64);
    r2v += __shfl_xor(r2v, 8, 64); r3v += __shfl_xor(r3v, 8, 64);
    if (l < 4) {
        int jb = 4 * l;
        float4 o = make_float4(r0v + bias16[jb + 0], r1v + bias16[jb + 1],
                               r2v + bias16[jb + 2], r3v + bias16[jb + 3]);
        *(float4*)(o16 + (size_t)dst * 16 + jb) = o;
    }
}

// ---------------- decoder: 4 lanes per label edge, float4 loads ----------------
__global__ __launch_bounds__(256) void decoder4(
    const float* __restrict__ pu16, const float* __restrict__ pm16,
    const int* __restrict__ lab_u, const int* __restrict__ lab_m,
    const float* __restrict__ dw2, const float* __restrict__ db2,
    float* __restrict__ out, int nE) {
    int t = blockIdx.x * 256 + threadIdx.x;
    int e = t >> 2, sub = t & 3;
    if (e >= nE) return;
    int u = lab_u[e], m = lab_m[e];
    float4 a = *(const float4*)(pu16 + (size_t)u * 16 + sub * 4);
    float4 b = *(const float4*)(pm16 + (size_t)m * 16 + sub * 4);
    const float* w = dw2 + sub * 4;
    float r = fmaxf(a.x + b.x, 0.f) * w[0] + fmaxf(a.y + b.y, 0.f) * w[1] +
              fmaxf(a.z + b.z, 0.f) * w[2] + fmaxf(a.w + b.w, 0.f) * w[3];
    r += __shfl_xor(r, 1, 64);
    r += __shfl_xor(r, 2, 64);
    if (sub == 0) out[e] = r + db2[0];
}

// ---------------- host ----------------

extern "C" void kernel_launch(void* const* d_in, const int* in_sizes, int n_in,
                              void* d_out, int out_size, void* d_ws, size_t ws_size,
                              hipStream_t stream) {
    const float* xu = (const float*)d_in[0];
    const float* xm = (const float*)d_in[1];
    const int* um_src = (const int*)d_in[2];
    const int* um_dst = (const int*)d_in[3];
    const int* mu_src = (const int*)d_in[4];
    const int* mu_dst = (const int*)d_in[5];
    const int* lab_u = (const int*)d_in[6];
    const int* lab_m = (const int*)d_in[7];
    const float* w1um_s = (const float*)d_in[8];
    const float* w1um_d = (const float*)d_in[9];
    const float* a1um_s = (const float*)d_in[10];
    const float* a1um_d = (const float*)d_in[11];
    const float* b1um = (const float*)d_in[12];
    const float* w1mu_s = (const float*)d_in[13];
    const float* w1mu_d = (const float*)d_in[14];
    const float* a1mu_s = (const float*)d_in[15];
    const float* a1mu_d = (const float*)d_in[16];
    const float* b1mu = (const float*)d_in[17];
    const float* w2um_s = (const float*)d_in[18];
    const float* w2um_d = (const float*)d_in[19];
    const float* a2um_s = (const float*)d_in[20];
    const float* a2um_d = (const float*)d_in[21];
    const float* b2um = (const float*)d_in[22];
    const float* w2mu_s = (const float*)d_in[23];
    const float* w2mu_d = (const float*)d_in[24];
    const float* a2mu_s = (const float*)d_in[25];
    const float* a2mu_d = (const float*)d_in[26];
    const float* b2mu = (const float*)d_in[27];
    const float* dw1 = (const float*)d_in[28];
    const float* db1 = (const float*)d_in[29];
    const float* dw2 = (const float*)d_in[30];
    const float* db2 = (const float*)d_in[31];
    float* out = (float*)d_out;

    // -------- workspace carving --------
    char* base = (char*)d_ws;
    size_t off = 0;
    auto alloc = [&](size_t bytes) -> void* {
        void* p = base + off;
        off = (off + bytes + 63) & ~(size_t)63;
        return p;
    };
    ushort* xu_bf   = (ushort*)alloc((size_t)NU_ * 32 * 2);
    ushort* xm_bf   = (ushort*)alloc((size_t)NM_ * 128 * 2);
    ushort* hproj_m = (ushort*)alloc((size_t)NM_ * 128 * 2);
    ushort* aggx    = (ushort*)alloc((size_t)NM_ * 256 * 2);
    ushort* zu_bf   = (ushort*)alloc((size_t)NU_ * 128 * 2);
    ushort* zm_bf   = (ushort*)alloc((size_t)NM_ * 128 * 2);
    ushort* qq_u    = (ushort*)alloc((size_t)NU_ * 64 * 2);
    ushort* qq_m    = (ushort*)alloc((size_t)NM_ * 64 * 2);
    ushort* Bt1u    = (ushort*)alloc((size_t)16 * 32 * 2);
    ushort* Bt1m    = (ushort*)alloc((size_t)144 * 128 * 2);
    ushort* Btp     = (ushort*)alloc((size_t)128 * 256 * 2);
    ushort* Bt2u    = (ushort*)alloc((size_t)80 * 128 * 2);
    ushort* Bt2m    = (ushort*)alloc((size_t)80 * 128 * 2);
    float* hlog_u = (float*)alloc((size_t)NU_ * 16 * 4);
    float* hlog_m = (float*)alloc((size_t)NM_ * 16 * 4);
    float* qlog_u = (float*)alloc((size_t)NU_ * 8 * 4);
    float* qlog_m = (float*)alloc((size_t)NM_ * 8 * 4);
    float* pu16   = (float*)alloc((size_t)NU_ * 16 * 4);
    float* pm16   = (float*)alloc((size_t)NM_ * 16 * 4);
    float* cj     = (float*)alloc(16 * 4);
    float* zero16 = (float*)alloc(16 * 4);
    int* rp_um    = (int*)alloc((NM_ + 1) * 4);
    int* rp_mu    = (int*)alloc((NU_ + 1) * 4);
    int* ssrc_um  = (int*)alloc((size_t)NE_ * 4);
    int* ssrc_mu  = (int*)alloc((size_t)NE_ * 4);
    int* ofs      = (int*)alloc((size_t)(NM_ + NU_) * 4);
    int* partials = (int*)alloc(128 * 4);
    if (ws_size < off) {
        fprintf(stderr, "kernel_launch: ws too small (%zu < %zu)\n", ws_size, off);
        return;
    }

    const int TB = 256;
    const int nbM = cdiv_i(NM_, SCHUNK);
    const int nbU = cdiv_i(NU_, SCHUNK);

    // -------- CSR (both graphs) --------
    hipMemsetAsync(ofs, 0, (size_t)(NM_ + NU_) * sizeof(int), stream);
    count_both<<<cdiv_i(2 * NE_, TB), TB, 0, stream>>>(um_dst, mu_dst, ofs);
    scan_phaseA2<<<nbM + nbU, 256, 0, stream>>>(ofs, partials, nbM);
    scan_phaseB2<<<1, 64, 0, stream>>>(partials, nbM, nbU, rp_um, rp_mu);
    scan_phaseC2<<<nbM + nbU, 256, 0, stream>>>(ofs, partials, rp_um, rp_mu, nbM);
    copy_both<<<cdiv_i(NM_ + NU_, TB), TB, 0, stream>>>(rp_um, rp_mu, ofs);
    fill_both<<<cdiv_i(2 * NE_, TB), TB, 0, stream>>>(
        um_dst, um_src, mu_dst, mu_src, ofs, ssrc_um, ssrc_mu);

    // -------- fused setup --------
    {
        int ntot = N_CONV + N_BT1U + N_BT1M + N_BTP + 2 * N_BT2 + 32;
        setup_all<<<cdiv_i(ntot, TB), TB, 0, stream>>>(
            xu, xu_bf, xm, xm_bf,
            w1um_s, a1um_s, w1mu_d, a1mu_d, Bt1u,
            w1mu_s, a1mu_s, w1um_d, a1um_d, Bt1m, Btp,
            w2um_s, a2um_s, w2mu_d, a2mu_d, Bt2u,
            w2mu_s, a2mu_s, w2um_d, a2um_d, Bt2m,
            b2mu, b2um, dw1, db1, cj, zero16);
    }

    // -------- layer-1 GEMMs (merged) --------
    {
        int gNU = cdiv_i(NU_, 64), gNM = cdiv_i(NM_, 64);
        gemm_l1<<<gNU + gNM, TB, 0, stream>>>(
            xu_bf, Bt1u, hlog_u, xm_bf, Bt1m, hproj_m, hlog_m, gNU);
    }

    // -------- layer-1 aggregations (merged) --------
    {
        int gA = cdiv_i(NM_, 4), gB = cdiv_i(NU_, 8);
        agg_l1<<<gA + gB, TB, 0, stream>>>(
            xu_bf, hlog_u, hlog_m, rp_um, ssrc_um, aggx,
            hproj_m, rp_mu, ssrc_mu, b1mu, zu_bf, gA);
    }
    gemm_proj<<<cdiv_i(NM_, 64), TB, 0, stream>>>(aggx, Btp, zm_bf, b1um);

    // -------- layer-2 GEMMs (merged) --------
    {
        int gNU = cdiv_i(NU_, 64), gNM = cdiv_i(NM_, 64);
        gemm_l2<<<gNU + gNM, TB, 0, stream>>>(
            zu_bf, Bt2u, qq_u, qlog_u, zm_bf, Bt2m, qq_m, qlog_m, gNU);
    }

    // -------- layer-2 aggregation (merged) --------
    {
        int nwA = cdiv_i(NM_, 4), nwB = cdiv_i(NU_, 4);
        agg_l2_m<<<cdiv_i(nwA + nwB, 4), TB, 0, stream>>>(
            qq_u, qlog_u, qlog_m + 4, rp_um, ssrc_um, cj, pm16, NM_,
            qq_m, qlog_m, qlog_u + 4, rp_mu, ssrc_mu, zero16, pu16, NU_);
    }

    // -------- decoder --------
    decoder4<<<cdiv_i(EL_ * 4, TB), TB, 0, stream>>>(
        pu16, pm16, lab_u, lab_m, dw2, db2, out, EL_);
}

// Round 11
// 224.609 us; speedup vs baseline: 4.3304x; 1.0563x over previous
//
#include <hip/hip_runtime.h>
#include <hip/hip_bf16.h>
#include <cstdio>

#define NU_ 100000
#define NM_ 20000
#define NE_ 250000
#define EL_ 200000
#define SCHUNK 2048

static inline int cdiv_i(int a, int b) { return (a + b - 1) / b; }

typedef __attribute__((ext_vector_type(8))) short bf16x8;
typedef __attribute__((ext_vector_type(4))) float f32x4;

__device__ __forceinline__ float bf2f(ushort u) {
    unsigned x = ((unsigned)u) << 16;
    return __builtin_bit_cast(float, x);
}
__device__ __forceinline__ ushort f2bf(float f) {
    unsigned x = __builtin_bit_cast(unsigned, f);
    x += 0x7fff + ((x >> 16) & 1);   // RNE
    return (ushort)(x >> 16);
}

// ---------------- CSR build (both graphs fused) ----------------

__global__ void count_both(const int* __restrict__ um_dst, const int* __restrict__ mu_dst,
                           int* __restrict__ cnt) {   // cnt: [NM_ | NU_]
    int i = blockIdx.x * blockDim.x + threadIdx.x;
    if (i < NE_) atomicAdd(&cnt[um_dst[i]], 1);
    else if (i < 2 * NE_) atomicAdd(&cnt[NM_ + mu_dst[i - NE_]], 1);
}

__global__ void copy_both(const int* __restrict__ rp_um, const int* __restrict__ rp_mu,
                          int* __restrict__ ofs) {
    int i = blockIdx.x * blockDim.x + threadIdx.x;
    if (i < NM_) ofs[i] = rp_um[i];
    else if (i < NM_ + NU_) ofs[i] = rp_mu[i - NM_];
}

__global__ void fill_both(const int* __restrict__ um_dst, const int* __restrict__ um_src,
                          const int* __restrict__ mu_dst, const int* __restrict__ mu_src,
                          int* __restrict__ ofs, int* __restrict__ ssrc_um,
                          int* __restrict__ ssrc_mu) {
    int i = blockIdx.x * blockDim.x + threadIdx.x;
    if (i < NE_) {
        int p = atomicAdd(&ofs[um_dst[i]], 1);
        ssrc_um[p] = um_src[i];
    } else if (i < 2 * NE_) {
        int j = i - NE_;
        int p = atomicAdd(&ofs[NM_ + mu_dst[j]], 1);
        ssrc_mu[p] = mu_src[j];
    }
}

__global__ __launch_bounds__(256) void scan_phaseA2(const int* __restrict__ in,
                                                    int* __restrict__ partial, int nbM) {
    __shared__ int red[256];
    int b = blockIdx.x, tid = threadIdx.x;
    const int* src; int n; int* part; int bb;
    if (b < nbM) { src = in; n = NM_; part = partial; bb = b; }
    else { src = in + NM_; n = NU_; part = partial + nbM; bb = b - nbM; }
    int base = bb * SCHUNK + tid * 8;
    int s = 0;
#pragma unroll
    for (int j = 0; j < 8; ++j) { int i = base + j; if (i < n) s += src[i]; }
    red[tid] = s;
    __syncthreads();
    for (int off = 128; off; off >>= 1) {
        if (tid < off) red[tid] += red[tid + off];
        __syncthreads();
    }
    if (tid == 0) part[bb] = red[0];
}

// wave-parallel scan of both partial segments (nbM, nbU <= 64)
__global__ void scan_phaseB2(int* __restrict__ partial, int nbM, int nbU,
                             int* __restrict__ rp_um, int* __restrict__ rp_mu) {
    int lane = threadIdx.x & 63;
    int vm = (lane < nbM) ? partial[lane] : 0;
    int om = vm;
#pragma unroll
    for (int off = 1; off < 64; off <<= 1) {
        int y = __shfl_up(vm, off, 64);
        if (lane >= off) vm += y;
    }
    if (lane < nbM) partial[lane] = vm - om;
    if (lane == nbM - 1) rp_um[NM_] = vm;
    int vu = (lane < nbU) ? partial[nbM + lane] : 0;
    int ou = vu;
#pragma unroll
    for (int off = 1; off < 64; off <<= 1) {
        int y = __shfl_up(vu, off, 64);
        if (lane >= off) vu += y;
    }
    if (lane < nbU) partial[nbM + lane] = vu - ou;
    if (lane == nbU - 1) rp_mu[NU_] = vu;
}

__global__ __launch_bounds__(256) void scan_phaseC2(const int* __restrict__ in,
                                                    const int* __restrict__ partial,
                                                    int* __restrict__ rp_um,
                                                    int* __restrict__ rp_mu, int nbM) {
    __shared__ int tsum[256];
    int b = blockIdx.x, tid = threadIdx.x;
    const int* src; int n; const int* part; int* outp; int bb;
    if (b < nbM) { src = in; n = NM_; part = partial; outp = rp_um; bb = b; }
    else { src = in + NM_; n = NU_; part = partial + nbM; outp = rp_mu; bb = b - nbM; }
    int base = bb * SCHUNK + tid * 8;
    int v[8];
    int s = 0;
#pragma unroll
    for (int j = 0; j < 8; ++j) { int i = base + j; v[j] = (i < n) ? src[i] : 0; s += v[j]; }
    tsum[tid] = s;
    __syncthreads();
    for (int off = 1; off < 256; off <<= 1) {
        int y = (tid >= off) ? tsum[tid - off] : 0;
        __syncthreads();
        tsum[tid] += y;
        __syncthreads();
    }
    int run = part[bb] + tsum[tid] - s;
#pragma unroll
    for (int j = 0; j < 8; ++j) { int i = base + j; if (i < n) outp[i] = run; run += v[j]; }
}

// ---------------- fused setup: bf16 casts + all B^T builders + cj + zero16 ----------------

#define N_CONV ((NU_ * 32 + NM_ * 128) / 4)
#define N_BT1U (16 * 32)
#define N_BT1M (144 * 128)
#define N_BTP  (128 * 256)
#define N_BT2  (80 * 128)

__global__ __launch_bounds__(256) void setup_all(
    const float* __restrict__ xu, ushort* __restrict__ xu_bf,
    const float* __restrict__ xm, ushort* __restrict__ xm_bf,
    const float* __restrict__ w1um_s, const float* __restrict__ a1um_s,
    const float* __restrict__ w1mu_d, const float* __restrict__ a1mu_d,
    ushort* __restrict__ Bt1u,
    const float* __restrict__ w1mu_s, const float* __restrict__ a1mu_s,
    const float* __restrict__ w1um_d, const float* __restrict__ a1um_d,
    ushort* __restrict__ Bt1m, ushort* __restrict__ Btp,
    const float* __restrict__ w2um_s, const float* __restrict__ a2um_s,
    const float* __restrict__ w2mu_d, const float* __restrict__ a2mu_d,
    ushort* __restrict__ Bt2u,
    const float* __restrict__ w2mu_s, const float* __restrict__ a2mu_s,
    const float* __restrict__ w2um_d, const float* __restrict__ a2um_d,
    ushort* __restrict__ Bt2m,
    const float* __restrict__ b2mu, const float* __restrict__ b2um,
    const float* __restrict__ dw1, const float* __restrict__ db1,
    float* __restrict__ cj, float* __restrict__ zero16) {
    int i = blockIdx.x * blockDim.x + threadIdx.x;
    if (i < N_CONV) {
        const float* s; ushort* d; int idx;
        int n4a = NU_ * 32 / 4;
        if (i < n4a) { s = xu; d = xu_bf; idx = i; }
        else { s = xm; d = xm_bf; idx = i - n4a; }
        float4 v = ((const float4*)s)[idx];
        ushort4 o;
        o.x = f2bf(v.x); o.y = f2bf(v.y); o.z = f2bf(v.z); o.w = f2bf(v.w);
        ((ushort4*)d)[idx] = o;
        return;
    }
    i -= N_CONV;
    if (i < N_BT1U) {
        int c = i >> 5, k = i & 31;
        float v = 0.f;
        if (c < 8) {
            for (int cc = 0; cc < 16; ++cc)
                v += w1um_s[(size_t)k * 128 + c * 16 + cc] * a1um_s[c * 16 + cc];
        } else {
            int h = c - 8;
            for (int cc = 0; cc < 16; ++cc)
                v += w1mu_d[(size_t)k * 128 + h * 16 + cc] * a1mu_d[h * 16 + cc];
        }
        Bt1u[c * 32 + k] = f2bf(v);
        return;
    }
    i -= N_BT1U;
    if (i < N_BT1M) {
        int c = i >> 7, k = i & 127;
        float v;
        if (c < 128) {
            v = w1mu_s[(size_t)k * 128 + c];
        } else if (c < 136) {
            int h = c - 128; v = 0.f;
            for (int cc = 0; cc < 16; ++cc)
                v += w1mu_s[(size_t)k * 128 + h * 16 + cc] * a1mu_s[h * 16 + cc];
        } else {
            int h = c - 136; v = 0.f;
            for (int cc = 0; cc < 16; ++cc)
                v += w1um_d[(size_t)k * 128 + h * 16 + cc] * a1um_d[h * 16 + cc];
        }
        Bt1m[(size_t)c * 128 + k] = f2bf(v);
        return;
    }
    i -= N_BT1M;
    if (i < N_BTP) {
        int c = i >> 8, kk = i & 255;
        int h = kk >> 5, k = kk & 31;
        float v = ((c >> 4) == h) ? w1um_s[(size_t)k * 128 + c] : 0.f;
        Btp[(size_t)c * 256 + kk] = f2bf(v);
        return;
    }
    i -= N_BTP;
    if (i < N_BT2) {
        int c = i >> 7, k = i & 127;
        float v = 0.f;
        if (c < 64) {
            int h = c >> 4, j = c & 15;
            for (int cc = 0; cc < 128; ++cc)
                v += w2um_s[(size_t)k * 512 + h * 128 + cc] * dw1[(size_t)(512 + h * 128 + cc) * 16 + j];
        } else if (c < 68) {
            int h = c - 64;
            for (int cc = 0; cc < 128; ++cc)
                v += w2um_s[(size_t)k * 512 + h * 128 + cc] * a2um_s[h * 128 + cc];
        } else if (c < 72) {
            int h = c - 68;
            for (int cc = 0; cc < 128; ++cc)
                v += w2mu_d[(size_t)k * 512 + h * 128 + cc] * a2mu_d[h * 128 + cc];
        }
        Bt2u[(size_t)c * 128 + k] = f2bf(v);
        return;
    }
    i -= N_BT2;
    if (i < N_BT2) {
        int c = i >> 7, k = i & 127;
        float v = 0.f;
        if (c < 64) {
            int h = c >> 4, j = c & 15;
            for (int cc = 0; cc < 128; ++cc)
                v += w2mu_s[(size_t)k * 512 + h * 128 + cc] * dw1[(size_t)(h * 128 + cc) * 16 + j];
        } else if (c < 68) {
            int h = c - 64;
            for (int cc = 0; cc < 128; ++cc)
                v += w2mu_s[(size_t)k * 512 + h * 128 + cc] * a2mu_s[h * 128 + cc];
        } else if (c < 72) {
            int h = c - 68;
            for (int cc = 0; cc < 128; ++cc)
                v += w2um_d[(size_t)k * 512 + h * 128 + cc] * a2um_d[h * 128 + cc];
        }
        Bt2m[(size_t)c * 128 + k] = f2bf(v);
        return;
    }
    i -= N_BT2;
    if (i < 16) {
        float s = db1[i];
        for (int col = 0; col < 512; ++col)
            s += b2mu[col] * dw1[col * 16 + i] + b2um[col] * dw1[(512 + col) * 16 + i];
        cj[i] = s;
    } else if (i < 32) {
        zero16[i - 16] = 0.f;
    }
}

// ---------------- MFMA GEMM body ----------------
template <int K, int NT>
__device__ __forceinline__ void mfma_body(
    int blk, const ushort* __restrict__ A, const ushort* __restrict__ Bt,
    ushort* __restrict__ outb, int sb, float* __restrict__ outf, int sf,
    int splitc, int maxc, int Nrows, const float* __restrict__ bias, int dorelu) {
    int wave = threadIdx.x >> 6;
    int lane = threadIdx.x & 63;
    int row0 = (blk * 4 + wave) * 16;
    if (row0 >= Nrows) return;
    int r = lane & 15;
    int kb = lane >> 4;
    bf16x8 afrag[K / 32];
    int arow = row0 + r;
    bool rowok = (arow < Nrows);
#pragma unroll
    for (int ks = 0; ks < K / 32; ++ks) {
        if (rowok)
            afrag[ks] = *(const bf16x8*)(A + (size_t)arow * K + ks * 32 + kb * 8);
        else
            afrag[ks] = (bf16x8){0, 0, 0, 0, 0, 0, 0, 0};
    }
#pragma unroll
    for (int nt = 0; nt < NT; ++nt) {
        f32x4 acc = {0.f, 0.f, 0.f, 0.f};
#pragma unroll
        for (int ks = 0; ks < K / 32; ++ks) {
            bf16x8 bfrag = *(const bf16x8*)(Bt + (size_t)(nt * 16 + r) * K + ks * 32 + kb * 8);
            acc = __builtin_amdgcn_mfma_f32_16x16x32_bf16(afrag[ks], bfrag, acc, 0, 0, 0);
        }
        int col = nt * 16 + r;
        float bv = (bias && col < splitc) ? bias[col] : 0.f;
#pragma unroll
        for (int reg = 0; reg < 4; ++reg) {
            int rr = row0 + kb * 4 + reg;
            if (rr < Nrows) {
                if (col < splitc) {
                    float v = acc[reg] + bv;
                    if (dorelu) v = fmaxf(v, 0.f);
                    outb[(size_t)rr * sb + col] = f2bf(v);
                } else if (col < maxc) {
                    outf[(size_t)rr * sf + (col - splitc)] = acc[reg];
                }
            }
        }
    }
}

__global__ __launch_bounds__(256) void gemm_l1(
    const ushort* __restrict__ xu_bf, const ushort* __restrict__ Bt1u,
    float* __restrict__ hlog_u,
    const ushort* __restrict__ xm_bf, const ushort* __restrict__ Bt1m,
    ushort* __restrict__ hproj_m, float* __restrict__ hlog_m, int gNU) {
    int b = blockIdx.x;
    if (b < gNU)
        mfma_body<32, 1>(b, xu_bf, Bt1u, nullptr, 0, hlog_u, 16, 0, 16, NU_, nullptr, 0);
    else
        mfma_body<128, 9>(b - gNU, xm_bf, Bt1m, hproj_m, 128, hlog_m, 16, 128, 144, NM_, nullptr, 0);
}

__global__ __launch_bounds__(256) void gemm_proj(
    const ushort* __restrict__ aggx, const ushort* __restrict__ Btp,
    ushort* __restrict__ zm_bf, const float* __restrict__ b1um) {
    mfma_body<256, 8>(blockIdx.x, aggx, Btp, zm_bf, 128, nullptr, 0, 128, 128, NM_, b1um, 1);
}

__global__ __launch_bounds__(256) void gemm_l2(
    const ushort* __restrict__ zu_bf, const ushort* __restrict__ Bt2u,
    ushort* __restrict__ qq_u, float* __restrict__ qlog_u,
    const ushort* __restrict__ zm_bf, const ushort* __restrict__ Bt2m,
    ushort* __restrict__ qq_m, float* __restrict__ qlog_m, int gNU) {
    int b = blockIdx.x;
    if (b < gNU)
        mfma_body<128, 5>(b, zu_bf, Bt2u, qq_u, 64, qlog_u, 8, 64, 72, NU_, nullptr, 0);
    else
        mfma_body<128, 5>(b - gNU, zm_bf, Bt2m, qq_m, 64, qlog_m, 8, 64, 72, NM_, nullptr, 0);
}

// ---------------- merged layer-1 aggregations (16B loads, edge-parallel) ----------------
// A-part: raw-x um, 1 dst/wave, 2 slots x 32 lanes (lane: h=l5>>2, c8=(l5&3)*8)
// B-part: hproj_m mu, 4 dst/wave x 16 lanes (lane: h=l>>1, c8=l*8)
__global__ __launch_bounds__(256) void agg_l1(
    const ushort* __restrict__ xu_bf, const float* __restrict__ hlog_u,
    const float* __restrict__ hlog_m, const int* __restrict__ rp_um,
    const int* __restrict__ ssrc_um, ushort* __restrict__ aggx,
    const ushort* __restrict__ hproj_m, const int* __restrict__ rp_mu,
    const int* __restrict__ ssrc_mu, const float* __restrict__ b1mu,
    ushort* __restrict__ zu_bf, int gA) {
    int b = blockIdx.x;
    int lane = threadIdx.x & 63;
    if (b < gA) {
        int wid = (b * 256 + (int)threadIdx.x) >> 6;
        if (wid >= NM_) return;
        int slot = lane >> 5;
        int l5 = lane & 31;
        int h = l5 >> 2, c8 = (l5 & 3) * 8;
        int r0 = rp_um[wid], r1 = rp_um[wid + 1];
        float edv = hlog_m[(size_t)wid * 16 + 8 + h];
        float ssum = 0.f;
        float acc[8] = {0.f, 0.f, 0.f, 0.f, 0.f, 0.f, 0.f, 0.f};
        for (int base = r0; base < r1; base += 64) {
            int cnt = min(64, r1 - base);
            int sv = (base + lane < r1) ? ssrc_um[base + lane] : 0;
            for (int j = 0; j < cnt; j += 2) {
                int jj = j + slot;
                int s = __shfl(sv, jj, 64);
                float x = hlog_u[(size_t)s * 16 + h] + edv;
                x = x > 0.f ? x : 0.2f * x;
                float w = (jj < cnt) ? __expf(x) : 0.f;
                ssum += w;
                bf16x8 xv = *(const bf16x8*)(xu_bf + (size_t)s * 32 + c8);
#pragma unroll
                for (int t = 0; t < 8; ++t)
                    acc[t] = fmaf(bf2f((ushort)xv[t]), w, acc[t]);
            }
        }
        ssum += __shfl_xor(ssum, 32, 64);
#pragma unroll
        for (int t = 0; t < 8; ++t) acc[t] += __shfl_xor(acc[t], 32, 64);
        float inv = 1.f / (ssum + 1e-16f);
        if (slot == 0) {
            bf16x8 o;
#pragma unroll
            for (int t = 0; t < 8; ++t) o[t] = (short)f2bf(acc[t] * inv);
            *(bf16x8*)(aggx + (size_t)wid * 256 + h * 32 + c8) = o;
        }
    } else {
        int wid = ((b - gA) * 256 + (int)threadIdx.x) >> 6;
        int g = lane >> 4, l = lane & 15;
        int dst = wid * 4 + g;
        if (dst >= NU_) return;
        int h = l >> 1, c8 = l * 8;
        int r0 = rp_mu[dst], r1 = rp_mu[dst + 1];
        float edv = hlog_u[(size_t)dst * 16 + 8 + h];
        float ssum = 0.f;
        float acc[8] = {0.f, 0.f, 0.f, 0.f, 0.f, 0.f, 0.f, 0.f};
        for (int base = r0; base < r1; base += 16) {
            int cnt = min(16, r1 - base);
            int sv = (base + l < r1) ? ssrc_mu[base + l] : 0;
            for (int j = 0; j < cnt; ++j) {
                int s = __shfl(sv, (g << 4) | j, 64);
                float x = hlog_m[(size_t)s * 16 + h] + edv;
                x = x > 0.f ? x : 0.2f * x;
                float w = __expf(x);
                ssum += w;
                bf16x8 hv = *(const bf16x8*)(hproj_m + (size_t)s * 128 + c8);
#pragma unroll
                for (int t = 0; t < 8; ++t)
                    acc[t] = fmaf(bf2f((ushort)hv[t]), w, acc[t]);
            }
        }
        float inv = 1.f / (ssum + 1e-16f);
        bf16x8 o;
#pragma unroll
        for (int t = 0; t < 8; ++t) {
            float v = fmaxf(fmaf(acc[t], inv, b1mu[c8 + t]), 0.f);
            o[t] = (short)f2bf(v);
        }
        *(bf16x8*)(zu_bf + (size_t)dst * 128 + c8) = o;
    }
}

// ---------------- layer-2 aggregation, both directions, 8 dsts/wave, 16B loads ----------------
// 8 lanes per dst: h = l>>1, c8 = l*8; per-head normalize then head-sum via xor 2,4
__global__ __launch_bounds__(256) void agg_l2_m(
    const ushort* __restrict__ qA, const float* __restrict__ esA,
    const float* __restrict__ edA, const int* __restrict__ rpA,
    const int* __restrict__ srcA, const float* __restrict__ biasA,
    float* __restrict__ outA, int NdA,
    const ushort* __restrict__ qB, const float* __restrict__ esB,
    const float* __restrict__ edB, const int* __restrict__ rpB,
    const int* __restrict__ srcB, const float* __restrict__ biasB,
    float* __restrict__ outB, int NdB) {
    int wid = (blockIdx.x * 256 + threadIdx.x) >> 6;
    int lane = threadIdx.x & 63;
    int g = lane >> 3, l = lane & 7;
    int nwA = (NdA + 7) >> 3;
    const ushort* q; const float* es; const float* ed; const int* rp;
    const int* src; const float* bias16; float* o16; int dst, Nd;
    if (wid < nwA) {
        q = qA; es = esA; ed = edA; rp = rpA; src = srcA;
        bias16 = biasA; o16 = outA; Nd = NdA; dst = wid * 8 + g;
    } else {
        int w2 = wid - nwA;
        q = qB; es = esB; ed = edB; rp = rpB; src = srcB;
        bias16 = biasB; o16 = outB; Nd = NdB; dst = w2 * 8 + g;
    }
    if (dst >= Nd) return;
    int h = l >> 1, c8 = l * 8;
    int r0 = rp[dst], r1 = rp[dst + 1];
    float edv = ed[(size_t)dst * 8 + h];
    float ssum = 0.f;
    float acc[8] = {0.f, 0.f, 0.f, 0.f, 0.f, 0.f, 0.f, 0.f};
    for (int base = r0; base < r1; base += 8) {
        int cnt = min(8, r1 - base);
        int sv = (base + l < r1) ? src[base + l] : 0;
        for (int j = 0; j < cnt; ++j) {
            int s = __shfl(sv, (g << 3) | j, 64);
            float x = es[(size_t)s * 8 + h] + edv;
            x = x > 0.f ? x : 0.2f * x;
            float w = __expf(x);
            ssum += w;
            bf16x8 qv = *(const bf16x8*)(q + (size_t)s * 64 + c8);
#pragma unroll
            for (int t = 0; t < 8; ++t)
                acc[t] = fmaf(bf2f((ushort)qv[t]), w, acc[t]);
        }
    }
    float inv = 1.f / (ssum + 1e-16f);
#pragma unroll
    for (int t = 0; t < 8; ++t) {
        acc[t] *= inv;
        acc[t] += __shfl_xor(acc[t], 2, 64);
        acc[t] += __shfl_xor(acc[t], 4, 64);
    }
    if (l < 2) {
        int jb = 8 * l;
        float4 o0 = make_float4(acc[0] + bias16[jb + 0], acc[1] + bias16[jb + 1],
                                acc[2] + bias16[jb + 2], acc[3] + bias16[jb + 3]);
        float4 o1 = make_float4(acc[4] + bias16[jb + 4], acc[5] + bias16[jb + 5],
                                acc[6] + bias16[jb + 6], acc[7] + bias16[jb + 7]);
        *(float4*)(o16 + (size_t)dst * 16 + jb) = o0;
        *(float4*)(o16 + (size_t)dst * 16 + jb + 4) = o1;
    }
}

// ---------------- decoder: 4 lanes per label edge, float4 loads ----------------
__global__ __launch_bounds__(256) void decoder4(
    const float* __restrict__ pu16, const float* __restrict__ pm16,
    const int* __restrict__ lab_u, const int* __restrict__ lab_m,
    const float* __restrict__ dw2, const float* __restrict__ db2,
    float* __restrict__ out, int nE) {
    int t = blockIdx.x * 256 + threadIdx.x;
    int e = t >> 2, sub = t & 3;
    if (e >= nE) return;
    int u = lab_u[e], m = lab_m[e];
    float4 a = *(const float4*)(pu16 + (size_t)u * 16 + sub * 4);
    float4 b = *(const float4*)(pm16 + (size_t)m * 16 + sub * 4);
    const float* w = dw2 + sub * 4;
    float r = fmaxf(a.x + b.x, 0.f) * w[0] + fmaxf(a.y + b.y, 0.f) * w[1] +
              fmaxf(a.z + b.z, 0.f) * w[2] + fmaxf(a.w + b.w, 0.f) * w[3];
    r += __shfl_xor(r, 1, 64);
    r += __shfl_xor(r, 2, 64);
    if (sub == 0) out[e] = r + db2[0];
}

// ---------------- host ----------------

extern "C" void kernel_launch(void* const* d_in, const int* in_sizes, int n_in,
                              void* d_out, int out_size, void* d_ws, size_t ws_size,
                              hipStream_t stream) {
    const float* xu = (const float*)d_in[0];
    const float* xm = (const float*)d_in[1];
    const int* um_src = (const int*)d_in[2];
    const int* um_dst = (const int*)d_in[3];
    const int* mu_src = (const int*)d_in[4];
    const int* mu_dst = (const int*)d_in[5];
    const int* lab_u = (const int*)d_in[6];
    const int* lab_m = (const int*)d_in[7];
    const float* w1um_s = (const float*)d_in[8];
    const float* w1um_d = (const float*)d_in[9];
    const float* a1um_s = (const float*)d_in[10];
    const float* a1um_d = (const float*)d_in[11];
    const float* b1um = (const float*)d_in[12];
    const float* w1mu_s = (const float*)d_in[13];
    const float* w1mu_d = (const float*)d_in[14];
    const float* a1mu_s = (const float*)d_in[15];
    const float* a1mu_d = (const float*)d_in[16];
    const float* b1mu = (const float*)d_in[17];
    const float* w2um_s = (const float*)d_in[18];
    const float* w2um_d = (const float*)d_in[19];
    const float* a2um_s = (const float*)d_in[20];
    const float* a2um_d = (const float*)d_in[21];
    const float* b2um = (const float*)d_in[22];
    const float* w2mu_s = (const float*)d_in[23];
    const float* w2mu_d = (const float*)d_in[24];
    const float* a2mu_s = (const float*)d_in[25];
    const float* a2mu_d = (const float*)d_in[26];
    const float* b2mu = (const float*)d_in[27];
    const float* dw1 = (const float*)d_in[28];
    const float* db1 = (const float*)d_in[29];
    const float* dw2 = (const float*)d_in[30];
    const float* db2 = (const float*)d_in[31];
    float* out = (float*)d_out;

    // -------- workspace carving --------
    char* base = (char*)d_ws;
    size_t off = 0;
    auto alloc = [&](size_t bytes) -> void* {
        void* p = base + off;
        off = (off + bytes + 63) & ~(size_t)63;
        return p;
    };
    ushort* xu_bf   = (ushort*)alloc((size_t)NU_ * 32 * 2);
    ushort* xm_bf   = (ushort*)alloc((size_t)NM_ * 128 * 2);
    ushort* hproj_m = (ushort*)alloc((size_t)NM_ * 128 * 2);
    ushort* aggx    = (ushort*)alloc((size_t)NM_ * 256 * 2);
    ushort* zu_bf   = (ushort*)alloc((size_t)NU_ * 128 * 2);
    ushort* zm_bf   = (ushort*)alloc((size_t)NM_ * 128 * 2);
    ushort* qq_u    = (ushort*)alloc((size_t)NU_ * 64 * 2);
    ushort* qq_m    = (ushort*)alloc((size_t)NM_ * 64 * 2);
    ushort* Bt1u    = (ushort*)alloc((size_t)16 * 32 * 2);
    ushort* Bt1m    = (ushort*)alloc((size_t)144 * 128 * 2);
    ushort* Btp     = (ushort*)alloc((size_t)128 * 256 * 2);
    ushort* Bt2u    = (ushort*)alloc((size_t)80 * 128 * 2);
    ushort* Bt2m    = (ushort*)alloc((size_t)80 * 128 * 2);
    float* hlog_u = (float*)alloc((size_t)NU_ * 16 * 4);
    float* hlog_m = (float*)alloc((size_t)NM_ * 16 * 4);
    float* qlog_u = (float*)alloc((size_t)NU_ * 8 * 4);
    float* qlog_m = (float*)alloc((size_t)NM_ * 8 * 4);
    float* pu16   = (float*)alloc((size_t)NU_ * 16 * 4);
    float* pm16   = (float*)alloc((size_t)NM_ * 16 * 4);
    float* cj     = (float*)alloc(16 * 4);
    float* zero16 = (float*)alloc(16 * 4);
    int* rp_um    = (int*)alloc((NM_ + 1) * 4);
    int* rp_mu    = (int*)alloc((NU_ + 1) * 4);
    int* ssrc_um  = (int*)alloc((size_t)NE_ * 4);
    int* ssrc_mu  = (int*)alloc((size_t)NE_ * 4);
    int* ofs      = (int*)alloc((size_t)(NM_ + NU_) * 4);
    int* partials = (int*)alloc(128 * 4);
    if (ws_size < off) {
        fprintf(stderr, "kernel_launch: ws too small (%zu < %zu)\n", ws_size, off);
        return;
    }

    const int TB = 256;
    const int nbM = cdiv_i(NM_, SCHUNK);
    const int nbU = cdiv_i(NU_, SCHUNK);

    // -------- CSR (both graphs) --------
    hipMemsetAsync(ofs, 0, (size_t)(NM_ + NU_) * sizeof(int), stream);
    count_both<<<cdiv_i(2 * NE_, TB), TB, 0, stream>>>(um_dst, mu_dst, ofs);
    scan_phaseA2<<<nbM + nbU, 256, 0, stream>>>(ofs, partials, nbM);
    scan_phaseB2<<<1, 64, 0, stream>>>(partials, nbM, nbU, rp_um, rp_mu);
    scan_phaseC2<<<nbM + nbU, 256, 0, stream>>>(ofs, partials, rp_um, rp_mu, nbM);
    copy_both<<<cdiv_i(NM_ + NU_, TB), TB, 0, stream>>>(rp_um, rp_mu, ofs);
    fill_both<<<cdiv_i(2 * NE_, TB), TB, 0, stream>>>(
        um_dst, um_src, mu_dst, mu_src, ofs, ssrc_um, ssrc_mu);

    // -------- fused setup --------
    {
        int ntot = N_CONV + N_BT1U + N_BT1M + N_BTP + 2 * N_BT2 + 32;
        setup_all<<<cdiv_i(ntot, TB), TB, 0, stream>>>(
            xu, xu_bf, xm, xm_bf,
            w1um_s, a1um_s, w1mu_d, a1mu_d, Bt1u,
            w1mu_s, a1mu_s, w1um_d, a1um_d, Bt1m, Btp,
            w2um_s, a2um_s, w2mu_d, a2mu_d, Bt2u,
            w2mu_s, a2mu_s, w2um_d, a2um_d, Bt2m,
            b2mu, b2um, dw1, db1, cj, zero16);
    }

    // -------- layer-1 GEMMs (merged) --------
    {
        int gNU = cdiv_i(NU_, 64), gNM = cdiv_i(NM_, 64);
        gemm_l1<<<gNU + gNM, TB, 0, stream>>>(
            xu_bf, Bt1u, hlog_u, xm_bf, Bt1m, hproj_m, hlog_m, gNU);
    }

    // -------- layer-1 aggregations (merged) --------
    {
        int gA = cdiv_i(NM_, 4), gB = cdiv_i(NU_, 16);
        agg_l1<<<gA + gB, TB, 0, stream>>>(
            xu_bf, hlog_u, hlog_m, rp_um, ssrc_um, aggx,
            hproj_m, rp_mu, ssrc_mu, b1mu, zu_bf, gA);
    }
    gemm_proj<<<cdiv_i(NM_, 64), TB, 0, stream>>>(aggx, Btp, zm_bf, b1um);

    // -------- layer-2 GEMMs (merged) --------
    {
        int gNU = cdiv_i(NU_, 64), gNM = cdiv_i(NM_, 64);
        gemm_l2<<<gNU + gNM, TB, 0, stream>>>(
            zu_bf, Bt2u, qq_u, qlog_u, zm_bf, Bt2m, qq_m, qlog_m, gNU);
    }

    // -------- layer-2 aggregation (merged, 8 dst/wave) --------
    {
        int nwA = cdiv_i(NM_, 8), nwB = cdiv_i(NU_, 8);
        agg_l2_m<<<cdiv_i(nwA + nwB, 4), TB, 0, stream>>>(
            qq_u, qlog_u, qlog_m + 4, rp_um, ssrc_um, cj, pm16, NM_,
            qq_m, qlog_m, qlog_u + 4, rp_mu, ssrc_mu, zero16, pu16, NU_);
    }

    // -------- decoder --------
    decoder4<<<cdiv_i(EL_ * 4, TB), TB, 0, stream>>>(
        pu16, pm16, lab_u, lab_m, dw2, db2, out, EL_);
}

// Round 12
// 208.067 us; speedup vs baseline: 4.6747x; 1.0795x over previous
//
#include <hip/hip_runtime.h>
#include <hip/hip_bf16.h>
#include <cstdio>

#define NU_ 100000
#define NM_ 20000
#define NE_ 250000
#define EL_ 200000
#define SCHUNK 2048

static inline int cdiv_i(int a, int b) { return (a + b - 1) / b; }

typedef __attribute__((ext_vector_type(8))) short bf16x8;
typedef __attribute__((ext_vector_type(4))) float f32x4;

__device__ __forceinline__ float bf2f(ushort u) {
    unsigned x = ((unsigned)u) << 16;
    return __builtin_bit_cast(float, x);
}
__device__ __forceinline__ ushort f2bf(float f) {
    unsigned x = __builtin_bit_cast(unsigned, f);
    x += 0x7fff + ((x >> 16) & 1);   // RNE
    return (ushort)(x >> 16);
}

// ---------------- CSR build (both graphs fused) ----------------

__global__ void count_both(const int* __restrict__ um_dst, const int* __restrict__ mu_dst,
                           int* __restrict__ cnt) {   // cnt: [NM_ | NU_]
    int i = blockIdx.x * blockDim.x + threadIdx.x;
    if (i < NE_) atomicAdd(&cnt[um_dst[i]], 1);
    else if (i < 2 * NE_) atomicAdd(&cnt[NM_ + mu_dst[i - NE_]], 1);
}

__global__ void fill_both(const int* __restrict__ um_dst, const int* __restrict__ um_src,
                          const int* __restrict__ mu_dst, const int* __restrict__ mu_src,
                          int* __restrict__ ofs, int* __restrict__ ssrc_um,
                          int* __restrict__ ssrc_mu) {
    int i = blockIdx.x * blockDim.x + threadIdx.x;
    if (i < NE_) {
        int p = atomicAdd(&ofs[um_dst[i]], 1);
        ssrc_um[p] = um_src[i];
    } else if (i < 2 * NE_) {
        int j = i - NE_;
        int p = atomicAdd(&ofs[NM_ + mu_dst[j]], 1);
        ssrc_mu[p] = mu_src[j];
    }
}

__global__ __launch_bounds__(256) void scan_phaseA2(const int* __restrict__ in,
                                                    int* __restrict__ partial, int nbM) {
    __shared__ int red[256];
    int b = blockIdx.x, tid = threadIdx.x;
    const int* src; int n; int* part; int bb;
    if (b < nbM) { src = in; n = NM_; part = partial; bb = b; }
    else { src = in + NM_; n = NU_; part = partial + nbM; bb = b - nbM; }
    int base = bb * SCHUNK + tid * 8;
    int s = 0;
#pragma unroll
    for (int j = 0; j < 8; ++j) { int i = base + j; if (i < n) s += src[i]; }
    red[tid] = s;
    __syncthreads();
    for (int off = 128; off; off >>= 1) {
        if (tid < off) red[tid] += red[tid + off];
        __syncthreads();
    }
    if (tid == 0) part[bb] = red[0];
}

// wave-parallel scan of both partial segments (nbM, nbU <= 64)
__global__ void scan_phaseB2(int* __restrict__ partial, int nbM, int nbU,
                             int* __restrict__ rp_um, int* __restrict__ rp_mu) {
    int lane = threadIdx.x & 63;
    int vm = (lane < nbM) ? partial[lane] : 0;
    int om = vm;
#pragma unroll
    for (int off = 1; off < 64; off <<= 1) {
        int y = __shfl_up(vm, off, 64);
        if (lane >= off) vm += y;
    }
    if (lane < nbM) partial[lane] = vm - om;
    if (lane == nbM - 1) rp_um[NM_] = vm;
    int vu = (lane < nbU) ? partial[nbM + lane] : 0;
    int ou = vu;
#pragma unroll
    for (int off = 1; off < 64; off <<= 1) {
        int y = __shfl_up(vu, off, 64);
        if (lane >= off) vu += y;
    }
    if (lane < nbU) partial[nbM + lane] = vu - ou;
    if (lane == nbU - 1) rp_mu[NU_] = vu;
}

// phase C also re-writes ofs (= running offsets) so copy_both is not needed
__global__ __launch_bounds__(256) void scan_phaseC2(int* __restrict__ inout,
                                                    const int* __restrict__ partial,
                                                    int* __restrict__ rp_um,
                                                    int* __restrict__ rp_mu, int nbM) {
    __shared__ int tsum[256];
    int b = blockIdx.x, tid = threadIdx.x;
    int* src; int n; const int* part; int* outp; int bb;
    if (b < nbM) { src = inout; n = NM_; part = partial; outp = rp_um; bb = b; }
    else { src = inout + NM_; n = NU_; part = partial + nbM; outp = rp_mu; bb = b - nbM; }
    int base = bb * SCHUNK + tid * 8;
    int v[8];
    int s = 0;
#pragma unroll
    for (int j = 0; j < 8; ++j) { int i = base + j; v[j] = (i < n) ? src[i] : 0; s += v[j]; }
    tsum[tid] = s;
    __syncthreads();
    for (int off = 1; off < 256; off <<= 1) {
        int y = (tid >= off) ? tsum[tid - off] : 0;
        __syncthreads();
        tsum[tid] += y;
        __syncthreads();
    }
    int run = part[bb] + tsum[tid] - s;
#pragma unroll
    for (int j = 0; j < 8; ++j) {
        int i = base + j;
        if (i < n) { outp[i] = run; src[i] = run; }
        run += v[j];
    }
}

// ---------------- fused setup: builders first (long poles), conv last ----------------

#define N_BT1U (16 * 32)
#define N_BT1M (144 * 128)
#define N_BTP  (128 * 256)
#define N_BT2  (80 * 128)
#define N_CJ   (32 * 16)
#define N_CONV ((NU_ * 32 + NM_ * 128) / 4)

__global__ __launch_bounds__(256) void setup_all(
    const float* __restrict__ xu, ushort* __restrict__ xu_bf,
    const float* __restrict__ xm, ushort* __restrict__ xm_bf,
    const float* __restrict__ w1um_s, const float* __restrict__ a1um_s,
    const float* __restrict__ w1mu_d, const float* __restrict__ a1mu_d,
    ushort* __restrict__ Bt1u,
    const float* __restrict__ w1mu_s, const float* __restrict__ a1mu_s,
    const float* __restrict__ w1um_d, const float* __restrict__ a1um_d,
    ushort* __restrict__ Bt1m, ushort* __restrict__ Btp,
    const float* __restrict__ w2um_s, const float* __restrict__ a2um_s,
    const float* __restrict__ w2mu_d, const float* __restrict__ a2mu_d,
    ushort* __restrict__ Bt2u,
    const float* __restrict__ w2mu_s, const float* __restrict__ a2mu_s,
    const float* __restrict__ w2um_d, const float* __restrict__ a2um_d,
    ushort* __restrict__ Bt2m,
    const float* __restrict__ b2mu, const float* __restrict__ b2um,
    const float* __restrict__ dw1, const float* __restrict__ db1,
    float* __restrict__ cj, float* __restrict__ zero16) {
    int i = blockIdx.x * blockDim.x + threadIdx.x;
    // S0: Bt2u (k-major: c fastest for coalesced dw1/a2 reads)
    if (i < N_BT2) {
        int k = i / 80, c = i % 80;
        float v = 0.f;
        if (c < 64) {
            int h = c >> 4, j = c & 15;
            for (int cc = 0; cc < 128; ++cc)
                v += w2um_s[(size_t)k * 512 + h * 128 + cc] * dw1[(size_t)(512 + h * 128 + cc) * 16 + j];
        } else if (c < 68) {
            int h = c - 64;
            for (int cc = 0; cc < 128; ++cc)
                v += w2um_s[(size_t)k * 512 + h * 128 + cc] * a2um_s[h * 128 + cc];
        } else if (c < 72) {
            int h = c - 68;
            for (int cc = 0; cc < 128; ++cc)
                v += w2mu_d[(size_t)k * 512 + h * 128 + cc] * a2mu_d[h * 128 + cc];
        }
        Bt2u[(size_t)c * 128 + k] = f2bf(v);
        return;
    }
    i -= N_BT2;
    // S1: Bt2m
    if (i < N_BT2) {
        int k = i / 80, c = i % 80;
        float v = 0.f;
        if (c < 64) {
            int h = c >> 4, j = c & 15;
            for (int cc = 0; cc < 128; ++cc)
                v += w2mu_s[(size_t)k * 512 + h * 128 + cc] * dw1[(size_t)(h * 128 + cc) * 16 + j];
        } else if (c < 68) {
            int h = c - 64;
            for (int cc = 0; cc < 128; ++cc)
                v += w2mu_s[(size_t)k * 512 + h * 128 + cc] * a2mu_s[h * 128 + cc];
        } else if (c < 72) {
            int h = c - 68;
            for (int cc = 0; cc < 128; ++cc)
                v += w2um_d[(size_t)k * 512 + h * 128 + cc] * a2um_d[h * 128 + cc];
        }
        Bt2m[(size_t)c * 128 + k] = f2bf(v);
        return;
    }
    i -= N_BT2;
    // S2: cj partials (32 col-groups x 16 j), atomicAdd into pre-zeroed cj
    if (i < N_CJ) {
        int g = i >> 4, j = i & 15;
        float s = 0.f;
        for (int cc = 0; cc < 16; ++cc) {
            int col = g * 16 + cc;
            s += b2mu[col] * dw1[col * 16 + j] + b2um[col] * dw1[(512 + col) * 16 + j];
        }
        if (g == 0) s += db1[j];
        atomicAdd(&cj[j], s);
        return;
    }
    i -= N_CJ;
    // S3: Bt1u
    if (i < N_BT1U) {
        int c = i >> 5, k = i & 31;
        float v = 0.f;
        if (c < 8) {
            for (int cc = 0; cc < 16; ++cc)
                v += w1um_s[(size_t)k * 128 + c * 16 + cc] * a1um_s[c * 16 + cc];
        } else {
            int h = c - 8;
            for (int cc = 0; cc < 16; ++cc)
                v += w1mu_d[(size_t)k * 128 + h * 16 + cc] * a1mu_d[h * 16 + cc];
        }
        Bt1u[c * 32 + k] = f2bf(v);
        return;
    }
    i -= N_BT1U;
    // S4: Bt1m
    if (i < N_BT1M) {
        int c = i >> 7, k = i & 127;
        float v;
        if (c < 128) {
            v = w1mu_s[(size_t)k * 128 + c];
        } else if (c < 136) {
            int h = c - 128; v = 0.f;
            for (int cc = 0; cc < 16; ++cc)
                v += w1mu_s[(size_t)k * 128 + h * 16 + cc] * a1mu_s[h * 16 + cc];
        } else {
            int h = c - 136; v = 0.f;
            for (int cc = 0; cc < 16; ++cc)
                v += w1um_d[(size_t)k * 128 + h * 16 + cc] * a1um_d[h * 16 + cc];
        }
        Bt1m[(size_t)c * 128 + k] = f2bf(v);
        return;
    }
    i -= N_BT1M;
    // S5: Btp (block-diag projection of w1um_s)
    if (i < N_BTP) {
        int c = i >> 8, kk = i & 255;
        int h = kk >> 5, k = kk & 31;
        float v = ((c >> 4) == h) ? w1um_s[(size_t)k * 128 + c] : 0.f;
        Btp[(size_t)c * 256 + kk] = f2bf(v);
        return;
    }
    i -= N_BTP;
    // S6: zero16
    if (i < 16) { zero16[i] = 0.f; return; }
    i -= 16;
    // S7: bf16 casts (bulk)
    if (i < N_CONV) {
        const float* s; ushort* d; int idx;
        int n4a = NU_ * 32 / 4;
        if (i < n4a) { s = xu; d = xu_bf; idx = i; }
        else { s = xm; d = xm_bf; idx = i - n4a; }
        float4 v = ((const float4*)s)[idx];
        ushort4 o;
        o.x = f2bf(v.x); o.y = f2bf(v.y); o.z = f2bf(v.z); o.w = f2bf(v.w);
        ((ushort4*)d)[idx] = o;
    }
}

// ---------------- MFMA GEMM body ----------------
template <int K, int NT>
__device__ __forceinline__ void mfma_body(
    int blk, const ushort* __restrict__ A, const ushort* __restrict__ Bt,
    ushort* __restrict__ outb, int sb, float* __restrict__ outf, int sf,
    int splitc, int maxc, int Nrows, const float* __restrict__ bias, int dorelu) {
    int wave = threadIdx.x >> 6;
    int lane = threadIdx.x & 63;
    int row0 = (blk * 4 + wave) * 16;
    if (row0 >= Nrows) return;
    int r = lane & 15;
    int kb = lane >> 4;
    bf16x8 afrag[K / 32];
    int arow = row0 + r;
    bool rowok = (arow < Nrows);
#pragma unroll
    for (int ks = 0; ks < K / 32; ++ks) {
        if (rowok)
            afrag[ks] = *(const bf16x8*)(A + (size_t)arow * K + ks * 32 + kb * 8);
        else
            afrag[ks] = (bf16x8){0, 0, 0, 0, 0, 0, 0, 0};
    }
#pragma unroll
    for (int nt = 0; nt < NT; ++nt) {
        f32x4 acc = {0.f, 0.f, 0.f, 0.f};
#pragma unroll
        for (int ks = 0; ks < K / 32; ++ks) {
            bf16x8 bfrag = *(const bf16x8*)(Bt + (size_t)(nt * 16 + r) * K + ks * 32 + kb * 8);
            acc = __builtin_amdgcn_mfma_f32_16x16x32_bf16(afrag[ks], bfrag, acc, 0, 0, 0);
        }
        int col = nt * 16 + r;
        float bv = (bias && col < splitc) ? bias[col] : 0.f;
#pragma unroll
        for (int reg = 0; reg < 4; ++reg) {
            int rr = row0 + kb * 4 + reg;
            if (rr < Nrows) {
                if (col < splitc) {
                    float v = acc[reg] + bv;
                    if (dorelu) v = fmaxf(v, 0.f);
                    outb[(size_t)rr * sb + col] = f2bf(v);
                } else if (col < maxc) {
                    outf[(size_t)rr * sf + (col - splitc)] = acc[reg];
                }
            }
        }
    }
}

__global__ __launch_bounds__(256) void gemm_l1(
    const ushort* __restrict__ xu_bf, const ushort* __restrict__ Bt1u,
    float* __restrict__ hlog_u,
    const ushort* __restrict__ xm_bf, const ushort* __restrict__ Bt1m,
    ushort* __restrict__ hproj_m, float* __restrict__ hlog_m, int gNU) {
    int b = blockIdx.x;
    if (b < gNU)
        mfma_body<32, 1>(b, xu_bf, Bt1u, nullptr, 0, hlog_u, 16, 0, 16, NU_, nullptr, 0);
    else
        mfma_body<128, 9>(b - gNU, xm_bf, Bt1m, hproj_m, 128, hlog_m, 16, 128, 144, NM_, nullptr, 0);
}

__global__ __launch_bounds__(256) void gemm_proj(
    const ushort* __restrict__ aggx, const ushort* __restrict__ Btp,
    ushort* __restrict__ zm_bf, const float* __restrict__ b1um) {
    mfma_body<256, 8>(blockIdx.x, aggx, Btp, zm_bf, 128, nullptr, 0, 128, 128, NM_, b1um, 1);
}

__global__ __launch_bounds__(256) void gemm_l2(
    const ushort* __restrict__ zu_bf, const ushort* __restrict__ Bt2u,
    ushort* __restrict__ qq_u, float* __restrict__ qlog_u,
    const ushort* __restrict__ zm_bf, const ushort* __restrict__ Bt2m,
    ushort* __restrict__ qq_m, float* __restrict__ qlog_m, int gNU) {
    int b = blockIdx.x;
    if (b < gNU)
        mfma_body<128, 5>(b, zu_bf, Bt2u, qq_u, 64, qlog_u, 8, 64, 72, NU_, nullptr, 0);
    else
        mfma_body<128, 5>(b - gNU, zm_bf, Bt2m, qq_m, 64, qlog_m, 8, 64, 72, NM_, nullptr, 0);
}

// ---------------- merged layer-1 aggregations (16B loads, edge-parallel) ----------------
__global__ __launch_bounds__(256) void agg_l1(
    const ushort* __restrict__ xu_bf, const float* __restrict__ hlog_u,
    const float* __restrict__ hlog_m, const int* __restrict__ rp_um,
    const int* __restrict__ ssrc_um, ushort* __restrict__ aggx,
    const ushort* __restrict__ hproj_m, const int* __restrict__ rp_mu,
    const int* __restrict__ ssrc_mu, const float* __restrict__ b1mu,
    ushort* __restrict__ zu_bf, int gA) {
    int b = blockIdx.x;
    int lane = threadIdx.x & 63;
    if (b < gA) {
        int wid = (b * 256 + (int)threadIdx.x) >> 6;
        if (wid >= NM_) return;
        int slot = lane >> 5;
        int l5 = lane & 31;
        int h = l5 >> 2, c8 = (l5 & 3) * 8;
        int r0 = rp_um[wid], r1 = rp_um[wid + 1];
        float edv = hlog_m[(size_t)wid * 16 + 8 + h];
        float ssum = 0.f;
        float acc[8] = {0.f, 0.f, 0.f, 0.f, 0.f, 0.f, 0.f, 0.f};
        for (int base = r0; base < r1; base += 64) {
            int cnt = min(64, r1 - base);
            int sv = (base + lane < r1) ? ssrc_um[base + lane] : 0;
            for (int j = 0; j < cnt; j += 2) {
                int jj = j + slot;
                int s = __shfl(sv, jj, 64);
                float x = hlog_u[(size_t)s * 16 + h] + edv;
                x = x > 0.f ? x : 0.2f * x;
                float w = (jj < cnt) ? __expf(x) : 0.f;
                ssum += w;
                bf16x8 xv = *(const bf16x8*)(xu_bf + (size_t)s * 32 + c8);
#pragma unroll
                for (int t = 0; t < 8; ++t)
                    acc[t] = fmaf(bf2f((ushort)xv[t]), w, acc[t]);
            }
        }
        ssum += __shfl_xor(ssum, 32, 64);
#pragma unroll
        for (int t = 0; t < 8; ++t) acc[t] += __shfl_xor(acc[t], 32, 64);
        float inv = 1.f / (ssum + 1e-16f);
        if (slot == 0) {
            bf16x8 o;
#pragma unroll
            for (int t = 0; t < 8; ++t) o[t] = (short)f2bf(acc[t] * inv);
            *(bf16x8*)(aggx + (size_t)wid * 256 + h * 32 + c8) = o;
        }
    } else {
        int wid = ((b - gA) * 256 + (int)threadIdx.x) >> 6;
        int g = lane >> 4, l = lane & 15;
        int dst = wid * 4 + g;
        if (dst >= NU_) return;
        int h = l >> 1, c8 = l * 8;
        int r0 = rp_mu[dst], r1 = rp_mu[dst + 1];
        float edv = hlog_u[(size_t)dst * 16 + 8 + h];
        float ssum = 0.f;
        float acc[8] = {0.f, 0.f, 0.f, 0.f, 0.f, 0.f, 0.f, 0.f};
        for (int base = r0; base < r1; base += 16) {
            int cnt = min(16, r1 - base);
            int sv = (base + l < r1) ? ssrc_mu[base + l] : 0;
            for (int j = 0; j < cnt; ++j) {
                int s = __shfl(sv, (g << 4) | j, 64);
                float x = hlog_m[(size_t)s * 16 + h] + edv;
                x = x > 0.f ? x : 0.2f * x;
                float w = __expf(x);
                ssum += w;
                bf16x8 hv = *(const bf16x8*)(hproj_m + (size_t)s * 128 + c8);
#pragma unroll
                for (int t = 0; t < 8; ++t)
                    acc[t] = fmaf(bf2f((ushort)hv[t]), w, acc[t]);
            }
        }
        float inv = 1.f / (ssum + 1e-16f);
        bf16x8 o;
#pragma unroll
        for (int t = 0; t < 8; ++t) {
            float v = fmaxf(fmaf(acc[t], inv, b1mu[c8 + t]), 0.f);
            o[t] = (short)f2bf(v);
        }
        *(bf16x8*)(zu_bf + (size_t)dst * 128 + c8) = o;
    }
}

// ---------------- layer-2 aggregation, both directions, 8 dsts/wave, 16B loads ----------------
__global__ __launch_bounds__(256) void agg_l2_m(
    const ushort* __restrict__ qA, const float* __restrict__ esA,
    const float* __restrict__ edA, const int* __restrict__ rpA,
    const int* __restrict__ srcA, const float* __restrict__ biasA,
    float* __restrict__ outA, int NdA,
    const ushort* __restrict__ qB, const float* __restrict__ esB,
    const float* __restrict__ edB, const int* __restrict__ rpB,
    const int* __restrict__ srcB, const float* __restrict__ biasB,
    float* __restrict__ outB, int NdB) {
    int wid = (blockIdx.x * 256 + threadIdx.x) >> 6;
    int lane = threadIdx.x & 63;
    int g = lane >> 3, l = lane & 7;
    int nwA = (NdA + 7) >> 3;
    const ushort* q; const float* es; const float* ed; const int* rp;
    const int* src; const float* bias16; float* o16; int dst, Nd;
    if (wid < nwA) {
        q = qA; es = esA; ed = edA; rp = rpA; src = srcA;
        bias16 = biasA; o16 = outA; Nd = NdA; dst = wid * 8 + g;
    } else {
        int w2 = wid - nwA;
        q = qB; es = esB; ed = edB; rp = rpB; src = srcB;
        bias16 = biasB; o16 = outB; Nd = NdB; dst = w2 * 8 + g;
    }
    if (dst >= Nd) return;
    int h = l >> 1, c8 = l * 8;
    int r0 = rp[dst], r1 = rp[dst + 1];
    float edv = ed[(size_t)dst * 8 + h];
    float ssum = 0.f;
    float acc[8] = {0.f, 0.f, 0.f, 0.f, 0.f, 0.f, 0.f, 0.f};
    for (int base = r0; base < r1; base += 8) {
        int cnt = min(8, r1 - base);
        int sv = (base + l < r1) ? src[base + l] : 0;
        for (int j = 0; j < cnt; ++j) {
            int s = __shfl(sv, (g << 3) | j, 64);
            float x = es[(size_t)s * 8 + h] + edv;
            x = x > 0.f ? x : 0.2f * x;
            float w = __expf(x);
            ssum += w;
            bf16x8 qv = *(const bf16x8*)(q + (size_t)s * 64 + c8);
#pragma unroll
            for (int t = 0; t < 8; ++t)
                acc[t] = fmaf(bf2f((ushort)qv[t]), w, acc[t]);
        }
    }
    float inv = 1.f / (ssum + 1e-16f);
#pragma unroll
    for (int t = 0; t < 8; ++t) {
        acc[t] *= inv;
        acc[t] += __shfl_xor(acc[t], 2, 64);
        acc[t] += __shfl_xor(acc[t], 4, 64);
    }
    if (l < 2) {
        int jb = 8 * l;
        float4 o0 = make_float4(acc[0] + bias16[jb + 0], acc[1] + bias16[jb + 1],
                                acc[2] + bias16[jb + 2], acc[3] + bias16[jb + 3]);
        float4 o1 = make_float4(acc[4] + bias16[jb + 4], acc[5] + bias16[jb + 5],
                                acc[6] + bias16[jb + 6], acc[7] + bias16[jb + 7]);
        *(float4*)(o16 + (size_t)dst * 16 + jb) = o0;
        *(float4*)(o16 + (size_t)dst * 16 + jb + 4) = o1;
    }
}

// ---------------- decoder: 4 lanes per label edge, float4 loads ----------------
__global__ __launch_bounds__(256) void decoder4(
    const float* __restrict__ pu16, const float* __restrict__ pm16,
    const int* __restrict__ lab_u, const int* __restrict__ lab_m,
    const float* __restrict__ dw2, const float* __restrict__ db2,
    float* __restrict__ out, int nE) {
    int t = blockIdx.x * 256 + threadIdx.x;
    int e = t >> 2, sub = t & 3;
    if (e >= nE) return;
    int u = lab_u[e], m = lab_m[e];
    float4 a = *(const float4*)(pu16 + (size_t)u * 16 + sub * 4);
    float4 b = *(const float4*)(pm16 + (size_t)m * 16 + sub * 4);
    const float* w = dw2 + sub * 4;
    float r = fmaxf(a.x + b.x, 0.f) * w[0] + fmaxf(a.y + b.y, 0.f) * w[1] +
              fmaxf(a.z + b.z, 0.f) * w[2] + fmaxf(a.w + b.w, 0.f) * w[3];
    r += __shfl_xor(r, 1, 64);
    r += __shfl_xor(r, 2, 64);
    if (sub == 0) out[e] = r + db2[0];
}

// ---------------- host ----------------

extern "C" void kernel_launch(void* const* d_in, const int* in_sizes, int n_in,
                              void* d_out, int out_size, void* d_ws, size_t ws_size,
                              hipStream_t stream) {
    const float* xu = (const float*)d_in[0];
    const float* xm = (const float*)d_in[1];
    const int* um_src = (const int*)d_in[2];
    const int* um_dst = (const int*)d_in[3];
    const int* mu_src = (const int*)d_in[4];
    const int* mu_dst = (const int*)d_in[5];
    const int* lab_u = (const int*)d_in[6];
    const int* lab_m = (const int*)d_in[7];
    const float* w1um_s = (const float*)d_in[8];
    const float* w1um_d = (const float*)d_in[9];
    const float* a1um_s = (const float*)d_in[10];
    const float* a1um_d = (const float*)d_in[11];
    const float* b1um = (const float*)d_in[12];
    const float* w1mu_s = (const float*)d_in[13];
    const float* w1mu_d = (const float*)d_in[14];
    const float* a1mu_s = (const float*)d_in[15];
    const float* a1mu_d = (const float*)d_in[16];
    const float* b1mu = (const float*)d_in[17];
    const float* w2um_s = (const float*)d_in[18];
    const float* w2um_d = (const float*)d_in[19];
    const float* a2um_s = (const float*)d_in[20];
    const float* a2um_d = (const float*)d_in[21];
    const float* b2um = (const float*)d_in[22];
    const float* w2mu_s = (const float*)d_in[23];
    const float* w2mu_d = (const float*)d_in[24];
    const float* a2mu_s = (const float*)d_in[25];
    const float* a2mu_d = (const float*)d_in[26];
    const float* b2mu = (const float*)d_in[27];
    const float* dw1 = (const float*)d_in[28];
    const float* db1 = (const float*)d_in[29];
    const float* dw2 = (const float*)d_in[30];
    const float* db2 = (const float*)d_in[31];
    float* out = (float*)d_out;

    // -------- workspace carving --------
    char* base = (char*)d_ws;
    size_t off = 0;
    auto alloc = [&](size_t bytes) -> void* {
        void* p = base + off;
        off = (off + bytes + 63) & ~(size_t)63;
        return p;
    };
    ushort* xu_bf   = (ushort*)alloc((size_t)NU_ * 32 * 2);
    ushort* xm_bf   = (ushort*)alloc((size_t)NM_ * 128 * 2);
    ushort* hproj_m = (ushort*)alloc((size_t)NM_ * 128 * 2);
    ushort* aggx    = (ushort*)alloc((size_t)NM_ * 256 * 2);
    ushort* zu_bf   = (ushort*)alloc((size_t)NU_ * 128 * 2);
    ushort* zm_bf   = (ushort*)alloc((size_t)NM_ * 128 * 2);
    ushort* qq_u    = (ushort*)alloc((size_t)NU_ * 64 * 2);
    ushort* qq_m    = (ushort*)alloc((size_t)NM_ * 64 * 2);
    ushort* Bt1u    = (ushort*)alloc((size_t)16 * 32 * 2);
    ushort* Bt1m    = (ushort*)alloc((size_t)144 * 128 * 2);
    ushort* Btp     = (ushort*)alloc((size_t)128 * 256 * 2);
    ushort* Bt2u    = (ushort*)alloc((size_t)80 * 128 * 2);
    ushort* Bt2m    = (ushort*)alloc((size_t)80 * 128 * 2);
    float* hlog_u = (float*)alloc((size_t)NU_ * 16 * 4);
    float* hlog_m = (float*)alloc((size_t)NM_ * 16 * 4);
    float* qlog_u = (float*)alloc((size_t)NU_ * 8 * 4);
    float* qlog_m = (float*)alloc((size_t)NM_ * 8 * 4);
    float* pu16   = (float*)alloc((size_t)NU_ * 16 * 4);
    float* pm16   = (float*)alloc((size_t)NM_ * 16 * 4);
    float* cj     = (float*)alloc(16 * 4);
    float* zero16 = (float*)alloc(16 * 4);
    int* rp_um    = (int*)alloc((NM_ + 1) * 4);
    int* rp_mu    = (int*)alloc((NU_ + 1) * 4);
    int* ssrc_um  = (int*)alloc((size_t)NE_ * 4);
    int* ssrc_mu  = (int*)alloc((size_t)NE_ * 4);
    int* ofs      = (int*)alloc((size_t)(NM_ + NU_) * 4);
    int* partials = (int*)alloc(128 * 4);
    if (ws_size < off) {
        fprintf(stderr, "kernel_launch: ws too small (%zu < %zu)\n", ws_size, off);
        return;
    }

    const int TB = 256;
    const int nbM = cdiv_i(NM_, SCHUNK);
    const int nbU = cdiv_i(NU_, SCHUNK);

    // -------- CSR (both graphs) --------
    hipMemsetAsync(ofs, 0, (size_t)(NM_ + NU_) * sizeof(int), stream);
    hipMemsetAsync(cj, 0, 16 * sizeof(float), stream);
    count_both<<<cdiv_i(2 * NE_, TB), TB, 0, stream>>>(um_dst, mu_dst, ofs);
    scan_phaseA2<<<nbM + nbU, 256, 0, stream>>>(ofs, partials, nbM);
    scan_phaseB2<<<1, 64, 0, stream>>>(partials, nbM, nbU, rp_um, rp_mu);
    scan_phaseC2<<<nbM + nbU, 256, 0, stream>>>(ofs, partials, rp_um, rp_mu, nbM);
    fill_both<<<cdiv_i(2 * NE_, TB), TB, 0, stream>>>(
        um_dst, um_src, mu_dst, mu_src, ofs, ssrc_um, ssrc_mu);

    // -------- fused setup (builders first, conv last) --------
    {
        int ntot = 2 * N_BT2 + N_CJ + N_BT1U + N_BT1M + N_BTP + 16 + N_CONV;
        setup_all<<<cdiv_i(ntot, TB), TB, 0, stream>>>(
            xu, xu_bf, xm, xm_bf,
            w1um_s, a1um_s, w1mu_d, a1mu_d, Bt1u,
            w1mu_s, a1mu_s, w1um_d, a1um_d, Bt1m, Btp,
            w2um_s, a2um_s, w2mu_d, a2mu_d, Bt2u,
            w2mu_s, a2mu_s, w2um_d, a2um_d, Bt2m,
            b2mu, b2um, dw1, db1, cj, zero16);
    }

    // -------- layer-1 GEMMs (merged) --------
    {
        int gNU = cdiv_i(NU_, 64), gNM = cdiv_i(NM_, 64);
        gemm_l1<<<gNU + gNM, TB, 0, stream>>>(
            xu_bf, Bt1u, hlog_u, xm_bf, Bt1m, hproj_m, hlog_m, gNU);
    }

    // -------- layer-1 aggregations (merged) --------
    {
        int gA = cdiv_i(NM_, 4), gB = cdiv_i(NU_, 16);
        agg_l1<<<gA + gB, TB, 0, stream>>>(
            xu_bf, hlog_u, hlog_m, rp_um, ssrc_um, aggx,
            hproj_m, rp_mu, ssrc_mu, b1mu, zu_bf, gA);
    }
    gemm_proj<<<cdiv_i(NM_, 64), TB, 0, stream>>>(aggx, Btp, zm_bf, b1um);

    // -------- layer-2 GEMMs (merged) --------
    {
        int gNU = cdiv_i(NU_, 64), gNM = cdiv_i(NM_, 64);
        gemm_l2<<<gNU + gNM, TB, 0, stream>>>(
            zu_bf, Bt2u, qq_u, qlog_u, zm_bf, Bt2m, qq_m, qlog_m, gNU);
    }

    // -------- layer-2 aggregation (merged, 8 dst/wave) --------
    {
        int nwA = cdiv_i(NM_, 8), nwB = cdiv_i(NU_, 8);
        agg_l2_m<<<cdiv_i(nwA + nwB, 4), TB, 0, stream>>>(
            qq_u, qlog_u, qlog_m + 4, rp_um, ssrc_um, cj, pm16, NM_,
            qq_m, qlog_m, qlog_u + 4, rp_mu, ssrc_mu, zero16, pu16, NU_);
    }

    // -------- decoder --------
    decoder4<<<cdiv_i(EL_ * 4, TB), TB, 0, stream>>>(
        pu16, pm16, lab_u, lab_m, dw2, db2, out, EL_);
}

// Round 13
// 203.497 us; speedup vs baseline: 4.7797x; 1.0225x over previous
//
#include <hip/hip_runtime.h>
#include <hip/hip_bf16.h>
#include <cstdio>

#define NU_ 100000
#define NM_ 20000
#define NE_ 250000
#define EL_ 200000
#define SCHUNK 2048

static inline int cdiv_i(int a, int b) { return (a + b - 1) / b; }

typedef __attribute__((ext_vector_type(8))) short bf16x8;
typedef __attribute__((ext_vector_type(4))) float f32x4;

__device__ __forceinline__ float bf2f(ushort u) {
    unsigned x = ((unsigned)u) << 16;
    return __builtin_bit_cast(float, x);
}
__device__ __forceinline__ ushort f2bf(float f) {
    unsigned x = __builtin_bit_cast(unsigned, f);
    x += 0x7fff + ((x >> 16) & 1);   // RNE
    return (ushort)(x >> 16);
}

// ---------------- CSR build (both graphs fused) ----------------

__global__ void count_both(const int* __restrict__ um_dst, const int* __restrict__ mu_dst,
                           int* __restrict__ cnt, float* __restrict__ cj) {
    int i = blockIdx.x * blockDim.x + threadIdx.x;
    if (i < 16) cj[i] = 0.f;
    if (i < NE_) atomicAdd(&cnt[um_dst[i]], 1);
    else if (i < 2 * NE_) atomicAdd(&cnt[NM_ + mu_dst[i - NE_]], 1);
}

__global__ __launch_bounds__(256) void scan_phaseA2(const int* __restrict__ in,
                                                    int* __restrict__ partial, int nbM) {
    __shared__ int red[256];
    int b = blockIdx.x, tid = threadIdx.x;
    const int* src; int n; int* part; int bb;
    if (b < nbM) { src = in; n = NM_; part = partial; bb = b; }
    else { src = in + NM_; n = NU_; part = partial + nbM; bb = b - nbM; }
    int base = bb * SCHUNK + tid * 8;
    int s = 0;
#pragma unroll
    for (int j = 0; j < 8; ++j) { int i = base + j; if (i < n) s += src[i]; }
    red[tid] = s;
    __syncthreads();
    for (int off = 128; off; off >>= 1) {
        if (tid < off) red[tid] += red[tid + off];
        __syncthreads();
    }
    if (tid == 0) part[bb] = red[0];
}

// phase C with inlined partials-scan (phase B eliminated); also rewrites inout = running offsets
__global__ __launch_bounds__(256) void scan_phaseC2(int* __restrict__ inout,
                                                    const int* __restrict__ partial,
                                                    int* __restrict__ rp_um,
                                                    int* __restrict__ rp_mu,
                                                    int nbM, int nbU) {
    __shared__ int tsum[256];
    __shared__ int blockoff_s, total_s;
    int b = blockIdx.x, tid = threadIdx.x;
    int* src; int n; const int* part; int* outp; int bb, nb;
    if (b < nbM) { src = inout; n = NM_; part = partial; outp = rp_um; bb = b; nb = nbM; }
    else { src = inout + NM_; n = NU_; part = partial + nbM; outp = rp_mu; bb = b - nbM; nb = nbU; }
    if (tid < 64) {
        int lane = tid;
        int v = (lane < nb) ? part[lane] : 0;
        int orig = v;
#pragma unroll
        for (int off = 1; off < 64; off <<= 1) {
            int y = __shfl_up(v, off, 64);
            if (lane >= off) v += y;
        }
        if (lane == bb) blockoff_s = v - orig;
        if (lane == nb - 1) total_s = v;
    }
    __syncthreads();
    int base = bb * SCHUNK + tid * 8;
    int v[8];
    int s = 0;
#pragma unroll
    for (int j = 0; j < 8; ++j) { int i = base + j; v[j] = (i < n) ? src[i] : 0; s += v[j]; }
    tsum[tid] = s;
    __syncthreads();
    for (int off = 1; off < 256; off <<= 1) {
        int y = (tid >= off) ? tsum[tid - off] : 0;
        __syncthreads();
        tsum[tid] += y;
        __syncthreads();
    }
    int run = blockoff_s + tsum[tid] - s;
#pragma unroll
    for (int j = 0; j < 8; ++j) {
        int i = base + j;
        if (i < n) { outp[i] = run; src[i] = run; }
        run += v[j];
    }
    if (bb == nb - 1 && tid == 0) outp[n] = total_s;
}

// ---------------- fused setup: CSR fill + builders + conv ----------------

#define N_FILL (2 * NE_)
#define N_BT1U (16 * 32)
#define N_BT1M (144 * 128)
#define N_BTP  (128 * 256)
#define N_BT2  (80 * 128)
#define N_CJ   (32 * 16)
#define N_CONV ((NU_ * 32 + NM_ * 128) / 4)

__global__ __launch_bounds__(256) void setup_all(
    const int* __restrict__ um_dst, const int* __restrict__ um_src,
    const int* __restrict__ mu_dst, const int* __restrict__ mu_src,
    int* __restrict__ ofs, int* __restrict__ ssrc_um, int* __restrict__ ssrc_mu,
    const float* __restrict__ xu, ushort* __restrict__ xu_bf,
    const float* __restrict__ xm, ushort* __restrict__ xm_bf,
    const float* __restrict__ w1um_s, const float* __restrict__ a1um_s,
    const float* __restrict__ w1mu_d, const float* __restrict__ a1mu_d,
    ushort* __restrict__ Bt1u,
    const float* __restrict__ w1mu_s, const float* __restrict__ a1mu_s,
    const float* __restrict__ w1um_d, const float* __restrict__ a1um_d,
    ushort* __restrict__ Bt1m, ushort* __restrict__ Btp,
    const float* __restrict__ w2um_s, const float* __restrict__ a2um_s,
    const float* __restrict__ w2mu_d, const float* __restrict__ a2mu_d,
    ushort* __restrict__ Bt2u,
    const float* __restrict__ w2mu_s, const float* __restrict__ a2mu_s,
    const float* __restrict__ w2um_d, const float* __restrict__ a2um_d,
    ushort* __restrict__ Bt2m,
    const float* __restrict__ b2mu, const float* __restrict__ b2um,
    const float* __restrict__ dw1, const float* __restrict__ db1,
    float* __restrict__ cj, float* __restrict__ zero16) {
    int i = blockIdx.x * blockDim.x + threadIdx.x;
    // F: CSR fill (latency-bound atomics issue first, hide under builders)
    if (i < N_FILL) {
        if (i < NE_) {
            int p = atomicAdd(&ofs[um_dst[i]], 1);
            ssrc_um[p] = um_src[i];
        } else {
            int j = i - NE_;
            int p = atomicAdd(&ofs[NM_ + mu_dst[j]], 1);
            ssrc_mu[p] = mu_src[j];
        }
        return;
    }
    i -= N_FILL;
    // S0: Bt2u (k-major: c fastest for coalesced dw1/a2 reads)
    if (i < N_BT2) {
        int k = i / 80, c = i % 80;
        float v = 0.f;
        if (c < 64) {
            int h = c >> 4, j = c & 15;
            for (int cc = 0; cc < 128; ++cc)
                v += w2um_s[(size_t)k * 512 + h * 128 + cc] * dw1[(size_t)(512 + h * 128 + cc) * 16 + j];
        } else if (c < 68) {
            int h = c - 64;
            for (int cc = 0; cc < 128; ++cc)
                v += w2um_s[(size_t)k * 512 + h * 128 + cc] * a2um_s[h * 128 + cc];
        } else if (c < 72) {
            int h = c - 68;
            for (int cc = 0; cc < 128; ++cc)
                v += w2mu_d[(size_t)k * 512 + h * 128 + cc] * a2mu_d[h * 128 + cc];
        }
        Bt2u[(size_t)c * 128 + k] = f2bf(v);
        return;
    }
    i -= N_BT2;
    // S1: Bt2m
    if (i < N_BT2) {
        int k = i / 80, c = i % 80;
        float v = 0.f;
        if (c < 64) {
            int h = c >> 4, j = c & 15;
            for (int cc = 0; cc < 128; ++cc)
                v += w2mu_s[(size_t)k * 512 + h * 128 + cc] * dw1[(size_t)(h * 128 + cc) * 16 + j];
        } else if (c < 68) {
            int h = c - 64;
            for (int cc = 0; cc < 128; ++cc)
                v += w2mu_s[(size_t)k * 512 + h * 128 + cc] * a2mu_s[h * 128 + cc];
        } else if (c < 72) {
            int h = c - 68;
            for (int cc = 0; cc < 128; ++cc)
                v += w2um_d[(size_t)k * 512 + h * 128 + cc] * a2um_d[h * 128 + cc];
        }
        Bt2m[(size_t)c * 128 + k] = f2bf(v);
        return;
    }
    i -= N_BT2;
    // S2: cj partials (32 col-groups x 16 j), atomicAdd into cj (zeroed by count_both)
    if (i < N_CJ) {
        int g = i >> 4, j = i & 15;
        float s = 0.f;
        for (int cc = 0; cc < 16; ++cc) {
            int col = g * 16 + cc;
            s += b2mu[col] * dw1[col * 16 + j] + b2um[col] * dw1[(512 + col) * 16 + j];
        }
        if (g == 0) s += db1[j];
        atomicAdd(&cj[j], s);
        return;
    }
    i -= N_CJ;
    // S3: Bt1u
    if (i < N_BT1U) {
        int c = i >> 5, k = i & 31;
        float v = 0.f;
        if (c < 8) {
            for (int cc = 0; cc < 16; ++cc)
                v += w1um_s[(size_t)k * 128 + c * 16 + cc] * a1um_s[c * 16 + cc];
        } else {
            int h = c - 8;
            for (int cc = 0; cc < 16; ++cc)
                v += w1mu_d[(size_t)k * 128 + h * 16 + cc] * a1mu_d[h * 16 + cc];
        }
        Bt1u[c * 32 + k] = f2bf(v);
        return;
    }
    i -= N_BT1U;
    // S4: Bt1m
    if (i < N_BT1M) {
        int c = i >> 7, k = i & 127;
        float v;
        if (c < 128) {
            v = w1mu_s[(size_t)k * 128 + c];
        } else if (c < 136) {
            int h = c - 128; v = 0.f;
            for (int cc = 0; cc < 16; ++cc)
                v += w1mu_s[(size_t)k * 128 + h * 16 + cc] * a1mu_s[h * 16 + cc];
        } else {
            int h = c - 136; v = 0.f;
            for (int cc = 0; cc < 16; ++cc)
                v += w1um_d[(size_t)k * 128 + h * 16 + cc] * a1um_d[h * 16 + cc];
        }
        Bt1m[(size_t)c * 128 + k] = f2bf(v);
        return;
    }
    i -= N_BT1M;
    // S5: Btp (block-diag projection of w1um_s)
    if (i < N_BTP) {
        int c = i >> 8, kk = i & 255;
        int h = kk >> 5, k = kk & 31;
        float v = ((c >> 4) == h) ? w1um_s[(size_t)k * 128 + c] : 0.f;
        Btp[(size_t)c * 256 + kk] = f2bf(v);
        return;
    }
    i -= N_BTP;
    // S6: zero16
    if (i < 16) { zero16[i] = 0.f; return; }
    i -= 16;
    // S7: bf16 casts (bulk)
    if (i < N_CONV) {
        const float* s; ushort* d; int idx;
        int n4a = NU_ * 32 / 4;
        if (i < n4a) { s = xu; d = xu_bf; idx = i; }
        else { s = xm; d = xm_bf; idx = i - n4a; }
        float4 v = ((const float4*)s)[idx];
        ushort4 o;
        o.x = f2bf(v.x); o.y = f2bf(v.y); o.z = f2bf(v.z); o.w = f2bf(v.w);
        ((ushort4*)d)[idx] = o;
    }
}

// ---------------- MFMA GEMM body ----------------
template <int K, int NT>
__device__ __forceinline__ void mfma_body(
    int blk, const ushort* __restrict__ A, const ushort* __restrict__ Bt,
    ushort* __restrict__ outb, int sb, float* __restrict__ outf, int sf,
    int splitc, int maxc, int Nrows, const float* __restrict__ bias, int dorelu) {
    int wave = threadIdx.x >> 6;
    int lane = threadIdx.x & 63;
    int row0 = (blk * 4 + wave) * 16;
    if (row0 >= Nrows) return;
    int r = lane & 15;
    int kb = lane >> 4;
    bf16x8 afrag[K / 32];
    int arow = row0 + r;
    bool rowok = (arow < Nrows);
#pragma unroll
    for (int ks = 0; ks < K / 32; ++ks) {
        if (rowok)
            afrag[ks] = *(const bf16x8*)(A + (size_t)arow * K + ks * 32 + kb * 8);
        else
            afrag[ks] = (bf16x8){0, 0, 0, 0, 0, 0, 0, 0};
    }
#pragma unroll
    for (int nt = 0; nt < NT; ++nt) {
        f32x4 acc = {0.f, 0.f, 0.f, 0.f};
#pragma unroll
        for (int ks = 0; ks < K / 32; ++ks) {
            bf16x8 bfrag = *(const bf16x8*)(Bt + (size_t)(nt * 16 + r) * K + ks * 32 + kb * 8);
            acc = __builtin_amdgcn_mfma_f32_16x16x32_bf16(afrag[ks], bfrag, acc, 0, 0, 0);
        }
        int col = nt * 16 + r;
        float bv = (bias && col < splitc) ? bias[col] : 0.f;
#pragma unroll
        for (int reg = 0; reg < 4; ++reg) {
            int rr = row0 + kb * 4 + reg;
            if (rr < Nrows) {
                if (col < splitc) {
                    float v = acc[reg] + bv;
                    if (dorelu) v = fmaxf(v, 0.f);
                    outb[(size_t)rr * sb + col] = f2bf(v);
                } else if (col < maxc) {
                    outf[(size_t)rr * sf + (col - splitc)] = acc[reg];
                }
            }
        }
    }
}

__global__ __launch_bounds__(256) void gemm_l1(
    const ushort* __restrict__ xu_bf, const ushort* __restrict__ Bt1u,
    float* __restrict__ hlog_u,
    const ushort* __restrict__ xm_bf, const ushort* __restrict__ Bt1m,
    ushort* __restrict__ hproj_m, float* __restrict__ hlog_m, int gNU) {
    int b = blockIdx.x;
    if (b < gNU)
        mfma_body<32, 1>(b, xu_bf, Bt1u, nullptr, 0, hlog_u, 16, 0, 16, NU_, nullptr, 0);
    else
        mfma_body<128, 9>(b - gNU, xm_bf, Bt1m, hproj_m, 128, hlog_m, 16, 128, 144, NM_, nullptr, 0);
}

__global__ __launch_bounds__(256) void gemm_proj(
    const ushort* __restrict__ aggx, const ushort* __restrict__ Btp,
    ushort* __restrict__ zm_bf, const float* __restrict__ b1um) {
    mfma_body<256, 8>(blockIdx.x, aggx, Btp, zm_bf, 128, nullptr, 0, 128, 128, NM_, b1um, 1);
}

__global__ __launch_bounds__(256) void gemm_l2(
    const ushort* __restrict__ zu_bf, const ushort* __restrict__ Bt2u,
    ushort* __restrict__ qq_u, float* __restrict__ qlog_u,
    const ushort* __restrict__ zm_bf, const ushort* __restrict__ Bt2m,
    ushort* __restrict__ qq_m, float* __restrict__ qlog_m, int gNU) {
    int b = blockIdx.x;
    if (b < gNU)
        mfma_body<128, 5>(b, zu_bf, Bt2u, qq_u, 64, qlog_u, 8, 64, 72, NU_, nullptr, 0);
    else
        mfma_body<128, 5>(b - gNU, zm_bf, Bt2m, qq_m, 64, qlog_m, 8, 64, 72, NM_, nullptr, 0);
}

// ---------------- merged layer-1 aggregations (16B loads, edge-parallel) ----------------
__global__ __launch_bounds__(256) void agg_l1(
    const ushort* __restrict__ xu_bf, const float* __restrict__ hlog_u,
    const float* __restrict__ hlog_m, const int* __restrict__ rp_um,
    const int* __restrict__ ssrc_um, ushort* __restrict__ aggx,
    const ushort* __restrict__ hproj_m, const int* __restrict__ rp_mu,
    const int* __restrict__ ssrc_mu, const float* __restrict__ b1mu,
    ushort* __restrict__ zu_bf, int gA) {
    int b = blockIdx.x;
    int lane = threadIdx.x & 63;
    if (b < gA) {
        int wid = (b * 256 + (int)threadIdx.x) >> 6;
        if (wid >= NM_) return;
        int slot = lane >> 5;
        int l5 = lane & 31;
        int h = l5 >> 2, c8 = (l5 & 3) * 8;
        int r0 = rp_um[wid], r1 = rp_um[wid + 1];
        float edv = hlog_m[(size_t)wid * 16 + 8 + h];
        float ssum = 0.f;
        float acc[8] = {0.f, 0.f, 0.f, 0.f, 0.f, 0.f, 0.f, 0.f};
        for (int base = r0; base < r1; base += 64) {
            int cnt = min(64, r1 - base);
            int sv = (base + lane < r1) ? ssrc_um[base + lane] : 0;
            for (int j = 0; j < cnt; j += 2) {
                int jj = j + slot;
                int s = __shfl(sv, jj, 64);
                float x = hlog_u[(size_t)s * 16 + h] + edv;
                x = x > 0.f ? x : 0.2f * x;
                float w = (jj < cnt) ? __expf(x) : 0.f;
                ssum += w;
                bf16x8 xv = *(const bf16x8*)(xu_bf + (size_t)s * 32 + c8);
#pragma unroll
                for (int t = 0; t < 8; ++t)
                    acc[t] = fmaf(bf2f((ushort)xv[t]), w, acc[t]);
            }
        }
        ssum += __shfl_xor(ssum, 32, 64);
#pragma unroll
        for (int t = 0; t < 8; ++t) acc[t] += __shfl_xor(acc[t], 32, 64);
        float inv = 1.f / (ssum + 1e-16f);
        if (slot == 0) {
            bf16x8 o;
#pragma unroll
            for (int t = 0; t < 8; ++t) o[t] = (short)f2bf(acc[t] * inv);
            *(bf16x8*)(aggx + (size_t)wid * 256 + h * 32 + c8) = o;
        }
    } else {
        int wid = ((b - gA) * 256 + (int)threadIdx.x) >> 6;
        int g = lane >> 4, l = lane & 15;
        int dst = wid * 4 + g;
        if (dst >= NU_) return;
        int h = l >> 1, c8 = l * 8;
        int r0 = rp_mu[dst], r1 = rp_mu[dst + 1];
        float edv = hlog_u[(size_t)dst * 16 + 8 + h];
        float ssum = 0.f;
        float acc[8] = {0.f, 0.f, 0.f, 0.f, 0.f, 0.f, 0.f, 0.f};
        for (int base = r0; base < r1; base += 16) {
            int cnt = min(16, r1 - base);
            int sv = (base + l < r1) ? ssrc_mu[base + l] : 0;
            for (int j = 0; j < cnt; ++j) {
                int s = __shfl(sv, (g << 4) | j, 64);
                float x = hlog_m[(size_t)s * 16 + h] + edv;
                x = x > 0.f ? x : 0.2f * x;
                float w = __expf(x);
                ssum += w;
                bf16x8 hv = *(const bf16x8*)(hproj_m + (size_t)s * 128 + c8);
#pragma unroll
                for (int t = 0; t < 8; ++t)
                    acc[t] = fmaf(bf2f((ushort)hv[t]), w, acc[t]);
            }
        }
        float inv = 1.f / (ssum + 1e-16f);
        bf16x8 o;
#pragma unroll
        for (int t = 0; t < 8; ++t) {
            float v = fmaxf(fmaf(acc[t], inv, b1mu[c8 + t]), 0.f);
            o[t] = (short)f2bf(v);
        }
        *(bf16x8*)(zu_bf + (size_t)dst * 128 + c8) = o;
    }
}

// ---------------- layer-2 aggregation, both directions, 8 dsts/wave, 16B loads ----------------
__global__ __launch_bounds__(256) void agg_l2_m(
    const ushort* __restrict__ qA, const float* __restrict__ esA,
    const float* __restrict__ edA, const int* __restrict__ rpA,
    const int* __restrict__ srcA, const float* __restrict__ biasA,
    float* __restrict__ outA, int NdA,
    const ushort* __restrict__ qB, const float* __restrict__ esB,
    const float* __restrict__ edB, const int* __restrict__ rpB,
    const int* __restrict__ srcB, const float* __restrict__ biasB,
    float* __restrict__ outB, int NdB) {
    int wid = (blockIdx.x * 256 + threadIdx.x) >> 6;
    int lane = threadIdx.x & 63;
    int g = lane >> 3, l = lane & 7;
    int nwA = (NdA + 7) >> 3;
    const ushort* q; const float* es; const float* ed; const int* rp;
    const int* src; const float* bias16; float* o16; int dst, Nd;
    if (wid < nwA) {
        q = qA; es = esA; ed = edA; rp = rpA; src = srcA;
        bias16 = biasA; o16 = outA; Nd = NdA; dst = wid * 8 + g;
    } else {
        int w2 = wid - nwA;
        q = qB; es = esB; ed = edB; rp = rpB; src = srcB;
        bias16 = biasB; o16 = outB; Nd = NdB; dst = w2 * 8 + g;
    }
    if (dst >= Nd) return;
    int h = l >> 1, c8 = l * 8;
    int r0 = rp[dst], r1 = rp[dst + 1];
    float edv = ed[(size_t)dst * 8 + h];
    float ssum = 0.f;
    float acc[8] = {0.f, 0.f, 0.f, 0.f, 0.f, 0.f, 0.f, 0.f};
    for (int base = r0; base < r1; base += 8) {
        int cnt = min(8, r1 - base);
        int sv = (base + l < r1) ? src[base + l] : 0;
        for (int j = 0; j < cnt; ++j) {
            int s = __shfl(sv, (g << 3) | j, 64);
            float x = es[(size_t)s * 8 + h] + edv;
            x = x > 0.f ? x : 0.2f * x;
            float w = __expf(x);
            ssum += w;
            bf16x8 qv = *(const bf16x8*)(q + (size_t)s * 64 + c8);
#pragma unroll
            for (int t = 0; t < 8; ++t)
                acc[t] = fmaf(bf2f((ushort)qv[t]), w, acc[t]);
        }
    }
    float inv = 1.f / (ssum + 1e-16f);
#pragma unroll
    for (int t = 0; t < 8; ++t) {
        acc[t] *= inv;
        acc[t] += __shfl_xor(acc[t], 2, 64);
        acc[t] += __shfl_xor(acc[t], 4, 64);
    }
    if (l < 2) {
        int jb = 8 * l;
        float4 o0 = make_float4(acc[0] + bias16[jb + 0], acc[1] + bias16[jb + 1],
                                acc[2] + bias16[jb + 2], acc[3] + bias16[jb + 3]);
        float4 o1 = make_float4(acc[4] + bias16[jb + 4], acc[5] + bias16[jb + 5],
                                acc[6] + bias16[jb + 6], acc[7] + bias16[jb + 7]);
        *(float4*)(o16 + (size_t)dst * 16 + jb) = o0;
        *(float4*)(o16 + (size_t)dst * 16 + jb + 4) = o1;
    }
}

// ---------------- decoder: 4 lanes per label edge, float4 loads ----------------
__global__ __launch_bounds__(256) void decoder4(
    const float* __restrict__ pu16, const float* __restrict__ pm16,
    const int* __restrict__ lab_u, const int* __restrict__ lab_m,
    const float* __restrict__ dw2, const float* __restrict__ db2,
    float* __restrict__ out, int nE) {
    int t = blockIdx.x * 256 + threadIdx.x;
    int e = t >> 2, sub = t & 3;
    if (e >= nE) return;
    int u = lab_u[e], m = lab_m[e];
    float4 a = *(const float4*)(pu16 + (size_t)u * 16 + sub * 4);
    float4 b = *(const float4*)(pm16 + (size_t)m * 16 + sub * 4);
    const float* w = dw2 + sub * 4;
    float r = fmaxf(a.x + b.x, 0.f) * w[0] + fmaxf(a.y + b.y, 0.f) * w[1] +
              fmaxf(a.z + b.z, 0.f) * w[2] + fmaxf(a.w + b.w, 0.f) * w[3];
    r += __shfl_xor(r, 1, 64);
    r += __shfl_xor(r, 2, 64);
    if (sub == 0) out[e] = r + db2[0];
}

// ---------------- host ----------------

extern "C" void kernel_launch(void* const* d_in, const int* in_sizes, int n_in,
                              void* d_out, int out_size, void* d_ws, size_t ws_size,
                              hipStream_t stream) {
    const float* xu = (const float*)d_in[0];
    const float* xm = (const float*)d_in[1];
    const int* um_src = (const int*)d_in[2];
    const int* um_dst = (const int*)d_in[3];
    const int* mu_src = (const int*)d_in[4];
    const int* mu_dst = (const int*)d_in[5];
    const int* lab_u = (const int*)d_in[6];
    const int* lab_m = (const int*)d_in[7];
    const float* w1um_s = (const float*)d_in[8];
    const float* w1um_d = (const float*)d_in[9];
    const float* a1um_s = (const float*)d_in[10];
    const float* a1um_d = (const float*)d_in[11];
    const float* b1um = (const float*)d_in[12];
    const float* w1mu_s = (const float*)d_in[13];
    const float* w1mu_d = (const float*)d_in[14];
    const float* a1mu_s = (const float*)d_in[15];
    const float* a1mu_d = (const float*)d_in[16];
    const float* b1mu = (const float*)d_in[17];
    const float* w2um_s = (const float*)d_in[18];
    const float* w2um_d = (const float*)d_in[19];
    const float* a2um_s = (const float*)d_in[20];
    const float* a2um_d = (const float*)d_in[21];
    const float* b2um = (const float*)d_in[22];
    const float* w2mu_s = (const float*)d_in[23];
    const float* w2mu_d = (const float*)d_in[24];
    const float* a2mu_s = (const float*)d_in[25];
    const float* a2mu_d = (const float*)d_in[26];
    const float* b2mu = (const float*)d_in[27];
    const float* dw1 = (const float*)d_in[28];
    const float* db1 = (const float*)d_in[29];
    const float* dw2 = (const float*)d_in[30];
    const float* db2 = (const float*)d_in[31];
    float* out = (float*)d_out;

    // -------- workspace carving --------
    char* base = (char*)d_ws;
    size_t off = 0;
    auto alloc = [&](size_t bytes) -> void* {
        void* p = base + off;
        off = (off + bytes + 63) & ~(size_t)63;
        return p;
    };
    ushort* xu_bf   = (ushort*)alloc((size_t)NU_ * 32 * 2);
    ushort* xm_bf   = (ushort*)alloc((size_t)NM_ * 128 * 2);
    ushort* hproj_m = (ushort*)alloc((size_t)NM_ * 128 * 2);
    ushort* aggx    = (ushort*)alloc((size_t)NM_ * 256 * 2);
    ushort* zu_bf   = (ushort*)alloc((size_t)NU_ * 128 * 2);
    ushort* zm_bf   = (ushort*)alloc((size_t)NM_ * 128 * 2);
    ushort* qq_u    = (ushort*)alloc((size_t)NU_ * 64 * 2);
    ushort* qq_m    = (ushort*)alloc((size_t)NM_ * 64 * 2);
    ushort* Bt1u    = (ushort*)alloc((size_t)16 * 32 * 2);
    ushort* Bt1m    = (ushort*)alloc((size_t)144 * 128 * 2);
    ushort* Btp     = (ushort*)alloc((size_t)128 * 256 * 2);
    ushort* Bt2u    = (ushort*)alloc((size_t)80 * 128 * 2);
    ushort* Bt2m    = (ushort*)alloc((size_t)80 * 128 * 2);
    float* hlog_u = (float*)alloc((size_t)NU_ * 16 * 4);
    float* hlog_m = (float*)alloc((size_t)NM_ * 16 * 4);
    float* qlog_u = (float*)alloc((size_t)NU_ * 8 * 4);
    float* qlog_m = (float*)alloc((size_t)NM_ * 8 * 4);
    float* pu16   = (float*)alloc((size_t)NU_ * 16 * 4);
    float* pm16   = (float*)alloc((size_t)NM_ * 16 * 4);
    float* cj     = (float*)alloc(16 * 4);
    float* zero16 = (float*)alloc(16 * 4);
    int* rp_um    = (int*)alloc((NM_ + 1) * 4);
    int* rp_mu    = (int*)alloc((NU_ + 1) * 4);
    int* ssrc_um  = (int*)alloc((size_t)NE_ * 4);
    int* ssrc_mu  = (int*)alloc((size_t)NE_ * 4);
    int* ofs      = (int*)alloc((size_t)(NM_ + NU_) * 4);
    int* partials = (int*)alloc(128 * 4);
    if (ws_size < off) {
        fprintf(stderr, "kernel_launch: ws too small (%zu < %zu)\n", ws_size, off);
        return;
    }

    const int TB = 256;
    const int nbM = cdiv_i(NM_, SCHUNK);
    const int nbU = cdiv_i(NU_, SCHUNK);

    // -------- CSR (both graphs) --------
    hipMemsetAsync(ofs, 0, (size_t)(NM_ + NU_) * sizeof(int), stream);
    count_both<<<cdiv_i(2 * NE_, TB), TB, 0, stream>>>(um_dst, mu_dst, ofs, cj);
    scan_phaseA2<<<nbM + nbU, 256, 0, stream>>>(ofs, partials, nbM);
    scan_phaseC2<<<nbM + nbU, 256, 0, stream>>>(ofs, partials, rp_um, rp_mu, nbM, nbU);

    // -------- fused setup (CSR fill + builders + conv) --------
    {
        int ntot = N_FILL + 2 * N_BT2 + N_CJ + N_BT1U + N_BT1M + N_BTP + 16 + N_CONV;
        setup_all<<<cdiv_i(ntot, TB), TB, 0, stream>>>(
            um_dst, um_src, mu_dst, mu_src, ofs, ssrc_um, ssrc_mu,
            xu, xu_bf, xm, xm_bf,
            w1um_s, a1um_s, w1mu_d, a1mu_d, Bt1u,
            w1mu_s, a1mu_s, w1um_d, a1um_d, Bt1m, Btp,
            w2um_s, a2um_s, w2mu_d, a2mu_d, Bt2u,
            w2mu_s, a2mu_s, w2um_d, a2um_d, Bt2m,
            b2mu, b2um, dw1, db1, cj, zero16);
    }

    // -------- layer-1 GEMMs (merged) --------
    {
        int gNU = cdiv_i(NU_, 64), gNM = cdiv_i(NM_, 64);
        gemm_l1<<<gNU + gNM, TB, 0, stream>>>(
            xu_bf, Bt1u, hlog_u, xm_bf, Bt1m, hproj_m, hlog_m, gNU);
    }

    // -------- layer-1 aggregations (merged) --------
    {
        int gA = cdiv_i(NM_, 4), gB = cdiv_i(NU_, 16);
        agg_l1<<<gA + gB, TB, 0, stream>>>(
            xu_bf, hlog_u, hlog_m, rp_um, ssrc_um, aggx,
            hproj_m, rp_mu, ssrc_mu, b1mu, zu_bf, gA);
    }
    gemm_proj<<<cdiv_i(NM_, 64), TB, 0, stream>>>(aggx, Btp, zm_bf, b1um);

    // -------- layer-2 GEMMs (merged) --------
    {
        int gNU = cdiv_i(NU_, 64), gNM = cdiv_i(NM_, 64);
        gemm_l2<<<gNU + gNM, TB, 0, stream>>>(
            zu_bf, Bt2u, qq_u, qlog_u, zm_bf, Bt2m, qq_m, qlog_m, gNU);
    }

    // -------- layer-2 aggregation (merged, 8 dst/wave) --------
    {
        int nwA = cdiv_i(NM_, 8), nwB = cdiv_i(NU_, 8);
        agg_l2_m<<<cdiv_i(nwA + nwB, 4), TB, 0, stream>>>(
            qq_u, qlog_u, qlog_m + 4, rp_um, ssrc_um, cj, pm16, NM_,
            qq_m, qlog_m, qlog_u + 4, rp_mu, ssrc_mu, zero16, pu16, NU_);
    }

    // -------- decoder --------
    decoder4<<<cdiv_i(EL_ * 4, TB), TB, 0, stream>>>(
        pu16, pm16, lab_u, lab_m, dw2, db2, out, EL_);
}

// Round 14
// 185.897 us; speedup vs baseline: 5.2322x; 1.0947x over previous
//
#include <hip/hip_runtime.h>
#include <hip/hip_bf16.h>
#include <cstdio>

#define NU_ 100000
#define NM_ 20000
#define NE_ 250000
#define EL_ 200000
#define SCHUNK 2048

static inline int cdiv_i(int a, int b) { return (a + b - 1) / b; }

typedef __attribute__((ext_vector_type(8))) short bf16x8;
typedef __attribute__((ext_vector_type(4))) float f32x4;

__device__ __forceinline__ float bf2f(ushort u) {
    unsigned x = ((unsigned)u) << 16;
    return __builtin_bit_cast(float, x);
}
__device__ __forceinline__ ushort f2bf(float f) {
    unsigned x = __builtin_bit_cast(unsigned, f);
    x += 0x7fff + ((x >> 16) & 1);   // RNE
    return (ushort)(x >> 16);
}

// ---------------- CSR build: count + per-edge rank (single atomic pass) ----------------

__global__ void count_both(const int* __restrict__ um_dst, const int* __restrict__ mu_dst,
                           int* __restrict__ cnt, int* __restrict__ rank_um,
                           int* __restrict__ rank_mu, float* __restrict__ cj) {
    int i = blockIdx.x * blockDim.x + threadIdx.x;
    if (i < 16) cj[i] = 0.f;
    if (i < NE_) {
        rank_um[i] = atomicAdd(&cnt[um_dst[i]], 1);
    } else if (i < 2 * NE_) {
        int j = i - NE_;
        rank_mu[j] = atomicAdd(&cnt[NM_ + mu_dst[j]], 1);
    }
}

__global__ __launch_bounds__(256) void scan_phaseA2(const int* __restrict__ in,
                                                    int* __restrict__ partial, int nbM) {
    __shared__ int red[256];
    int b = blockIdx.x, tid = threadIdx.x;
    const int* src; int n; int* part; int bb;
    if (b < nbM) { src = in; n = NM_; part = partial; bb = b; }
    else { src = in + NM_; n = NU_; part = partial + nbM; bb = b - nbM; }
    int base = bb * SCHUNK + tid * 8;
    int s = 0;
#pragma unroll
    for (int j = 0; j < 8; ++j) { int i = base + j; if (i < n) s += src[i]; }
    red[tid] = s;
    __syncthreads();
    for (int off = 128; off; off >>= 1) {
        if (tid < off) red[tid] += red[tid + off];
        __syncthreads();
    }
    if (tid == 0) part[bb] = red[0];
}

// phase C with inlined partials-scan (phase B eliminated); writes rp only
__global__ __launch_bounds__(256) void scan_phaseC2(const int* __restrict__ in,
                                                    const int* __restrict__ partial,
                                                    int* __restrict__ rp_um,
                                                    int* __restrict__ rp_mu,
                                                    int nbM, int nbU) {
    __shared__ int tsum[256];
    __shared__ int blockoff_s, total_s;
    int b = blockIdx.x, tid = threadIdx.x;
    const int* src; int n; const int* part; int* outp; int bb, nb;
    if (b < nbM) { src = in; n = NM_; part = partial; outp = rp_um; bb = b; nb = nbM; }
    else { src = in + NM_; n = NU_; part = partial + nbM; outp = rp_mu; bb = b - nbM; nb = nbU; }
    if (tid < 64) {
        int lane = tid;
        int v = (lane < nb) ? part[lane] : 0;
        int orig = v;
#pragma unroll
        for (int off = 1; off < 64; off <<= 1) {
            int y = __shfl_up(v, off, 64);
            if (lane >= off) v += y;
        }
        if (lane == bb) blockoff_s = v - orig;
        if (lane == nb - 1) total_s = v;
    }
    __syncthreads();
    int base = bb * SCHUNK + tid * 8;
    int v[8];
    int s = 0;
#pragma unroll
    for (int j = 0; j < 8; ++j) { int i = base + j; v[j] = (i < n) ? src[i] : 0; s += v[j]; }
    tsum[tid] = s;
    __syncthreads();
    for (int off = 1; off < 256; off <<= 1) {
        int y = (tid >= off) ? tsum[tid - off] : 0;
        __syncthreads();
        tsum[tid] += y;
        __syncthreads();
    }
    int run = blockoff_s + tsum[tid] - s;
#pragma unroll
    for (int j = 0; j < 8; ++j) {
        int i = base + j;
        if (i < n) outp[i] = run;
        run += v[j];
    }
    if (bb == nb - 1 && tid == 0) outp[n] = total_s;
}

// ---------------- fused setup: atomic-free CSR fill + builders + conv ----------------

#define N_FILL (2 * NE_)
#define N_BT1U (16 * 32)
#define N_BT1M (144 * 128)
#define N_BTP  (128 * 256)
#define N_BT2  (80 * 128)
#define N_CJ   (32 * 16)
#define N_CONV ((NU_ * 32 + NM_ * 128) / 4)

__global__ __launch_bounds__(256) void setup_all(
    const int* __restrict__ um_dst, const int* __restrict__ um_src,
    const int* __restrict__ mu_dst, const int* __restrict__ mu_src,
    const int* __restrict__ rp_um, const int* __restrict__ rp_mu,
    const int* __restrict__ rank_um, const int* __restrict__ rank_mu,
    int* __restrict__ ssrc_um, int* __restrict__ ssrc_mu,
    const float* __restrict__ xu, ushort* __restrict__ xu_bf,
    const float* __restrict__ xm, ushort* __restrict__ xm_bf,
    const float* __restrict__ w1um_s, const float* __restrict__ a1um_s,
    const float* __restrict__ w1mu_d, const float* __restrict__ a1mu_d,
    ushort* __restrict__ Bt1u,
    const float* __restrict__ w1mu_s, const float* __restrict__ a1mu_s,
    const float* __restrict__ w1um_d, const float* __restrict__ a1um_d,
    ushort* __restrict__ Bt1m, ushort* __restrict__ Btp,
    const float* __restrict__ w2um_s, const float* __restrict__ a2um_s,
    const float* __restrict__ w2mu_d, const float* __restrict__ a2mu_d,
    ushort* __restrict__ Bt2u,
    const float* __restrict__ w2mu_s, const float* __restrict__ a2mu_s,
    const float* __restrict__ w2um_d, const float* __restrict__ a2um_d,
    ushort* __restrict__ Bt2m,
    const float* __restrict__ b2mu, const float* __restrict__ b2um,
    const float* __restrict__ dw1, const float* __restrict__ db1,
    float* __restrict__ cj, float* __restrict__ zero16) {
    int i = blockIdx.x * blockDim.x + threadIdx.x;
    // F: CSR fill — pure scatter, no atomics (rank precomputed by count_both)
    if (i < N_FILL) {
        if (i < NE_) {
            int p = rp_um[um_dst[i]] + rank_um[i];
            ssrc_um[p] = um_src[i];
        } else {
            int j = i - NE_;
            int p = rp_mu[mu_dst[j]] + rank_mu[j];
            ssrc_mu[p] = mu_src[j];
        }
        return;
    }
    i -= N_FILL;
    // S0: Bt2u (k-major: c fastest for coalesced dw1/a2 reads)
    if (i < N_BT2) {
        int k = i / 80, c = i % 80;
        float v = 0.f;
        if (c < 64) {
            int h = c >> 4, j = c & 15;
            for (int cc = 0; cc < 128; ++cc)
                v += w2um_s[(size_t)k * 512 + h * 128 + cc] * dw1[(size_t)(512 + h * 128 + cc) * 16 + j];
        } else if (c < 68) {
            int h = c - 64;
            for (int cc = 0; cc < 128; ++cc)
                v += w2um_s[(size_t)k * 512 + h * 128 + cc] * a2um_s[h * 128 + cc];
        } else if (c < 72) {
            int h = c - 68;
            for (int cc = 0; cc < 128; ++cc)
                v += w2mu_d[(size_t)k * 512 + h * 128 + cc] * a2mu_d[h * 128 + cc];
        }
        Bt2u[(size_t)c * 128 + k] = f2bf(v);
        return;
    }
    i -= N_BT2;
    // S1: Bt2m
    if (i < N_BT2) {
        int k = i / 80, c = i % 80;
        float v = 0.f;
        if (c < 64) {
            int h = c >> 4, j = c & 15;
            for (int cc = 0; cc < 128; ++cc)
                v += w2mu_s[(size_t)k * 512 + h * 128 + cc] * dw1[(size_t)(h * 128 + cc) * 16 + j];
        } else if (c < 68) {
            int h = c - 64;
            for (int cc = 0; cc < 128; ++cc)
                v += w2mu_s[(size_t)k * 512 + h * 128 + cc] * a2mu_s[h * 128 + cc];
        } else if (c < 72) {
            int h = c - 68;
            for (int cc = 0; cc < 128; ++cc)
                v += w2um_d[(size_t)k * 512 + h * 128 + cc] * a2um_d[h * 128 + cc];
        }
        Bt2m[(size_t)c * 128 + k] = f2bf(v);
        return;
    }
    i -= N_BT2;
    // S2: cj partials (32 col-groups x 16 j), atomicAdd into cj (zeroed by count_both)
    if (i < N_CJ) {
        int g = i >> 4, j = i & 15;
        float s = 0.f;
        for (int cc = 0; cc < 16; ++cc) {
            int col = g * 16 + cc;
            s += b2mu[col] * dw1[col * 16 + j] + b2um[col] * dw1[(512 + col) * 16 + j];
        }
        if (g == 0) s += db1[j];
        atomicAdd(&cj[j], s);
        return;
    }
    i -= N_CJ;
    // S3: Bt1u
    if (i < N_BT1U) {
        int c = i >> 5, k = i & 31;
        float v = 0.f;
        if (c < 8) {
            for (int cc = 0; cc < 16; ++cc)
                v += w1um_s[(size_t)k * 128 + c * 16 + cc] * a1um_s[c * 16 + cc];
        } else {
            int h = c - 8;
            for (int cc = 0; cc < 16; ++cc)
                v += w1mu_d[(size_t)k * 128 + h * 16 + cc] * a1mu_d[h * 16 + cc];
        }
        Bt1u[c * 32 + k] = f2bf(v);
        return;
    }
    i -= N_BT1U;
    // S4: Bt1m
    if (i < N_BT1M) {
        int c = i >> 7, k = i & 127;
        float v;
        if (c < 128) {
            v = w1mu_s[(size_t)k * 128 + c];
        } else if (c < 136) {
            int h = c - 128; v = 0.f;
            for (int cc = 0; cc < 16; ++cc)
                v += w1mu_s[(size_t)k * 128 + h * 16 + cc] * a1mu_s[h * 16 + cc];
        } else {
            int h = c - 136; v = 0.f;
            for (int cc = 0; cc < 16; ++cc)
                v += w1um_d[(size_t)k * 128 + h * 16 + cc] * a1um_d[h * 16 + cc];
        }
        Bt1m[(size_t)c * 128 + k] = f2bf(v);
        return;
    }
    i -= N_BT1M;
    // S5: Btp (block-diag projection of w1um_s)
    if (i < N_BTP) {
        int c = i >> 8, kk = i & 255;
        int h = kk >> 5, k = kk & 31;
        float v = ((c >> 4) == h) ? w1um_s[(size_t)k * 128 + c] : 0.f;
        Btp[(size_t)c * 256 + kk] = f2bf(v);
        return;
    }
    i -= N_BTP;
    // S6: zero16
    if (i < 16) { zero16[i] = 0.f; return; }
    i -= 16;
    // S7: bf16 casts (bulk)
    if (i < N_CONV) {
        const float* s; ushort* d; int idx;
        int n4a = NU_ * 32 / 4;
        if (i < n4a) { s = xu; d = xu_bf; idx = i; }
        else { s = xm; d = xm_bf; idx = i - n4a; }
        float4 v = ((const float4*)s)[idx];
        ushort4 o;
        o.x = f2bf(v.x); o.y = f2bf(v.y); o.z = f2bf(v.z); o.w = f2bf(v.w);
        ((ushort4*)d)[idx] = o;
    }
}

// ---------------- MFMA GEMM body ----------------
template <int K, int NT>
__device__ __forceinline__ void mfma_body(
    int blk, const ushort* __restrict__ A, const ushort* __restrict__ Bt,
    ushort* __restrict__ outb, int sb, float* __restrict__ outf, int sf,
    int splitc, int maxc, int Nrows, const float* __restrict__ bias, int dorelu) {
    int wave = threadIdx.x >> 6;
    int lane = threadIdx.x & 63;
    int row0 = (blk * 4 + wave) * 16;
    if (row0 >= Nrows) return;
    int r = lane & 15;
    int kb = lane >> 4;
    bf16x8 afrag[K / 32];
    int arow = row0 + r;
    bool rowok = (arow < Nrows);
#pragma unroll
    for (int ks = 0; ks < K / 32; ++ks) {
        if (rowok)
            afrag[ks] = *(const bf16x8*)(A + (size_t)arow * K + ks * 32 + kb * 8);
        else
            afrag[ks] = (bf16x8){0, 0, 0, 0, 0, 0, 0, 0};
    }
#pragma unroll
    for (int nt = 0; nt < NT; ++nt) {
        f32x4 acc = {0.f, 0.f, 0.f, 0.f};
#pragma unroll
        for (int ks = 0; ks < K / 32; ++ks) {
            bf16x8 bfrag = *(const bf16x8*)(Bt + (size_t)(nt * 16 + r) * K + ks * 32 + kb * 8);
            acc = __builtin_amdgcn_mfma_f32_16x16x32_bf16(afrag[ks], bfrag, acc, 0, 0, 0);
        }
        int col = nt * 16 + r;
        float bv = (bias && col < splitc) ? bias[col] : 0.f;
#pragma unroll
        for (int reg = 0; reg < 4; ++reg) {
            int rr = row0 + kb * 4 + reg;
            if (rr < Nrows) {
                if (col < splitc) {
                    float v = acc[reg] + bv;
                    if (dorelu) v = fmaxf(v, 0.f);
                    outb[(size_t)rr * sb + col] = f2bf(v);
                } else if (col < maxc) {
                    outf[(size_t)rr * sf + (col - splitc)] = acc[reg];
                }
            }
        }
    }
}

__global__ __launch_bounds__(256) void gemm_l1(
    const ushort* __restrict__ xu_bf, const ushort* __restrict__ Bt1u,
    float* __restrict__ hlog_u,
    const ushort* __restrict__ xm_bf, const ushort* __restrict__ Bt1m,
    ushort* __restrict__ hproj_m, float* __restrict__ hlog_m, int gNU) {
    int b = blockIdx.x;
    if (b < gNU)
        mfma_body<32, 1>(b, xu_bf, Bt1u, nullptr, 0, hlog_u, 16, 0, 16, NU_, nullptr, 0);
    else
        mfma_body<128, 9>(b - gNU, xm_bf, Bt1m, hproj_m, 128, hlog_m, 16, 128, 144, NM_, nullptr, 0);
}

__global__ __launch_bounds__(256) void gemm_proj(
    const ushort* __restrict__ aggx, const ushort* __restrict__ Btp,
    ushort* __restrict__ zm_bf, const float* __restrict__ b1um) {
    mfma_body<256, 8>(blockIdx.x, aggx, Btp, zm_bf, 128, nullptr, 0, 128, 128, NM_, b1um, 1);
}

__global__ __launch_bounds__(256) void gemm_l2(
    const ushort* __restrict__ zu_bf, const ushort* __restrict__ Bt2u,
    ushort* __restrict__ qq_u, float* __restrict__ qlog_u,
    const ushort* __restrict__ zm_bf, const ushort* __restrict__ Bt2m,
    ushort* __restrict__ qq_m, float* __restrict__ qlog_m, int gNU) {
    int b = blockIdx.x;
    if (b < gNU)
        mfma_body<128, 5>(b, zu_bf, Bt2u, qq_u, 64, qlog_u, 8, 64, 72, NU_, nullptr, 0);
    else
        mfma_body<128, 5>(b - gNU, zm_bf, Bt2m, qq_m, 64, qlog_m, 8, 64, 72, NM_, nullptr, 0);
}

// ---------------- merged layer-1 aggregations (16B loads, edge-parallel) ----------------
__global__ __launch_bounds__(256) void agg_l1(
    const ushort* __restrict__ xu_bf, const float* __restrict__ hlog_u,
    const float* __restrict__ hlog_m, const int* __restrict__ rp_um,
    const int* __restrict__ ssrc_um, ushort* __restrict__ aggx,
    const ushort* __restrict__ hproj_m, const int* __restrict__ rp_mu,
    const int* __restrict__ ssrc_mu, const float* __restrict__ b1mu,
    ushort* __restrict__ zu_bf, int gA) {
    int b = blockIdx.x;
    int lane = threadIdx.x & 63;
    if (b < gA) {
        int wid = (b * 256 + (int)threadIdx.x) >> 6;
        if (wid >= NM_) return;
        int slot = lane >> 5;
        int l5 = lane & 31;
        int h = l5 >> 2, c8 = (l5 & 3) * 8;
        int r0 = rp_um[wid], r1 = rp_um[wid + 1];
        float edv = hlog_m[(size_t)wid * 16 + 8 + h];
        float ssum = 0.f;
        float acc[8] = {0.f, 0.f, 0.f, 0.f, 0.f, 0.f, 0.f, 0.f};
        for (int base = r0; base < r1; base += 64) {
            int cnt = min(64, r1 - base);
            int sv = (base + lane < r1) ? ssrc_um[base + lane] : 0;
            for (int j = 0; j < cnt; j += 2) {
                int jj = j + slot;
                int s = __shfl(sv, jj, 64);
                float x = hlog_u[(size_t)s * 16 + h] + edv;
                x = x > 0.f ? x : 0.2f * x;
                float w = (jj < cnt) ? __expf(x) : 0.f;
                ssum += w;
                bf16x8 xv = *(const bf16x8*)(xu_bf + (size_t)s * 32 + c8);
#pragma unroll
                for (int t = 0; t < 8; ++t)
                    acc[t] = fmaf(bf2f((ushort)xv[t]), w, acc[t]);
            }
        }
        ssum += __shfl_xor(ssum, 32, 64);
#pragma unroll
        for (int t = 0; t < 8; ++t) acc[t] += __shfl_xor(acc[t], 32, 64);
        float inv = 1.f / (ssum + 1e-16f);
        if (slot == 0) {
            bf16x8 o;
#pragma unroll
            for (int t = 0; t < 8; ++t) o[t] = (short)f2bf(acc[t] * inv);
            *(bf16x8*)(aggx + (size_t)wid * 256 + h * 32 + c8) = o;
        }
    } else {
        int wid = ((b - gA) * 256 + (int)threadIdx.x) >> 6;
        int g = lane >> 4, l = lane & 15;
        int dst = wid * 4 + g;
        if (dst >= NU_) return;
        int h = l >> 1, c8 = l * 8;
        int r0 = rp_mu[dst], r1 = rp_mu[dst + 1];
        float edv = hlog_u[(size_t)dst * 16 + 8 + h];
        float ssum = 0.f;
        float acc[8] = {0.f, 0.f, 0.f, 0.f, 0.f, 0.f, 0.f, 0.f};
        for (int base = r0; base < r1; base += 16) {
            int cnt = min(16, r1 - base);
            int sv = (base + l < r1) ? ssrc_mu[base + l] : 0;
            for (int j = 0; j < cnt; ++j) {
                int s = __shfl(sv, (g << 4) | j, 64);
                float x = hlog_m[(size_t)s * 16 + h] + edv;
                x = x > 0.f ? x : 0.2f * x;
                float w = __expf(x);
                ssum += w;
                bf16x8 hv = *(const bf16x8*)(hproj_m + (size_t)s * 128 + c8);
#pragma unroll
                for (int t = 0; t < 8; ++t)
                    acc[t] = fmaf(bf2f((ushort)hv[t]), w, acc[t]);
            }
        }
        float inv = 1.f / (ssum + 1e-16f);
        bf16x8 o;
#pragma unroll
        for (int t = 0; t < 8; ++t) {
            float v = fmaxf(fmaf(acc[t], inv, b1mu[c8 + t]), 0.f);
            o[t] = (short)f2bf(v);
        }
        *(bf16x8*)(zu_bf + (size_t)dst * 128 + c8) = o;
    }
}

// ---------------- layer-2 aggregation, both directions, 8 dsts/wave, 16B loads ----------------
__global__ __launch_bounds__(256) void agg_l2_m(
    const ushort* __restrict__ qA, const float* __restrict__ esA,
    const float* __restrict__ edA, const int* __restrict__ rpA,
    const int* __restrict__ srcA, const float* __restrict__ biasA,
    float* __restrict__ outA, int NdA,
    const ushort* __restrict__ qB, const float* __restrict__ esB,
    const float* __restrict__ edB, const int* __restrict__ rpB,
    const int* __restrict__ srcB, const float* __restrict__ biasB,
    float* __restrict__ outB, int NdB) {
    int wid = (blockIdx.x * 256 + threadIdx.x) >> 6;
    int lane = threadIdx.x & 63;
    int g = lane >> 3, l = lane & 7;
    int nwA = (NdA + 7) >> 3;
    const ushort* q; const float* es; const float* ed; const int* rp;
    const int* src; const float* bias16; float* o16; int dst, Nd;
    if (wid < nwA) {
        q = qA; es = esA; ed = edA; rp = rpA; src = srcA;
        bias16 = biasA; o16 = outA; Nd = NdA; dst = wid * 8 + g;
    } else {
        int w2 = wid - nwA;
        q = qB; es = esB; ed = edB; rp = rpB; src = srcB;
        bias16 = biasB; o16 = outB; Nd = NdB; dst = w2 * 8 + g;
    }
    if (dst >= Nd) return;
    int h = l >> 1, c8 = l * 8;
    int r0 = rp[dst], r1 = rp[dst + 1];
    float edv = ed[(size_t)dst * 8 + h];
    float ssum = 0.f;
    float acc[8] = {0.f, 0.f, 0.f, 0.f, 0.f, 0.f, 0.f, 0.f};
    for (int base = r0; base < r1; base += 8) {
        int cnt = min(8, r1 - base);
        int sv = (base + l < r1) ? src[base + l] : 0;
        for (int j = 0; j < cnt; ++j) {
            int s = __shfl(sv, (g << 3) | j, 64);
            float x = es[(size_t)s * 8 + h] + edv;
            x = x > 0.f ? x : 0.2f * x;
            float w = __expf(x);
            ssum += w;
            bf16x8 qv = *(const bf16x8*)(q + (size_t)s * 64 + c8);
#pragma unroll
            for (int t = 0; t < 8; ++t)
                acc[t] = fmaf(bf2f((ushort)qv[t]), w, acc[t]);
        }
    }
    float inv = 1.f / (ssum + 1e-16f);
#pragma unroll
    for (int t = 0; t < 8; ++t) {
        acc[t] *= inv;
        acc[t] += __shfl_xor(acc[t], 2, 64);
        acc[t] += __shfl_xor(acc[t], 4, 64);
    }
    if (l < 2) {
        int jb = 8 * l;
        float4 o0 = make_float4(acc[0] + bias16[jb + 0], acc[1] + bias16[jb + 1],
                                acc[2] + bias16[jb + 2], acc[3] + bias16[jb + 3]);
        float4 o1 = make_float4(acc[4] + bias16[jb + 4], acc[5] + bias16[jb + 5],
                                acc[6] + bias16[jb + 6], acc[7] + bias16[jb + 7]);
        *(float4*)(o16 + (size_t)dst * 16 + jb) = o0;
        *(float4*)(o16 + (size_t)dst * 16 + jb + 4) = o1;
    }
}

// ---------------- decoder: 4 lanes per label edge, float4 loads ----------------
__global__ __launch_bounds__(256) void decoder4(
    const float* __restrict__ pu16, const float* __restrict__ pm16,
    const int* __restrict__ lab_u, const int* __restrict__ lab_m,
    const float* __restrict__ dw2, const float* __restrict__ db2,
    float* __restrict__ out, int nE) {
    int t = blockIdx.x * 256 + threadIdx.x;
    int e = t >> 2, sub = t & 3;
    if (e >= nE) return;
    int u = lab_u[e], m = lab_m[e];
    float4 a = *(const float4*)(pu16 + (size_t)u * 16 + sub * 4);
    float4 b = *(const float4*)(pm16 + (size_t)m * 16 + sub * 4);
    const float* w = dw2 + sub * 4;
    float r = fmaxf(a.x + b.x, 0.f) * w[0] + fmaxf(a.y + b.y, 0.f) * w[1] +
              fmaxf(a.z + b.z, 0.f) * w[2] + fmaxf(a.w + b.w, 0.f) * w[3];
    r += __shfl_xor(r, 1, 64);
    r += __shfl_xor(r, 2, 64);
    if (sub == 0) out[e] = r + db2[0];
}

// ---------------- host ----------------

extern "C" void kernel_launch(void* const* d_in, const int* in_sizes, int n_in,
                              void* d_out, int out_size, void* d_ws, size_t ws_size,
                              hipStream_t stream) {
    const float* xu = (const float*)d_in[0];
    const float* xm = (const float*)d_in[1];
    const int* um_src = (const int*)d_in[2];
    const int* um_dst = (const int*)d_in[3];
    const int* mu_src = (const int*)d_in[4];
    const int* mu_dst = (const int*)d_in[5];
    const int* lab_u = (const int*)d_in[6];
    const int* lab_m = (const int*)d_in[7];
    const float* w1um_s = (const float*)d_in[8];
    const float* w1um_d = (const float*)d_in[9];
    const float* a1um_s = (const float*)d_in[10];
    const float* a1um_d = (const float*)d_in[11];
    const float* b1um = (const float*)d_in[12];
    const float* w1mu_s = (const float*)d_in[13];
    const float* w1mu_d = (const float*)d_in[14];
    const float* a1mu_s = (const float*)d_in[15];
    const float* a1mu_d = (const float*)d_in[16];
    const float* b1mu = (const float*)d_in[17];
    const float* w2um_s = (const float*)d_in[18];
    const float* w2um_d = (const float*)d_in[19];
    const float* a2um_s = (const float*)d_in[20];
    const float* a2um_d = (const float*)d_in[21];
    const float* b2um = (const float*)d_in[22];
    const float* w2mu_s = (const float*)d_in[23];
    const float* w2mu_d = (const float*)d_in[24];
    const float* a2mu_s = (const float*)d_in[25];
    const float* a2mu_d = (const float*)d_in[26];
    const float* b2mu = (const float*)d_in[27];
    const float* dw1 = (const float*)d_in[28];
    const float* db1 = (const float*)d_in[29];
    const float* dw2 = (const float*)d_in[30];
    const float* db2 = (const float*)d_in[31];
    float* out = (float*)d_out;

    // -------- workspace carving --------
    char* base = (char*)d_ws;
    size_t off = 0;
    auto alloc = [&](size_t bytes) -> void* {
        void* p = base + off;
        off = (off + bytes + 63) & ~(size_t)63;
        return p;
    };
    ushort* xu_bf   = (ushort*)alloc((size_t)NU_ * 32 * 2);
    ushort* xm_bf   = (ushort*)alloc((size_t)NM_ * 128 * 2);
    ushort* hproj_m = (ushort*)alloc((size_t)NM_ * 128 * 2);
    ushort* aggx    = (ushort*)alloc((size_t)NM_ * 256 * 2);
    ushort* zu_bf   = (ushort*)alloc((size_t)NU_ * 128 * 2);
    ushort* zm_bf   = (ushort*)alloc((size_t)NM_ * 128 * 2);
    ushort* qq_u    = (ushort*)alloc((size_t)NU_ * 64 * 2);
    ushort* qq_m    = (ushort*)alloc((size_t)NM_ * 64 * 2);
    ushort* Bt1u    = (ushort*)alloc((size_t)16 * 32 * 2);
    ushort* Bt1m    = (ushort*)alloc((size_t)144 * 128 * 2);
    ushort* Btp     = (ushort*)alloc((size_t)128 * 256 * 2);
    ushort* Bt2u    = (ushort*)alloc((size_t)80 * 128 * 2);
    ushort* Bt2m    = (ushort*)alloc((size_t)80 * 128 * 2);
    float* hlog_u = (float*)alloc((size_t)NU_ * 16 * 4);
    float* hlog_m = (float*)alloc((size_t)NM_ * 16 * 4);
    float* qlog_u = (float*)alloc((size_t)NU_ * 8 * 4);
    float* qlog_m = (float*)alloc((size_t)NM_ * 8 * 4);
    float* pu16   = (float*)alloc((size_t)NU_ * 16 * 4);
    float* pm16   = (float*)alloc((size_t)NM_ * 16 * 4);
    float* cj     = (float*)alloc(16 * 4);
    float* zero16 = (float*)alloc(16 * 4);
    int* rp_um    = (int*)alloc((NM_ + 1) * 4);
    int* rp_mu    = (int*)alloc((NU_ + 1) * 4);
    int* ssrc_um  = (int*)alloc((size_t)NE_ * 4);
    int* ssrc_mu  = (int*)alloc((size_t)NE_ * 4);
    int* rank_um  = (int*)alloc((size_t)NE_ * 4);
    int* rank_mu  = (int*)alloc((size_t)NE_ * 4);
    int* ofs      = (int*)alloc((size_t)(NM_ + NU_) * 4);
    int* partials = (int*)alloc(128 * 4);
    if (ws_size < off) {
        fprintf(stderr, "kernel_launch: ws too small (%zu < %zu)\n", ws_size, off);
        return;
    }

    const int TB = 256;
    const int nbM = cdiv_i(NM_, SCHUNK);
    const int nbU = cdiv_i(NU_, SCHUNK);

    // -------- CSR: count + rank (single atomic pass), scan --------
    hipMemsetAsync(ofs, 0, (size_t)(NM_ + NU_) * sizeof(int), stream);
    count_both<<<cdiv_i(2 * NE_, TB), TB, 0, stream>>>(um_dst, mu_dst, ofs, rank_um, rank_mu, cj);
    scan_phaseA2<<<nbM + nbU, 256, 0, stream>>>(ofs, partials, nbM);
    scan_phaseC2<<<nbM + nbU, 256, 0, stream>>>(ofs, partials, rp_um, rp_mu, nbM, nbU);

    // -------- fused setup (atomic-free CSR fill + builders + conv) --------
    {
        int ntot = N_FILL + 2 * N_BT2 + N_CJ + N_BT1U + N_BT1M + N_BTP + 16 + N_CONV;
        setup_all<<<cdiv_i(ntot, TB), TB, 0, stream>>>(
            um_dst, um_src, mu_dst, mu_src, rp_um, rp_mu, rank_um, rank_mu,
            ssrc_um, ssrc_mu,
            xu, xu_bf, xm, xm_bf,
            w1um_s, a1um_s, w1mu_d, a1mu_d, Bt1u,
            w1mu_s, a1mu_s, w1um_d, a1um_d, Bt1m, Btp,
            w2um_s, a2um_s, w2mu_d, a2mu_d, Bt2u,
            w2mu_s, a2mu_s, w2um_d, a2um_d, Bt2m,
            b2mu, b2um, dw1, db1, cj, zero16);
    }

    // -------- layer-1 GEMMs (merged) --------
    {
        int gNU = cdiv_i(NU_, 64), gNM = cdiv_i(NM_, 64);
        gemm_l1<<<gNU + gNM, TB, 0, stream>>>(
            xu_bf, Bt1u, hlog_u, xm_bf, Bt1m, hproj_m, hlog_m, gNU);
    }

    // -------- layer-1 aggregations (merged) --------
    {
        int gA = cdiv_i(NM_, 4), gB = cdiv_i(NU_, 16);
        agg_l1<<<gA + gB, TB, 0, stream>>>(
            xu_bf, hlog_u, hlog_m, rp_um, ssrc_um, aggx,
            hproj_m, rp_mu, ssrc_mu, b1mu, zu_bf, gA);
    }
    gemm_proj<<<cdiv_i(NM_, 64), TB, 0, stream>>>(aggx, Btp, zm_bf, b1um);

    // -------- layer-2 GEMMs (merged) --------
    {
        int gNU = cdiv_i(NU_, 64), gNM = cdiv_i(NM_, 64);
        gemm_l2<<<gNU + gNM, TB, 0, stream>>>(
            zu_bf, Bt2u, qq_u, qlog_u, zm_bf, Bt2m, qq_m, qlog_m, gNU);
    }

    // -------- layer-2 aggregation (merged, 8 dst/wave) --------
    {
        int nwA = cdiv_i(NM_, 8), nwB = cdiv_i(NU_, 8);
        agg_l2_m<<<cdiv_i(nwA + nwB, 4), TB, 0, stream>>>(
            qq_u, qlog_u, qlog_m + 4, rp_um, ssrc_um, cj, pm16, NM_,
            qq_m, qlog_m, qlog_u + 4, rp_mu, ssrc_mu, zero16, pu16, NU_);
    }

    // -------- decoder --------
    decoder4<<<cdiv_i(EL_ * 4, TB), TB, 0, stream>>>(
        pu16, pm16, lab_u, lab_m, dw2, db2, out, EL_);
}

// Round 15
// 185.419 us; speedup vs baseline: 5.2457x; 1.0026x over previous
//
#include <hip/hip_runtime.h>
#include <hip/hip_bf16.h>
#include <cstdio>

#define NU_ 100000
#define NM_ 20000
#define NE_ 250000
#define EL_ 200000
#define SCHUNK 2048

static inline int cdiv_i(int a, int b) { return (a + b - 1) / b; }

typedef __attribute__((ext_vector_type(8))) short bf16x8;
typedef __attribute__((ext_vector_type(4))) float f32x4;

__device__ __forceinline__ float bf2f(ushort u) {
    unsigned x = ((unsigned)u) << 16;
    return __builtin_bit_cast(float, x);
}
__device__ __forceinline__ ushort f2bf(float f) {
    unsigned x = __builtin_bit_cast(unsigned, f);
    x += 0x7fff + ((x >> 16) & 1);   // RNE
    return (ushort)(x >> 16);
}

// ---------------- fast zero of ofs (+cj): replaces slow runtime fill ----------------
__global__ __launch_bounds__(256) void zero_ofs(int* __restrict__ ofs, float* __restrict__ cj,
                                                int n) {   // n = NM_+NU_
    int i = blockIdx.x * blockDim.x + threadIdx.x;
    int n4 = n >> 2;
    if (i < n4) ((int4*)ofs)[i] = make_int4(0, 0, 0, 0);
    else if (i < n4 + (n & 3)) ofs[(n4 << 2) + (i - n4)] = 0;
    if (i < 16) cj[i] = 0.f;
}

// ---------------- CSR build: count + per-edge rank (single atomic pass) ----------------

__global__ void count_both(const int* __restrict__ um_dst, const int* __restrict__ mu_dst,
                           int* __restrict__ cnt, int* __restrict__ rank_um,
                           int* __restrict__ rank_mu) {
    int i = blockIdx.x * blockDim.x + threadIdx.x;
    if (i < NE_) {
        rank_um[i] = atomicAdd(&cnt[um_dst[i]], 1);
    } else if (i < 2 * NE_) {
        int j = i - NE_;
        rank_mu[j] = atomicAdd(&cnt[NM_ + mu_dst[j]], 1);
    }
}

__global__ __launch_bounds__(256) void scan_phaseA2(const int* __restrict__ in,
                                                    int* __restrict__ partial, int nbM) {
    __shared__ int red[256];
    int b = blockIdx.x, tid = threadIdx.x;
    const int* src; int n; int* part; int bb;
    if (b < nbM) { src = in; n = NM_; part = partial; bb = b; }
    else { src = in + NM_; n = NU_; part = partial + nbM; bb = b - nbM; }
    int base = bb * SCHUNK + tid * 8;
    int s = 0;
#pragma unroll
    for (int j = 0; j < 8; ++j) { int i = base + j; if (i < n) s += src[i]; }
    red[tid] = s;
    __syncthreads();
    for (int off = 128; off; off >>= 1) {
        if (tid < off) red[tid] += red[tid + off];
        __syncthreads();
    }
    if (tid == 0) part[bb] = red[0];
}

// phase C with inlined partials-scan (phase B eliminated); writes rp only
__global__ __launch_bounds__(256) void scan_phaseC2(const int* __restrict__ in,
                                                    const int* __restrict__ partial,
                                                    int* __restrict__ rp_um,
                                                    int* __restrict__ rp_mu,
                                                    int nbM, int nbU) {
    __shared__ int tsum[256];
    __shared__ int blockoff_s, total_s;
    int b = blockIdx.x, tid = threadIdx.x;
    const int* src; int n; const int* part; int* outp; int bb, nb;
    if (b < nbM) { src = in; n = NM_; part = partial; outp = rp_um; bb = b; nb = nbM; }
    else { src = in + NM_; n = NU_; part = partial + nbM; outp = rp_mu; bb = b - nbM; nb = nbU; }
    if (tid < 64) {
        int lane = tid;
        int v = (lane < nb) ? part[lane] : 0;
        int orig = v;
#pragma unroll
        for (int off = 1; off < 64; off <<= 1) {
            int y = __shfl_up(v, off, 64);
            if (lane >= off) v += y;
        }
        if (lane == bb) blockoff_s = v - orig;
        if (lane == nb - 1) total_s = v;
    }
    __syncthreads();
    int base = bb * SCHUNK + tid * 8;
    int v[8];
    int s = 0;
#pragma unroll
    for (int j = 0; j < 8; ++j) { int i = base + j; v[j] = (i < n) ? src[i] : 0; s += v[j]; }
    tsum[tid] = s;
    __syncthreads();
    for (int off = 1; off < 256; off <<= 1) {
        int y = (tid >= off) ? tsum[tid - off] : 0;
        __syncthreads();
        tsum[tid] += y;
        __syncthreads();
    }
    int run = blockoff_s + tsum[tid] - s;
#pragma unroll
    for (int j = 0; j < 8; ++j) {
        int i = base + j;
        if (i < n) outp[i] = run;
        run += v[j];
    }
    if (bb == nb - 1 && tid == 0) outp[n] = total_s;
}

// ---------------- fused setup: atomic-free CSR fill + builders + conv ----------------

#define N_FILL (2 * NE_)
#define N_BT1U (16 * 32)
#define N_BT1M (144 * 128)
#define N_BTP  (128 * 256)
#define N_BT2  (80 * 128)
#define N_CJ   (32 * 16)
#define N_CONV ((NU_ * 32 + NM_ * 128) / 4)

__global__ __launch_bounds__(256) void setup_all(
    const int* __restrict__ um_dst, const int* __restrict__ um_src,
    const int* __restrict__ mu_dst, const int* __restrict__ mu_src,
    const int* __restrict__ rp_um, const int* __restrict__ rp_mu,
    const int* __restrict__ rank_um, const int* __restrict__ rank_mu,
    int* __restrict__ ssrc_um, int* __restrict__ ssrc_mu,
    const float* __restrict__ xu, ushort* __restrict__ xu_bf,
    const float* __restrict__ xm, ushort* __restrict__ xm_bf,
    const float* __restrict__ w1um_s, const float* __restrict__ a1um_s,
    const float* __restrict__ w1mu_d, const float* __restrict__ a1mu_d,
    ushort* __restrict__ Bt1u,
    const float* __restrict__ w1mu_s, const float* __restrict__ a1mu_s,
    const float* __restrict__ w1um_d, const float* __restrict__ a1um_d,
    ushort* __restrict__ Bt1m, ushort* __restrict__ Btp,
    const float* __restrict__ w2um_s, const float* __restrict__ a2um_s,
    const float* __restrict__ w2mu_d, const float* __restrict__ a2mu_d,
    ushort* __restrict__ Bt2u,
    const float* __restrict__ w2mu_s, const float* __restrict__ a2mu_s,
    const float* __restrict__ w2um_d, const float* __restrict__ a2um_d,
    ushort* __restrict__ Bt2m,
    const float* __restrict__ b2mu, const float* __restrict__ b2um,
    const float* __restrict__ dw1, const float* __restrict__ db1,
    float* __restrict__ cj, float* __restrict__ zero16) {
    int i = blockIdx.x * blockDim.x + threadIdx.x;
    // F: CSR fill — pure scatter, no atomics (rank precomputed by count_both)
    if (i < N_FILL) {
        if (i < NE_) {
            int p = rp_um[um_dst[i]] + rank_um[i];
            ssrc_um[p] = um_src[i];
        } else {
            int j = i - NE_;
            int p = rp_mu[mu_dst[j]] + rank_mu[j];
            ssrc_mu[p] = mu_src[j];
        }
        return;
    }
    i -= N_FILL;
    // S0: Bt2u (k-major: c fastest for coalesced dw1/a2 reads)
    if (i < N_BT2) {
        int k = i / 80, c = i % 80;
        float v = 0.f;
        if (c < 64) {
            int h = c >> 4, j = c & 15;
            for (int cc = 0; cc < 128; ++cc)
                v += w2um_s[(size_t)k * 512 + h * 128 + cc] * dw1[(size_t)(512 + h * 128 + cc) * 16 + j];
        } else if (c < 68) {
            int h = c - 64;
            for (int cc = 0; cc < 128; ++cc)
                v += w2um_s[(size_t)k * 512 + h * 128 + cc] * a2um_s[h * 128 + cc];
        } else if (c < 72) {
            int h = c - 68;
            for (int cc = 0; cc < 128; ++cc)
                v += w2mu_d[(size_t)k * 512 + h * 128 + cc] * a2mu_d[h * 128 + cc];
        }
        Bt2u[(size_t)c * 128 + k] = f2bf(v);
        return;
    }
    i -= N_BT2;
    // S1: Bt2m
    if (i < N_BT2) {
        int k = i / 80, c = i % 80;
        float v = 0.f;
        if (c < 64) {
            int h = c >> 4, j = c & 15;
            for (int cc = 0; cc < 128; ++cc)
                v += w2mu_s[(size_t)k * 512 + h * 128 + cc] * dw1[(size_t)(h * 128 + cc) * 16 + j];
        } else if (c < 68) {
            int h = c - 64;
            for (int cc = 0; cc < 128; ++cc)
                v += w2mu_s[(size_t)k * 512 + h * 128 + cc] * a2mu_s[h * 128 + cc];
        } else if (c < 72) {
            int h = c - 68;
            for (int cc = 0; cc < 128; ++cc)
                v += w2um_d[(size_t)k * 512 + h * 128 + cc] * a2um_d[h * 128 + cc];
        }
        Bt2m[(size_t)c * 128 + k] = f2bf(v);
        return;
    }
    i -= N_BT2;
    // S2: cj partials (32 col-groups x 16 j), atomicAdd into cj (zeroed by zero_ofs)
    if (i < N_CJ) {
        int g = i >> 4, j = i & 15;
        float s = 0.f;
        for (int cc = 0; cc < 16; ++cc) {
            int col = g * 16 + cc;
            s += b2mu[col] * dw1[col * 16 + j] + b2um[col] * dw1[(512 + col) * 16 + j];
        }
        if (g == 0) s += db1[j];
        atomicAdd(&cj[j], s);
        return;
    }
    i -= N_CJ;
    // S3: Bt1u
    if (i < N_BT1U) {
        int c = i >> 5, k = i & 31;
        float v = 0.f;
        if (c < 8) {
            for (int cc = 0; cc < 16; ++cc)
                v += w1um_s[(size_t)k * 128 + c * 16 + cc] * a1um_s[c * 16 + cc];
        } else {
            int h = c - 8;
            for (int cc = 0; cc < 16; ++cc)
                v += w1mu_d[(size_t)k * 128 + h * 16 + cc] * a1mu_d[h * 16 + cc];
        }
        Bt1u[c * 32 + k] = f2bf(v);
        return;
    }
    i -= N_BT1U;
    // S4: Bt1m
    if (i < N_BT1M) {
        int c = i >> 7, k = i & 127;
        float v;
        if (c < 128) {
            v = w1mu_s[(size_t)k * 128 + c];
        } else if (c < 136) {
            int h = c - 128; v = 0.f;
            for (int cc = 0; cc < 16; ++cc)
                v += w1mu_s[(size_t)k * 128 + h * 16 + cc] * a1mu_s[h * 16 + cc];
        } else {
            int h = c - 136; v = 0.f;
            for (int cc = 0; cc < 16; ++cc)
                v += w1um_d[(size_t)k * 128 + h * 16 + cc] * a1um_d[h * 16 + cc];
        }
        Bt1m[(size_t)c * 128 + k] = f2bf(v);
        return;
    }
    i -= N_BT1M;
    // S5: Btp (block-diag projection of w1um_s)
    if (i < N_BTP) {
        int c = i >> 8, kk = i & 255;
        int h = kk >> 5, k = kk & 31;
        float v = ((c >> 4) == h) ? w1um_s[(size_t)k * 128 + c] : 0.f;
        Btp[(size_t)c * 256 + kk] = f2bf(v);
        return;
    }
    i -= N_BTP;
    // S6: zero16
    if (i < 16) { zero16[i] = 0.f; return; }
    i -= 16;
    // S7: bf16 casts (bulk)
    if (i < N_CONV) {
        const float* s; ushort* d; int idx;
        int n4a = NU_ * 32 / 4;
        if (i < n4a) { s = xu; d = xu_bf; idx = i; }
        else { s = xm; d = xm_bf; idx = i - n4a; }
        float4 v = ((const float4*)s)[idx];
        ushort4 o;
        o.x = f2bf(v.x); o.y = f2bf(v.y); o.z = f2bf(v.z); o.w = f2bf(v.w);
        ((ushort4*)d)[idx] = o;
    }
}

// ---------------- MFMA GEMM body ----------------
template <int K, int NT>
__device__ __forceinline__ void mfma_body(
    int blk, const ushort* __restrict__ A, const ushort* __restrict__ Bt,
    ushort* __restrict__ outb, int sb, float* __restrict__ outf, int sf,
    int splitc, int maxc, int Nrows, const float* __restrict__ bias, int dorelu) {
    int wave = threadIdx.x >> 6;
    int lane = threadIdx.x & 63;
    int row0 = (blk * 4 + wave) * 16;
    if (row0 >= Nrows) return;
    int r = lane & 15;
    int kb = lane >> 4;
    bf16x8 afrag[K / 32];
    int arow = row0 + r;
    bool rowok = (arow < Nrows);
#pragma unroll
    for (int ks = 0; ks < K / 32; ++ks) {
        if (rowok)
            afrag[ks] = *(const bf16x8*)(A + (size_t)arow * K + ks * 32 + kb * 8);
        else
            afrag[ks] = (bf16x8){0, 0, 0, 0, 0, 0, 0, 0};
    }
#pragma unroll
    for (int nt = 0; nt < NT; ++nt) {
        f32x4 acc = {0.f, 0.f, 0.f, 0.f};
#pragma unroll
        for (int ks = 0; ks < K / 32; ++ks) {
            bf16x8 bfrag = *(const bf16x8*)(Bt + (size_t)(nt * 16 + r) * K + ks * 32 + kb * 8);
            acc = __builtin_amdgcn_mfma_f32_16x16x32_bf16(afrag[ks], bfrag, acc, 0, 0, 0);
        }
        int col = nt * 16 + r;
        float bv = (bias && col < splitc) ? bias[col] : 0.f;
#pragma unroll
        for (int reg = 0; reg < 4; ++reg) {
            int rr = row0 + kb * 4 + reg;
            if (rr < Nrows) {
                if (col < splitc) {
                    float v = acc[reg] + bv;
                    if (dorelu) v = fmaxf(v, 0.f);
                    outb[(size_t)rr * sb + col] = f2bf(v);
                } else if (col < maxc) {
                    outf[(size_t)rr * sf + (col - splitc)] = acc[reg];
                }
            }
        }
    }
}

__global__ __launch_bounds__(256) void gemm_l1(
    const ushort* __restrict__ xu_bf, const ushort* __restrict__ Bt1u,
    float* __restrict__ hlog_u,
    const ushort* __restrict__ xm_bf, const ushort* __restrict__ Bt1m,
    ushort* __restrict__ hproj_m, float* __restrict__ hlog_m, int gNU) {
    int b = blockIdx.x;
    if (b < gNU)
        mfma_body<32, 1>(b, xu_bf, Bt1u, nullptr, 0, hlog_u, 16, 0, 16, NU_, nullptr, 0);
    else
        mfma_body<128, 9>(b - gNU, xm_bf, Bt1m, hproj_m, 128, hlog_m, 16, 128, 144, NM_, nullptr, 0);
}

__global__ __launch_bounds__(256) void gemm_proj(
    const ushort* __restrict__ aggx, const ushort* __restrict__ Btp,
    ushort* __restrict__ zm_bf, const float* __restrict__ b1um) {
    mfma_body<256, 8>(blockIdx.x, aggx, Btp, zm_bf, 128, nullptr, 0, 128, 128, NM_, b1um, 1);
}

__global__ __launch_bounds__(256) void gemm_l2(
    const ushort* __restrict__ zu_bf, const ushort* __restrict__ Bt2u,
    ushort* __restrict__ qq_u, float* __restrict__ qlog_u,
    const ushort* __restrict__ zm_bf, const ushort* __restrict__ Bt2m,
    ushort* __restrict__ qq_m, float* __restrict__ qlog_m, int gNU) {
    int b = blockIdx.x;
    if (b < gNU)
        mfma_body<128, 5>(b, zu_bf, Bt2u, qq_u, 64, qlog_u, 8, 64, 72, NU_, nullptr, 0);
    else
        mfma_body<128, 5>(b - gNU, zm_bf, Bt2m, qq_m, 64, qlog_m, 8, 64, 72, NM_, nullptr, 0);
}

// ---------------- merged layer-1 aggregations (16B loads, edge-parallel) ----------------
__global__ __launch_bounds__(256) void agg_l1(
    const ushort* __restrict__ xu_bf, const float* __restrict__ hlog_u,
    const float* __restrict__ hlog_m, const int* __restrict__ rp_um,
    const int* __restrict__ ssrc_um, ushort* __restrict__ aggx,
    const ushort* __restrict__ hproj_m, const int* __restrict__ rp_mu,
    const int* __restrict__ ssrc_mu, const float* __restrict__ b1mu,
    ushort* __restrict__ zu_bf, int gA) {
    int b = blockIdx.x;
    int lane = threadIdx.x & 63;
    if (b < gA) {
        int wid = (b * 256 + (int)threadIdx.x) >> 6;
        if (wid >= NM_) return;
        int slot = lane >> 5;
        int l5 = lane & 31;
        int h = l5 >> 2, c8 = (l5 & 3) * 8;
        int r0 = rp_um[wid], r1 = rp_um[wid + 1];
        float edv = hlog_m[(size_t)wid * 16 + 8 + h];
        float ssum = 0.f;
        float acc[8] = {0.f, 0.f, 0.f, 0.f, 0.f, 0.f, 0.f, 0.f};
        for (int base = r0; base < r1; base += 64) {
            int cnt = min(64, r1 - base);
            int sv = (base + lane < r1) ? ssrc_um[base + lane] : 0;
            for (int j = 0; j < cnt; j += 2) {
                int jj = j + slot;
                int s = __shfl(sv, jj, 64);
                float x = hlog_u[(size_t)s * 16 + h] + edv;
                x = x > 0.f ? x : 0.2f * x;
                float w = (jj < cnt) ? __expf(x) : 0.f;
                ssum += w;
                bf16x8 xv = *(const bf16x8*)(xu_bf + (size_t)s * 32 + c8);
#pragma unroll
                for (int t = 0; t < 8; ++t)
                    acc[t] = fmaf(bf2f((ushort)xv[t]), w, acc[t]);
            }
        }
        ssum += __shfl_xor(ssum, 32, 64);
#pragma unroll
        for (int t = 0; t < 8; ++t) acc[t] += __shfl_xor(acc[t], 32, 64);
        float inv = 1.f / (ssum + 1e-16f);
        if (slot == 0) {
            bf16x8 o;
#pragma unroll
            for (int t = 0; t < 8; ++t) o[t] = (short)f2bf(acc[t] * inv);
            *(bf16x8*)(aggx + (size_t)wid * 256 + h * 32 + c8) = o;
        }
    } else {
        int wid = ((b - gA) * 256 + (int)threadIdx.x) >> 6;
        int g = lane >> 4, l = lane & 15;
        int dst = wid * 4 + g;
        if (dst >= NU_) return;
        int h = l >> 1, c8 = l * 8;
        int r0 = rp_mu[dst], r1 = rp_mu[dst + 1];
        float edv = hlog_u[(size_t)dst * 16 + 8 + h];
        float ssum = 0.f;
        float acc[8] = {0.f, 0.f, 0.f, 0.f, 0.f, 0.f, 0.f, 0.f};
        for (int base = r0; base < r1; base += 16) {
            int cnt = min(16, r1 - base);
            int sv = (base + l < r1) ? ssrc_mu[base + l] : 0;
            for (int j = 0; j < cnt; ++j) {
                int s = __shfl(sv, (g << 4) | j, 64);
                float x = hlog_m[(size_t)s * 16 + h] + edv;
                x = x > 0.f ? x : 0.2f * x;
                float w = __expf(x);
                ssum += w;
                bf16x8 hv = *(const bf16x8*)(hproj_m + (size_t)s * 128 + c8);
#pragma unroll
                for (int t = 0; t < 8; ++t)
                    acc[t] = fmaf(bf2f((ushort)hv[t]), w, acc[t]);
            }
        }
        float inv = 1.f / (ssum + 1e-16f);
        bf16x8 o;
#pragma unroll
        for (int t = 0; t < 8; ++t) {
            float v = fmaxf(fmaf(acc[t], inv, b1mu[c8 + t]), 0.f);
            o[t] = (short)f2bf(v);
        }
        *(bf16x8*)(zu_bf + (size_t)dst * 128 + c8) = o;
    }
}

// ---------------- layer-2 aggregation, both directions, 8 dsts/wave, 16B loads ----------------
__global__ __launch_bounds__(256) void agg_l2_m(
    const ushort* __restrict__ qA, const float* __restrict__ esA,
    const float* __restrict__ edA, const int* __restrict__ rpA,
    const int* __restrict__ srcA, const float* __restrict__ biasA,
    float* __restrict__ outA, int NdA,
    const ushort* __restrict__ qB, const float* __restrict__ esB,
    const float* __restrict__ edB, const int* __restrict__ rpB,
    const int* __restrict__ srcB, const float* __restrict__ biasB,
    float* __restrict__ outB, int NdB) {
    int wid = (blockIdx.x * 256 + threadIdx.x) >> 6;
    int lane = threadIdx.x & 63;
    int g = lane >> 3, l = lane & 7;
    int nwA = (NdA + 7) >> 3;
    const ushort* q; const float* es; const float* ed; const int* rp;
    const int* src; const float* bias16; float* o16; int dst, Nd;
    if (wid < nwA) {
        q = qA; es = esA; ed = edA; rp = rpA; src = srcA;
        bias16 = biasA; o16 = outA; Nd = NdA; dst = wid * 8 + g;
    } else {
        int w2 = wid - nwA;
        q = qB; es = esB; ed = edB; rp = rpB; src = srcB;
        bias16 = biasB; o16 = outB; Nd = NdB; dst = w2 * 8 + g;
    }
    if (dst >= Nd) return;
    int h = l >> 1, c8 = l * 8;
    int r0 = rp[dst], r1 = rp[dst + 1];
    float edv = ed[(size_t)dst * 8 + h];
    float ssum = 0.f;
    float acc[8] = {0.f, 0.f, 0.f, 0.f, 0.f, 0.f, 0.f, 0.f};
    for (int base = r0; base < r1; base += 8) {
        int cnt = min(8, r1 - base);
        int sv = (base + l < r1) ? src[base + l] : 0;
        for (int j = 0; j < cnt; ++j) {
            int s = __shfl(sv, (g << 3) | j, 64);
            float x = es[(size_t)s * 8 + h] + edv;
            x = x > 0.f ? x : 0.2f * x;
            float w = __expf(x);
            ssum += w;
            bf16x8 qv = *(const bf16x8*)(q + (size_t)s * 64 + c8);
#pragma unroll
            for (int t = 0; t < 8; ++t)
                acc[t] = fmaf(bf2f((ushort)qv[t]), w, acc[t]);
        }
    }
    float inv = 1.f / (ssum + 1e-16f);
#pragma unroll
    for (int t = 0; t < 8; ++t) {
        acc[t] *= inv;
        acc[t] += __shfl_xor(acc[t], 2, 64);
        acc[t] += __shfl_xor(acc[t], 4, 64);
    }
    if (l < 2) {
        int jb = 8 * l;
        float4 o0 = make_float4(acc[0] + bias16[jb + 0], acc[1] + bias16[jb + 1],
                                acc[2] + bias16[jb + 2], acc[3] + bias16[jb + 3]);
        float4 o1 = make_float4(acc[4] + bias16[jb + 4], acc[5] + bias16[jb + 5],
                                acc[6] + bias16[jb + 6], acc[7] + bias16[jb + 7]);
        *(float4*)(o16 + (size_t)dst * 16 + jb) = o0;
        *(float4*)(o16 + (size_t)dst * 16 + jb + 4) = o1;
    }
}

// ---------------- decoder: 4 lanes per label edge, float4 loads ----------------
__global__ __launch_bounds__(256) void decoder4(
    const float* __restrict__ pu16, const float* __restrict__ pm16,
    const int* __restrict__ lab_u, const int* __restrict__ lab_m,
    const float* __restrict__ dw2, const float* __restrict__ db2,
    float* __restrict__ out, int nE) {
    int t = blockIdx.x * 256 + threadIdx.x;
    int e = t >> 2, sub = t & 3;
    if (e >= nE) return;
    int u = lab_u[e], m = lab_m[e];
    float4 a = *(const float4*)(pu16 + (size_t)u * 16 + sub * 4);
    float4 b = *(const float4*)(pm16 + (size_t)m * 16 + sub * 4);
    const float* w = dw2 + sub * 4;
    float r = fmaxf(a.x + b.x, 0.f) * w[0] + fmaxf(a.y + b.y, 0.f) * w[1] +
              fmaxf(a.z + b.z, 0.f) * w[2] + fmaxf(a.w + b.w, 0.f) * w[3];
    r += __shfl_xor(r, 1, 64);
    r += __shfl_xor(r, 2, 64);
    if (sub == 0) out[e] = r + db2[0];
}

// ---------------- host ----------------

extern "C" void kernel_launch(void* const* d_in, const int* in_sizes, int n_in,
                              void* d_out, int out_size, void* d_ws, size_t ws_size,
                              hipStream_t stream) {
    const float* xu = (const float*)d_in[0];
    const float* xm = (const float*)d_in[1];
    const int* um_src = (const int*)d_in[2];
    const int* um_dst = (const int*)d_in[3];
    const int* mu_src = (const int*)d_in[4];
    const int* mu_dst = (const int*)d_in[5];
    const int* lab_u = (const int*)d_in[6];
    const int* lab_m = (const int*)d_in[7];
    const float* w1um_s = (const float*)d_in[8];
    const float* w1um_d = (const float*)d_in[9];
    const float* a1um_s = (const float*)d_in[10];
    const float* a1um_d = (const float*)d_in[11];
    const float* b1um = (const float*)d_in[12];
    const float* w1mu_s = (const float*)d_in[13];
    const float* w1mu_d = (const float*)d_in[14];
    const float* a1mu_s = (const float*)d_in[15];
    const float* a1mu_d = (const float*)d_in[16];
    const float* b1mu = (const float*)d_in[17];
    const float* w2um_s = (const float*)d_in[18];
    const float* w2um_d = (const float*)d_in[19];
    const float* a2um_s = (const float*)d_in[20];
    const float* a2um_d = (const float*)d_in[21];
    const float* b2um = (const float*)d_in[22];
    const float* w2mu_s = (const float*)d_in[23];
    const float* w2mu_d = (const float*)d_in[24];
    const float* a2mu_s = (const float*)d_in[25];
    const float* a2mu_d = (const float*)d_in[26];
    const float* b2mu = (const float*)d_in[27];
    const float* dw1 = (const float*)d_in[28];
    const float* db1 = (const float*)d_in[29];
    const float* dw2 = (const float*)d_in[30];
    const float* db2 = (const float*)d_in[31];
    float* out = (float*)d_out;

    // -------- workspace carving --------
    char* base = (char*)d_ws;
    size_t off = 0;
    auto alloc = [&](size_t bytes) -> void* {
        void* p = base + off;
        off = (off + bytes + 63) & ~(size_t)63;
        return p;
    };
    ushort* xu_bf   = (ushort*)alloc((size_t)NU_ * 32 * 2);
    ushort* xm_bf   = (ushort*)alloc((size_t)NM_ * 128 * 2);
    ushort* hproj_m = (ushort*)alloc((size_t)NM_ * 128 * 2);
    ushort* aggx    = (ushort*)alloc((size_t)NM_ * 256 * 2);
    ushort* zu_bf   = (ushort*)alloc((size_t)NU_ * 128 * 2);
    ushort* zm_bf   = (ushort*)alloc((size_t)NM_ * 128 * 2);
    ushort* qq_u    = (ushort*)alloc((size_t)NU_ * 64 * 2);
    ushort* qq_m    = (ushort*)alloc((size_t)NM_ * 64 * 2);
    ushort* Bt1u    = (ushort*)alloc((size_t)16 * 32 * 2);
    ushort* Bt1m    = (ushort*)alloc((size_t)144 * 128 * 2);
    ushort* Btp     = (ushort*)alloc((size_t)128 * 256 * 2);
    ushort* Bt2u    = (ushort*)alloc((size_t)80 * 128 * 2);
    ushort* Bt2m    = (ushort*)alloc((size_t)80 * 128 * 2);
    float* hlog_u = (float*)alloc((size_t)NU_ * 16 * 4);
    float* hlog_m = (float*)alloc((size_t)NM_ * 16 * 4);
    float* qlog_u = (float*)alloc((size_t)NU_ * 8 * 4);
    float* qlog_m = (float*)alloc((size_t)NM_ * 8 * 4);
    float* pu16   = (float*)alloc((size_t)NU_ * 16 * 4);
    float* pm16   = (float*)alloc((size_t)NM_ * 16 * 4);
    float* cj     = (float*)alloc(16 * 4);
    float* zero16 = (float*)alloc(16 * 4);
    int* rp_um    = (int*)alloc((NM_ + 1) * 4);
    int* rp_mu    = (int*)alloc((NU_ + 1) * 4);
    int* ssrc_um  = (int*)alloc((size_t)NE_ * 4);
    int* ssrc_mu  = (int*)alloc((size_t)NE_ * 4);
    int* rank_um  = (int*)alloc((size_t)NE_ * 4);
    int* rank_mu  = (int*)alloc((size_t)NE_ * 4);
    int* ofs      = (int*)alloc((size_t)(NM_ + NU_) * 4);
    int* partials = (int*)alloc(128 * 4);
    if (ws_size < off) {
        fprintf(stderr, "kernel_launch: ws too small (%zu < %zu)\n", ws_size, off);
        return;
    }

    const int TB = 256;
    const int nbM = cdiv_i(NM_, SCHUNK);
    const int nbU = cdiv_i(NU_, SCHUNK);

    // -------- CSR: fast zero, count + rank (single atomic pass), scan --------
    zero_ofs<<<cdiv_i((NM_ + NU_) / 4 + 8, TB), TB, 0, stream>>>(ofs, cj, NM_ + NU_);
    count_both<<<cdiv_i(2 * NE_, TB), TB, 0, stream>>>(um_dst, mu_dst, ofs, rank_um, rank_mu);
    scan_phaseA2<<<nbM + nbU, 256, 0, stream>>>(ofs, partials, nbM);
    scan_phaseC2<<<nbM + nbU, 256, 0, stream>>>(ofs, partials, rp_um, rp_mu, nbM, nbU);

    // -------- fused setup (atomic-free CSR fill + builders + conv) --------
    {
        int ntot = N_FILL + 2 * N_BT2 + N_CJ + N_BT1U + N_BT1M + N_BTP + 16 + N_CONV;
        setup_all<<<cdiv_i(ntot, TB), TB, 0, stream>>>(
            um_dst, um_src, mu_dst, mu_src, rp_um, rp_mu, rank_um, rank_mu,
            ssrc_um, ssrc_mu,
            xu, xu_bf, xm, xm_bf,
            w1um_s, a1um_s, w1mu_d, a1mu_d, Bt1u,
            w1mu_s, a1mu_s, w1um_d, a1um_d, Bt1m, Btp,
            w2um_s, a2um_s, w2mu_d, a2mu_d, Bt2u,
            w2mu_s, a2mu_s, w2um_d, a2um_d, Bt2m,
            b2mu, b2um, dw1, db1, cj, zero16);
    }

    // -------- layer-1 GEMMs (merged) --------
    {
        int gNU = cdiv_i(NU_, 64), gNM = cdiv_i(NM_, 64);
        gemm_l1<<<gNU + gNM, TB, 0, stream>>>(
            xu_bf, Bt1u, hlog_u, xm_bf, Bt1m, hproj_m, hlog_m, gNU);
    }

    // -------- layer-1 aggregations (merged) --------
    {
        int gA = cdiv_i(NM_, 4), gB = cdiv_i(NU_, 16);
        agg_l1<<<gA + gB, TB, 0, stream>>>(
            xu_bf, hlog_u, hlog_m, rp_um, ssrc_um, aggx,
            hproj_m, rp_mu, ssrc_mu, b1mu, zu_bf, gA);
    }
    gemm_proj<<<cdiv_i(NM_, 64), TB, 0, stream>>>(aggx, Btp, zm_bf, b1um);

    // -------- layer-2 GEMMs (merged) --------
    {
        int gNU = cdiv_i(NU_, 64), gNM = cdiv_i(NM_, 64);
        gemm_l2<<<gNU + gNM, TB, 0, stream>>>(
            zu_bf, Bt2u, qq_u, qlog_u, zm_bf, Bt2m, qq_m, qlog_m, gNU);
    }

    // -------- layer-2 aggregation (merged, 8 dst/wave) --------
    {
        int nwA = cdiv_i(NM_, 8), nwB = cdiv_i(NU_, 8);
        agg_l2_m<<<cdiv_i(nwA + nwB, 4), TB, 0, stream>>>(
            qq_u, qlog_u, qlog_m + 4, rp_um, ssrc_um, cj, pm16, NM_,
            qq_m, qlog_m, qlog_u + 4, rp_mu, ssrc_mu, zero16, pu16, NU_);
    }

    // -------- decoder --------
    decoder4<<<cdiv_i(EL_ * 4, TB), TB, 0, stream>>>(
        pu16, pm16, lab_u, lab_m, dw2, db2, out, EL_);
}